// Round 7
// baseline (661.225 us; speedup 1.0000x reference)
//
#include <hip/hip_runtime.h>
#include <hip/hip_bf16.h>
#include <math.h>

#define BN_EPS 1e-3f

constexpr int Bn = 4, Hn = 64, Wn = 64, CIN = 512, CI = 128;
constexpr int HWn = Hn * Wn;        // 4096
constexpr int NPIX = Bn * HWn;      // 16384
constexpr int COn = 19;

struct F8 { float4 lo, hi; };

__device__ __forceinline__ F8 f8zero() {
    F8 r; r.lo = make_float4(0.f,0.f,0.f,0.f); r.hi = make_float4(0.f,0.f,0.f,0.f); return r;
}
__device__ __forceinline__ void fma8(F8 &acc, float a, const float4 &wlo, const float4 &whi) {
    acc.lo.x = fmaf(a, wlo.x, acc.lo.x);
    acc.lo.y = fmaf(a, wlo.y, acc.lo.y);
    acc.lo.z = fmaf(a, wlo.z, acc.lo.z);
    acc.lo.w = fmaf(a, wlo.w, acc.lo.w);
    acc.hi.x = fmaf(a, whi.x, acc.hi.x);
    acc.hi.y = fmaf(a, whi.y, acc.hi.y);
    acc.hi.z = fmaf(a, whi.z, acc.hi.z);
    acc.hi.w = fmaf(a, whi.w, acc.hi.w);
}

// ---- MFMA helpers -----------------------------------------------------------
typedef __attribute__((ext_vector_type(8)))  short short8;   // 8 bf16 in 4 VGPRs
typedef __attribute__((ext_vector_type(16))) float f32x16;

__device__ __forceinline__ f32x16 f16z() {
    f32x16 z;
    #pragma unroll
    for (int i = 0; i < 16; ++i) z[i] = 0.f;
    return z;
}
// fp32 -> bf16 (RNE), pure integer ops
__device__ __forceinline__ unsigned f2b(float f) {
    union { float f; unsigned u; } c; c.f = f;
    return (c.u + 0x7FFFu + ((c.u >> 16) & 1u)) >> 16;
}
__device__ __forceinline__ unsigned pack2(float lo, float hi) {
    return (f2b(hi) << 16) | f2b(lo);
}
// split (a,b) into packed bf16 hi words + bf16 lo residuals (a in low half)
__device__ __forceinline__ void split2(float a, float b, unsigned &hi, unsigned &lo) {
    const unsigned ha = f2b(a), hb = f2b(b);
    union { unsigned u; float f; } ua, ub; ua.u = ha << 16; ub.u = hb << 16;
    hi = (hb << 16) | ha;
    lo = pack2(a - ua.f, b - ub.f);
}

// ---------------- prep: weights -> bf16 hi/lo, co-major, LINEAR --------------
// wt1{H,L}: [32 chunk][9 tap][256 co][16 ch]  (co<128 -> w5a, else w5c)
// wt2a/b{H,L}: [8 chunk][9 tap][128 co][16 ch] for w51/w52 (294912 B each)
// Linear layout (no swizzle): consumed by per-wave global_load_dwordx4.
__global__ __launch_bounds__(256)
void k_prep_w(const float* __restrict__ w5a, const float* __restrict__ w5c,
              const float* __restrict__ w51, const float* __restrict__ w52,
              char* __restrict__ wt1H, char* __restrict__ wt1L,
              char* __restrict__ wt2aH, char* __restrict__ wt2aL,
              char* __restrict__ wt2bH, char* __restrict__ wt2bL)
{
    int idx = blockIdx.x * 256 + threadIdx.x;
    if (idx < 589824) {                       // 32*9*256*8 pairs
        const int jp = idx & 7, co = (idx >> 3) & 255, ct = idx >> 11; // ct=c*9+tap
        const int tap = ct % 9, c = ct / 9;
        const float* src = (co < 128) ? w5a : w5c;
        const int coc = co & 127;
        const int ci = c*16 + jp*2;
        const float a = src[((size_t)tap*CIN + ci)*CI + coc];
        const float b = src[((size_t)tap*CIN + ci + 1)*CI + coc];
        unsigned hi, lo; split2(a, b, hi, lo);
        const int L = co*32 + jp*4;
        *(unsigned*)(wt1H + (size_t)ct*8192 + L) = hi;
        *(unsigned*)(wt1L + (size_t)ct*8192 + L) = lo;
    } else {
        int k = idx - 589824;                 // 2 * 8*9*128*8 pairs
        if (k >= 147456) return;
        const float* src = (k < 73728) ? w51 : w52;
        char* dstH = (k < 73728) ? wt2aH : wt2bH;
        char* dstL = (k < 73728) ? wt2aL : wt2bL;
        if (k >= 73728) k -= 73728;
        const int jp = k & 7, co = (k >> 3) & 127, ct = k >> 10; // ct=c*9+tap
        const int tap = ct % 9, c = ct / 9;
        const int ci = c*16 + jp*2;
        const float a = src[((size_t)tap*CI + ci)*CI + co];
        const float b = src[((size_t)tap*CI + ci + 1)*CI + co];
        unsigned hi, lo; split2(a, b, hi, lo);
        const int L = co*32 + jp*4;
        *(unsigned*)(dstH + (size_t)ct*4096 + L) = hi;
        *(unsigned*)(dstL + (size_t)ct*4096 + L) = lo;
    }
}

// ---------------- prep: BN -> folded scale/bias tables -----------------------
__global__ __launch_bounds__(256)
void k_prep_bn(const float* g1, const float* b1, const float* m1, const float* v1,
               const float* g2, const float* b2, const float* m2, const float* v2,
               const float* g3, const float* b3, const float* m3, const float* v3,
               const float* g4, const float* b4, const float* m4, const float* v4,
               float* bnAs, float* bnAb, float* bnBs, float* bnBb)
{
    const int t = threadIdx.x, c = t & 127;
    {
        const float *g = (t < 128) ? g1 : g2, *b = (t < 128) ? b1 : b2;
        const float *m = (t < 128) ? m1 : m2, *v = (t < 128) ? v1 : v2;
        const float s = g[c] * rsqrtf(v[c] + BN_EPS);
        bnAs[t] = s; bnAb[t] = b[c] - m[c]*s;
    }
    {
        const float *g = (t < 128) ? g3 : g4, *b = (t < 128) ? b3 : b4;
        const float *m = (t < 128) ? m3 : m4, *v = (t < 128) ? v3 : v4;
        const float s = g[c] * rsqrtf(v[c] + BN_EPS);
        bnBs[t] = s; bnBb[t] = b[c] - m[c]*s;
    }
}

// ---------------- MFMA 3x3 conv, bf16x3 split + folded BN + ReLU -------------
// Block = one image row (64 px) x 128 co (blockIdx.y selects the co half for
// conv1). 256 thr / 4 waves; wave = 2 M-tiles x 1 N-tile. W is read directly
// global->VGPR per wave (wave-private co rows, L2-resident) — no W staging,
// no W barriers. X staged in LDS as bf16 hi/lo with XOR swizzle ((s&7)<<4),
// software-pipelined: chunk c+1's global loads issue during chunk c's MFMAs.
// 3-term product: xh*wh + xl*wh + xh*wl (~fp32 accurate).
// mfma(A=W^T[co][k], B=X[px][k]) -> D[col=px][row=co]  (k_pam-validated map)
template<int CICH, int NCO>
__global__ __launch_bounds__(256)
void k_convm(const float* __restrict__ xin,
             const char* __restrict__ wtH, const char* __restrict__ wtL,
             const float* __restrict__ bnS, const float* __restrict__ bnBi,
             float* __restrict__ out0, float* __restrict__ out1)
{
    constexpr int NCHNK = CICH / 16;
    constexpr int XPAGE = 66 * 32;            // 2112 B per staged row
    __shared__ __align__(16) char Xs[6*XPAGE];
    char* Xh = Xs;
    char* Xl = Xs + 3*XPAGE;

    const int t   = threadIdx.x;
    const int row = blockIdx.x;               // 0..255 = b*64 + h
    const int cg  = blockIdx.y;               // co half (conv1: 0/1)
    const int bb  = row >> 6, hh = row & 63;
    const int dyLo = (hh == 0)  ? 1 : 0;
    const int dyHi = (hh == 63) ? 1 : 2;
    const int l = t & 63, w = t >> 6;
    const int lo5 = l & 31, hf = l >> 5;
    const int cobase = cg*128 + w*32 + lo5;   // this lane's co row in wt pages

    f32x16 acc[2];
    acc[0] = f16z(); acc[1] = f16z();

    float4 xr[4];
    // ---- prefetch chunk 0 ----
    #pragma unroll
    for (int i = 0; i < 4; ++i) {
        const int u = t + i*256;
        float4 v = make_float4(0.f,0.f,0.f,0.f);
        if (u < 792) {
            const int dyr = u/264, rs = u - dyr*264;
            const int s = rs >> 2, u4 = rs & 3;
            if (dyr >= dyLo && dyr <= dyHi && s >= 1 && s <= 64)
                v = *(const float4*)&xin[
                    (((size_t)bb*Hn + (hh + dyr - 1))*Wn + (s - 1))*CICH + u4*4];
        }
        xr[i] = v;
    }

    for (int c = 0; c < NCHNK; ++c) {
        __syncthreads();                      // previous chunk's reads done
        // ---- write staged X (hi/lo, swizzled) ----
        #pragma unroll
        for (int i = 0; i < 4; ++i) {
            const int u = t + i*256;
            if (u < 792) {
                const int dyr = u/264, rs = u - dyr*264;
                const int s = rs >> 2, u4 = rs & 3;
                if (dyr >= dyLo && dyr <= dyHi) {
                    uint2 vh, vl;
                    split2(xr[i].x, xr[i].y, vh.x, vl.x);
                    split2(xr[i].z, xr[i].w, vh.y, vl.y);
                    const int off = dyr*XPAGE + ((s*32 + u4*8) ^ ((s & 7) << 4));
                    *(uint2*)(Xh + off) = vh;
                    *(uint2*)(Xl + off) = vl;
                }
            }
        }
        __syncthreads();
        // ---- prefetch chunk c+1 (hides under MFMA phase) ----
        if (c + 1 < NCHNK) {
            #pragma unroll
            for (int i = 0; i < 4; ++i) {
                const int u = t + i*256;
                float4 v = make_float4(0.f,0.f,0.f,0.f);
                if (u < 792) {
                    const int dyr = u/264, rs = u - dyr*264;
                    const int s = rs >> 2, u4 = rs & 3;
                    if (dyr >= dyLo && dyr <= dyHi && s >= 1 && s <= 64)
                        v = *(const float4*)&xin[
                            (((size_t)bb*Hn + (hh + dyr - 1))*Wn + (s - 1))*CICH
                            + (c + 1)*16 + u4*4];
                }
                xr[i] = v;
            }
        }
        // ---- compute: 9 taps, W straight from global (L2) ----
        #pragma unroll
        for (int dy = 0; dy < 3; ++dy) {
            if (dy < dyLo || dy > dyHi) continue;   // block-uniform
            const char* Xph = Xh + dy*XPAGE;
            const char* Xpl = Xl + dy*XPAGE;
            #pragma unroll
            for (int dx = 0; dx < 3; ++dx) {
                short8 xfh[2], xfl[2];
                #pragma unroll
                for (int mi = 0; mi < 2; ++mi) {
                    const int s = mi*32 + lo5 + dx;
                    const int xo = (s*32 + hf*16) ^ ((s & 7) << 4);
                    xfh[mi] = *(const short8*)(Xph + xo);
                    xfl[mi] = *(const short8*)(Xpl + xo);
                }
                const size_t wo = ((size_t)(c*9 + dy*3 + dx)*NCO + cobase)*32 + hf*16;
                const short8 wfh = *(const short8*)(wtH + wo);
                const short8 wfl = *(const short8*)(wtL + wo);
                #pragma unroll
                for (int mi = 0; mi < 2; ++mi) {
                    acc[mi] = __builtin_amdgcn_mfma_f32_32x32x16_bf16(wfh, xfh[mi], acc[mi], 0, 0, 0);
                    acc[mi] = __builtin_amdgcn_mfma_f32_32x32x16_bf16(wfh, xfl[mi], acc[mi], 0, 0, 0);
                    acc[mi] = __builtin_amdgcn_mfma_f32_32x32x16_bf16(wfl, xfh[mi], acc[mi], 0, 0, 0);
                }
            }
        }
    }
    // ---- epilogue: folded BN + ReLU ----
    float* dst = (cg == 0) ? out0 : out1;
    #pragma unroll
    for (int mi = 0; mi < 2; ++mi) {
        const int px = mi*32 + lo5;
        const size_t p = (size_t)row*Wn + px;
        #pragma unroll
        for (int r = 0; r < 16; ++r) {
            const int crow = (r & 3) + 8*(r >> 2) + 4*hf;
            const int och = w*32 + crow;
            const int bnidx = cg*128 + och;
            dst[p*CI + och] = fmaxf(fmaf(acc[mi][r], bnS[bnidx], bnBi[bnidx]), 0.f);
        }
    }
}

// ---------------- K2a: q,k 1x1 conv -> bf16 [NPIX][16] each ------------------
__global__ __launch_bounds__(256)
void k_qk(const float* __restrict__ feat1,
          const float* __restrict__ wq, const float* __restrict__ bq,
          const float* __restrict__ wk, const float* __restrict__ bk,
          __hip_bfloat16* __restrict__ qb, __hip_bfloat16* __restrict__ kb)
{
    __shared__ float Al[64*129];
    __shared__ __align__(16) float Wl[128*32];
    const int t = threadIdx.x;
    const int pb = blockIdx.x * 64;
    for (int idx = t; idx < 64*128; idx += 256) {
        const int p = idx >> 7, ci = idx & 127;
        Al[p*129 + ci] = feat1[(size_t)(pb + p)*CI + ci];
    }
    for (int idx = t; idx < 128*32; idx += 256) {
        const int ci = idx >> 5, c = idx & 31;
        Wl[idx] = (c < 16) ? wq[ci*16 + c] : wk[ci*16 + (c - 16)];
    }
    __syncthreads();
    const int p = t & 63, cg = t >> 6, co = cg * 8;
    F8 acc = f8zero();
    #pragma unroll 8
    for (int ci = 0; ci < 128; ++ci) {
        const float a = Al[p*129 + ci];
        const float4 wlo = *(const float4*)&Wl[ci*32 + co];
        const float4 whi = *(const float4*)&Wl[ci*32 + co + 4];
        fma8(acc, a, wlo, whi);
    }
    const float* af = (const float*)&acc;
    #pragma unroll
    for (int j = 0; j < 8; ++j) {
        const int c = co + j;
        if (c < 16) qb[(size_t)(pb + p)*16 + c]        = __float2bfloat16(af[j] + bq[c]);
        else        kb[(size_t)(pb + p)*16 + (c - 16)] = __float2bfloat16(af[j] + bk[c - 16]);
    }
}

// ---------------- K2b: v 1x1 conv -> bf16 TRANSPOSED [b][c][pix] -------------
__global__ __launch_bounds__(256)
void k_v(const float* __restrict__ feat1, const float* __restrict__ wv,
         const float* __restrict__ bv, __hip_bfloat16* __restrict__ vbT)
{
    __shared__ float Al[32*129];
    __shared__ __align__(16) float Wl[64*128];
    const int t = threadIdx.x;
    const int pb = blockIdx.x * 32;
    for (int idx = t; idx < 32*128; idx += 256) {
        const int p = idx >> 7, ci = idx & 127;
        Al[p*129 + ci] = feat1[(size_t)(pb + p)*CI + ci];
    }
    const int px = t & 15, co = (t >> 4) * 8;
    F8 acc0 = f8zero(), acc1 = f8zero();
    for (int ch = 0; ch < 2; ++ch) {
        __syncthreads();
        #pragma unroll
        for (int r = 0; r < 8; ++r) {
            const int i4 = t + r*256;
            const int kk = i4 >> 5, c4 = (i4 & 31) * 4;
            *(float4*)&Wl[kk*128 + c4] = *(const float4*)&wv[(size_t)(ch*64 + kk)*CI + c4];
        }
        __syncthreads();
        #pragma unroll 4
        for (int kk = 0; kk < 64; ++kk) {
            const float a0 = Al[px*129 + ch*64 + kk];
            const float a1 = Al[(px+16)*129 + ch*64 + kk];
            const float4 wlo = *(const float4*)&Wl[kk*128 + co];
            const float4 whi = *(const float4*)&Wl[kk*128 + co + 4];
            fma8(acc0, a0, wlo, whi);
            fma8(acc1, a1, wlo, whi);
        }
    }
    const int p0 = pb + px;
    const int bb = p0 / HWn, pin0 = p0 % HWn;
    const float* a0f = (const float*)&acc0;
    const float* a1f = (const float*)&acc1;
    #pragma unroll
    for (int j = 0; j < 8; ++j) {
        const int c = co + j;
        const size_t rowb = ((size_t)bb*CI + c) * HWn;
        vbT[rowb + pin0]      = __float2bfloat16(a0f[j] + bv[c]);
        vbT[rowb + pin0 + 16] = __float2bfloat16(a1f[j] + bv[c]);
    }
}

// ---------------- K3: PAM flash attention via MFMA ---------------------------
__global__ __launch_bounds__(64)
void k_pam(const __hip_bfloat16* __restrict__ qb, const __hip_bfloat16* __restrict__ kb,
           const __hip_bfloat16* __restrict__ vbT, const float* __restrict__ feat1,
           const float* __restrict__ gamma, float* __restrict__ saf)
{
    __shared__ unsigned Ppk[32*32];   // [key-pair 0..31][q 0..31], bf16x2 packed
    const int l   = threadIdx.x;
    const int lo5 = l & 31, h = l >> 5;
    const int q0  = blockIdx.x * 32;
    const int bb  = q0 / HWn;
    const size_t jb = (size_t)bb * HWn;
    const __hip_bfloat16* vbB = vbT + (size_t)bb * CI * HWn;

    const short8 qfrag = *(const short8*)&qb[(size_t)(q0 + lo5)*16 + 8*h];
    const f32x16 zro = f16z();

    f32x16 o[4];
    #pragma unroll
    for (int cb = 0; cb < 4; ++cb) o[cb] = f16z();

    float m_run = -1e30f, s_run = 0.f;

    for (int k0 = 0; k0 < HWn; k0 += 64) {
        const short8 kf0 = *(const short8*)&kb[(jb + k0 +      lo5)*16 + 8*h];
        const short8 kf1 = *(const short8*)&kb[(jb + k0 + 32 + lo5)*16 + 8*h];
        short8 vf[4][4];
        #pragma unroll
        for (int s = 0; s < 4; ++s)
            #pragma unroll
            for (int cb = 0; cb < 4; ++cb)
                vf[s][cb] = *(const short8*)&vbB[((size_t)(cb*32 + lo5))*HWn + k0 + s*16 + 8*h];

        f32x16 e0 = __builtin_amdgcn_mfma_f32_32x32x16_bf16(kf0, qfrag, zro, 0, 0, 0);
        f32x16 e1 = __builtin_amdgcn_mfma_f32_32x32x16_bf16(kf1, qfrag, zro, 0, 0, 0);

        float mt = fmaxf(e0[0], e1[0]);
        #pragma unroll
        for (int r = 1; r < 16; ++r) mt = fmaxf(mt, fmaxf(e0[r], e1[r]));
        mt = fmaxf(mt, __shfl_xor(mt, 32));

        if (__any(mt > m_run + 8.f)) {
            const float mnew = fmaxf(m_run, mt);
            const float sc = __expf(m_run - mnew);
            s_run *= sc;
            #pragma unroll
            for (int cb = 0; cb < 4; ++cb)
                #pragma unroll
                for (int r = 0; r < 16; ++r) o[cb][r] *= sc;
            m_run = mnew;
        }

        #pragma unroll
        for (int r = 0; r < 16; ++r) {
            e0[r] = __expf(e0[r] - m_run);
            e1[r] = __expf(e1[r] - m_run);
        }
        float ss = 0.f;
        #pragma unroll
        for (int r = 0; r < 16; ++r) ss += e0[r] + e1[r];
        s_run += ss;

        #pragma unroll
        for (int r = 0; r < 16; r += 2) {
            const int pidx = ((r & 3) >> 1) + 4*(r >> 2) + 2*h;
            Ppk[pidx*32 + lo5]        = pack2(e0[r], e0[r+1]);
            Ppk[(16 + pidx)*32 + lo5] = pack2(e1[r], e1[r+1]);
        }
        #pragma unroll
        for (int s = 0; s < 4; ++s) {
            union { unsigned u[4]; short8 s8; } P;
            #pragma unroll
            for (int w = 0; w < 4; ++w)
                P.u[w] = Ppk[(s*8 + 4*h + w)*32 + lo5];
            #pragma unroll
            for (int cb = 0; cb < 4; ++cb)
                o[cb] = __builtin_amdgcn_mfma_f32_32x32x16_bf16(vf[s][cb], P.s8, o[cb], 0, 0, 0);
        }
    }

    const float s_tot = s_run + __shfl_xor(s_run, 32);
    const float inv = 1.f / s_tot;
    const float g = gamma[0];
    const size_t q = (size_t)q0 + lo5;
    #pragma unroll
    for (int cb = 0; cb < 4; ++cb)
        #pragma unroll
        for (int r = 0; r < 16; ++r) {
            const int c = cb*32 + (r & 3) + 8*(r >> 2) + 4*h;
            const size_t idx = q*CI + c;
            saf[idx] = g*(o[cb][r]*inv) + feat1[idx];
        }
}

// ---------------- K4a: CAM energy = X^T X (per batch, 32x32 tiles) ----------
__global__ __launch_bounds__(256)
void k_cam_energy(const float* __restrict__ feat2, float* __restrict__ energy)
{
    __shared__ float Xc[64*33];
    __shared__ float Xd[64*33];
    const int t = threadIdx.x;
    const int tile = blockIdx.x;            // 0..15
    const int bb = blockIdx.y;
    const int c0 = (tile & 3) * 32, d0 = (tile >> 2) * 32;
    const int tc = t & 31, dg = t >> 5;
    float acc[4] = {0.f,0.f,0.f,0.f};
    const size_t base = (size_t)bb * HWn;
    for (int n0 = 0; n0 < HWn; n0 += 64) {
        __syncthreads();
        for (int idx = t; idx < 64*32; idx += 256) {
            const int n = idx >> 5, col = idx & 31;
            Xc[n*33 + col] = feat2[(base + n0 + n)*CI + c0 + col];
            Xd[n*33 + col] = feat2[(base + n0 + n)*CI + d0 + col];
        }
        __syncthreads();
        #pragma unroll 4
        for (int n = 0; n < 64; ++n) {
            const float a = Xc[n*33 + tc];
            #pragma unroll
            for (int i = 0; i < 4; ++i)
                acc[i] = fmaf(a, Xd[n*33 + dg*4 + i], acc[i]);
        }
    }
    const int c = c0 + tc;
    #pragma unroll
    for (int i = 0; i < 4; ++i)
        energy[((size_t)bb*CI + c)*CI + d0 + dg*4 + i] = acc[i];
}

// ---------------- K4b: CAM softmax (max-subtract variant, per row) ----------
__global__ __launch_bounds__(64)
void k_cam_softmax(const float* __restrict__ energy, float* __restrict__ att)
{
    const int lane = threadIdx.x;
    const size_t row = blockIdx.x;
    const float2 e = *(const float2*)&energy[row*CI + lane*2];
    float M = fmaxf(e.x, e.y);
    #pragma unroll
    for (int off = 32; off > 0; off >>= 1) M = fmaxf(M, __shfl_xor(M, off));
    const float en0 = M - e.x, en1 = M - e.y;
    float mx = fmaxf(en0, en1);
    #pragma unroll
    for (int off = 32; off > 0; off >>= 1) mx = fmaxf(mx, __shfl_xor(mx, off));
    const float p0 = __expf(en0 - mx), p1 = __expf(en1 - mx);
    float s = p0 + p1;
    #pragma unroll
    for (int off = 32; off > 0; off >>= 1) s += __shfl_xor(s, off);
    const float inv = 1.f / s;
    float2 o; o.x = p0*inv; o.y = p1*inv;
    *(float2*)&att[row*CI + lane*2] = o;
}

// ---------------- K4c: CAM apply: sc = g*(X att^T) + X ----------------------
__global__ __launch_bounds__(256)
void k_cam_apply(const float* __restrict__ feat2, const float* __restrict__ att,
                 const float* __restrict__ gamma, float* __restrict__ sc_feat)
{
    __shared__ float Xl[64*129];
    __shared__ __align__(16) float aT[128*64];
    const int t = threadIdx.x;
    const int pb = blockIdx.x * 64;
    const int bb = pb / HWn;
    const int ch = blockIdx.y * 64;
    for (int idx = t; idx < 64*128; idx += 256) {
        const int p = idx >> 7, ci = idx & 127;
        Xl[p*129 + ci] = feat2[(size_t)(pb + p)*CI + ci];
    }
    for (int idx = t; idx < 128*64; idx += 256) {
        const int d = idx >> 6, cc = idx & 63;
        aT[d*64 + cc] = att[((size_t)bb*CI + ch + cc)*CI + d];
    }
    __syncthreads();
    const int px = t & 63, cg = t >> 6;
    F8 accA = f8zero(), accB = f8zero();
    #pragma unroll 4
    for (int d = 0; d < 128; ++d) {
        const float xv = Xl[px*129 + d];
        const float* ap = &aT[d*64 + cg*16];
        const float4 a0 = *(const float4*)&ap[0];
        const float4 a1 = *(const float4*)&ap[4];
        const float4 a2 = *(const float4*)&ap[8];
        const float4 a3 = *(const float4*)&ap[12];
        fma8(accA, xv, a0, a1);
        fma8(accB, xv, a2, a3);
    }
    const float g = gamma[0];
    const float* fa = (const float*)&accA;
    const float* fb = (const float*)&accB;
    #pragma unroll
    for (int j = 0; j < 8; ++j) {
        const int cA = ch + cg*16 + j;
        const int cB = cA + 8;
        sc_feat[(size_t)(pb + px)*CI + cA] = g*fa[j] + Xl[px*129 + cA];
        sc_feat[(size_t)(pb + px)*CI + cB] = g*fb[j] + Xl[px*129 + cB];
    }
}

// ---------------- K7: final 1x1 conv (sum of two branches) -> out ------------
__global__ __launch_bounds__(256)
void k_final(const float* __restrict__ sa, const float* __restrict__ sc,
             const float* __restrict__ w8, float* __restrict__ out)
{
    __shared__ float Xl[64*129];
    __shared__ float w8l[128*COn];
    const int t = threadIdx.x;
    const int pb = blockIdx.x * 64;
    for (int idx = t; idx < 64*128; idx += 256) {
        const int p = idx >> 7, ci = idx & 127;
        const size_t gi = (size_t)(pb + p)*CI + ci;
        Xl[p*129 + ci] = sa[gi] + sc[gi];
    }
    for (int idx = t; idx < 128*COn; idx += 256) w8l[idx] = w8[idx];
    __syncthreads();
    for (int idx = t; idx < 64*COn; idx += 256) {
        const int p = idx / COn, co = idx - p*COn;
        float acc = 0.f;
        #pragma unroll 8
        for (int ci = 0; ci < 128; ++ci)
            acc = fmaf(Xl[p*129 + ci], w8l[ci*COn + co], acc);
        out[(size_t)(pb + p)*COn + co] = acc;
    }
}

extern "C" void kernel_launch(void* const* d_in, const int* in_sizes, int n_in,
                              void* d_out, int out_size, void* d_ws, size_t ws_size,
                              hipStream_t stream)
{
    const float* x    = (const float*)d_in[0];
    const float* w5a  = (const float*)d_in[1];
    const float* w5c  = (const float*)d_in[2];
    const float* wq   = (const float*)d_in[3];
    const float* bq   = (const float*)d_in[4];
    const float* wk   = (const float*)d_in[5];
    const float* bk   = (const float*)d_in[6];
    const float* wv   = (const float*)d_in[7];
    const float* bv   = (const float*)d_in[8];
    const float* pgam = (const float*)d_in[9];
    const float* cgam = (const float*)d_in[10];
    const float* w51  = (const float*)d_in[11];
    const float* w52  = (const float*)d_in[12];
    const float* w8   = (const float*)d_in[13];
    const float* bn1g = (const float*)d_in[14];
    const float* bn1b = (const float*)d_in[15];
    const float* bn1m = (const float*)d_in[16];
    const float* bn1v = (const float*)d_in[17];
    const float* bn2g = (const float*)d_in[18];
    const float* bn2b = (const float*)d_in[19];
    const float* bn2m = (const float*)d_in[20];
    const float* bn2v = (const float*)d_in[21];
    const float* bn3g = (const float*)d_in[22];
    const float* bn3b = (const float*)d_in[23];
    const float* bn3m = (const float*)d_in[24];
    const float* bn3v = (const float*)d_in[25];
    const float* bn4g = (const float*)d_in[26];
    const float* bn4b = (const float*)d_in[27];
    const float* bn4m = (const float*)d_in[28];
    const float* bn4v = (const float*)d_in[29];

    char* wsb = (char*)d_ws;
    float* feat1  = (float*)(wsb + 0);          // 8 MB (reused as sa_conv)
    float* feat2  = (float*)(wsb + 8388608);    // 8 MB (reused as sc_conv)
    float* saf    = (float*)(wsb + 16777216);   // 8 MB
    float* scf    = (float*)(wsb + 25165824);   // 8 MB
    float* energy = (float*)(wsb + 33554432);   // 256 KB
    float* att    = (float*)(wsb + 33816576);   // 256 KB
    __hip_bfloat16* qb16 = (__hip_bfloat16*)(wsb + 34078720);  // 512 KB
    __hip_bfloat16* kb16 = (__hip_bfloat16*)(wsb + 34603008);  // 512 KB
    __hip_bfloat16* vbT  = (__hip_bfloat16*)(wsb + 35127296);  // 4 MB -> 39321600
    char* wt1H = wsb + 25165824;                // alias scf (dead until cam_apply)
    char* wt1L = wsb + 27525120;                // 2359296 each -> 29884416
    char* wt2aH = wsb + 39321600;               // 294912 -> 39616512
    char* wt2aL = wsb + 39616512;               // 294912 -> 39911424
    char* wt2bH = wsb + 39911424;               // 294912 -> 40206336
    char* wt2bL = wsb + 40206336;               // 294912 -> 40501248
    float* bnAs = (float*)(wsb + 40501248);     // 1 KB each
    float* bnAb = (float*)(wsb + 40502272);
    float* bnBs = (float*)(wsb + 40503296);
    float* bnBb = (float*)(wsb + 40504320);     // high-water 40505344
    float* sa_conv = feat1;                     // alias: feat1 dead after k_pam
    float* sc_conv = feat2;                     // alias: feat2 dead after cam_apply
    float* out  = (float*)d_out;

    k_prep_w<<<dim3(2880), 256, 0, stream>>>(w5a, w5c, w51, w52,
        wt1H, wt1L, wt2aH, wt2aL, wt2bH, wt2bL);
    k_prep_bn<<<dim3(1), 256, 0, stream>>>(bn1g, bn1b, bn1m, bn1v, bn2g, bn2b, bn2m, bn2v,
                                           bn3g, bn3b, bn3m, bn3v, bn4g, bn4b, bn4m, bn4v,
                                           bnAs, bnAb, bnBs, bnBb);
    k_convm<512, 256><<<dim3(256, 2), 256, 0, stream>>>(x, wt1H, wt1L, bnAs, bnAb, feat1, feat2);
    k_qk<<<dim3(NPIX/64), 256, 0, stream>>>(feat1, wq, bq, wk, bk, qb16, kb16);
    k_v<<<dim3(NPIX/32), 256, 0, stream>>>(feat1, wv, bv, vbT);
    k_pam<<<dim3(NPIX/32), 64, 0, stream>>>(qb16, kb16, vbT, feat1, pgam, saf);
    k_cam_energy<<<dim3(16, Bn), 256, 0, stream>>>(feat2, energy);
    k_cam_softmax<<<dim3(Bn*CI), 64, 0, stream>>>(energy, att);
    k_cam_apply<<<dim3(NPIX/64, 2), 256, 0, stream>>>(feat2, att, cgam, scf);
    k_convm<128, 128><<<dim3(256, 1), 256, 0, stream>>>(saf, wt2aH, wt2aL, bnBs,       bnBb,       sa_conv, nullptr);
    k_convm<128, 128><<<dim3(256, 1), 256, 0, stream>>>(scf, wt2bH, wt2bL, bnBs + 128, bnBb + 128, sc_conv, nullptr);
    k_final<<<dim3(NPIX/64), 256, 0, stream>>>(sa_conv, sc_conv, w8, out);
}

// Round 8
// 465.487 us; speedup vs baseline: 1.4205x; 1.4205x over previous
//
#include <hip/hip_runtime.h>
#include <hip/hip_bf16.h>
#include <math.h>

#define BN_EPS 1e-3f

constexpr int Bn = 4, Hn = 64, Wn = 64, CIN = 512, CI = 128;
constexpr int HWn = Hn * Wn;        // 4096
constexpr int NPIX = Bn * HWn;      // 16384
constexpr int COn = 19;

struct F8 { float4 lo, hi; };

__device__ __forceinline__ F8 f8zero() {
    F8 r; r.lo = make_float4(0.f,0.f,0.f,0.f); r.hi = make_float4(0.f,0.f,0.f,0.f); return r;
}
__device__ __forceinline__ void fma8(F8 &acc, float a, const float4 &wlo, const float4 &whi) {
    acc.lo.x = fmaf(a, wlo.x, acc.lo.x);
    acc.lo.y = fmaf(a, wlo.y, acc.lo.y);
    acc.lo.z = fmaf(a, wlo.z, acc.lo.z);
    acc.lo.w = fmaf(a, wlo.w, acc.lo.w);
    acc.hi.x = fmaf(a, whi.x, acc.hi.x);
    acc.hi.y = fmaf(a, whi.y, acc.hi.y);
    acc.hi.z = fmaf(a, whi.z, acc.hi.z);
    acc.hi.w = fmaf(a, whi.w, acc.hi.w);
}

// ---- MFMA helpers -----------------------------------------------------------
typedef __attribute__((ext_vector_type(8)))  short short8;   // 8 bf16 in 4 VGPRs
typedef __attribute__((ext_vector_type(16))) float f32x16;

__device__ __forceinline__ f32x16 f16z() {
    f32x16 z;
    #pragma unroll
    for (int i = 0; i < 16; ++i) z[i] = 0.f;
    return z;
}
// fp32 -> bf16 (RNE), pure integer ops
__device__ __forceinline__ unsigned f2b(float f) {
    union { float f; unsigned u; } c; c.f = f;
    return (c.u + 0x7FFFu + ((c.u >> 16) & 1u)) >> 16;
}
__device__ __forceinline__ unsigned pack2(float lo, float hi) {
    return (f2b(hi) << 16) | f2b(lo);
}
// split (a,b) into packed bf16 hi words + bf16 lo residuals (a in low half)
__device__ __forceinline__ void split2(float a, float b, unsigned &hi, unsigned &lo) {
    const unsigned ha = f2b(a), hb = f2b(b);
    union { unsigned u; float f; } ua, ub; ua.u = ha << 16; ub.u = hb << 16;
    hi = (hb << 16) | ha;
    lo = pack2(a - ua.f, b - ub.f);
}

// ---------------- prep: weights -> bf16 hi/lo, co-major, LINEAR --------------
__global__ __launch_bounds__(256)
void k_prep_w(const float* __restrict__ w5a, const float* __restrict__ w5c,
              const float* __restrict__ w51, const float* __restrict__ w52,
              char* __restrict__ wt1H, char* __restrict__ wt1L,
              char* __restrict__ wt2aH, char* __restrict__ wt2aL,
              char* __restrict__ wt2bH, char* __restrict__ wt2bL)
{
    int idx = blockIdx.x * 256 + threadIdx.x;
    if (idx < 589824) {                       // 32*9*256*8 pairs
        const int jp = idx & 7, co = (idx >> 3) & 255, ct = idx >> 11; // ct=c*9+tap
        const int tap = ct % 9, c = ct / 9;
        const float* src = (co < 128) ? w5a : w5c;
        const int coc = co & 127;
        const int ci = c*16 + jp*2;
        const float a = src[((size_t)tap*CIN + ci)*CI + coc];
        const float b = src[((size_t)tap*CIN + ci + 1)*CI + coc];
        unsigned hi, lo; split2(a, b, hi, lo);
        const int L = co*32 + jp*4;
        *(unsigned*)(wt1H + (size_t)ct*8192 + L) = hi;
        *(unsigned*)(wt1L + (size_t)ct*8192 + L) = lo;
    } else {
        int k = idx - 589824;                 // 2 * 8*9*128*8 pairs
        if (k >= 147456) return;
        const float* src = (k < 73728) ? w51 : w52;
        char* dstH = (k < 73728) ? wt2aH : wt2bH;
        char* dstL = (k < 73728) ? wt2aL : wt2bL;
        if (k >= 73728) k -= 73728;
        const int jp = k & 7, co = (k >> 3) & 127, ct = k >> 10; // ct=c*9+tap
        const int tap = ct % 9, c = ct / 9;
        const int ci = c*16 + jp*2;
        const float a = src[((size_t)tap*CI + ci)*CI + co];
        const float b = src[((size_t)tap*CI + ci + 1)*CI + co];
        unsigned hi, lo; split2(a, b, hi, lo);
        const int L = co*32 + jp*4;
        *(unsigned*)(dstH + (size_t)ct*4096 + L) = hi;
        *(unsigned*)(dstL + (size_t)ct*4096 + L) = lo;
    }
}

// ---------------- prep: BN -> folded scale/bias tables -----------------------
__global__ __launch_bounds__(256)
void k_prep_bn(const float* g1, const float* b1, const float* m1, const float* v1,
               const float* g2, const float* b2, const float* m2, const float* v2,
               const float* g3, const float* b3, const float* m3, const float* v3,
               const float* g4, const float* b4, const float* m4, const float* v4,
               float* bnAs, float* bnAb, float* bnBs, float* bnBb)
{
    const int t = threadIdx.x, c = t & 127;
    {
        const float *g = (t < 128) ? g1 : g2, *b = (t < 128) ? b1 : b2;
        const float *m = (t < 128) ? m1 : m2, *v = (t < 128) ? v1 : v2;
        const float s = g[c] * rsqrtf(v[c] + BN_EPS);
        bnAs[t] = s; bnAb[t] = b[c] - m[c]*s;
    }
    {
        const float *g = (t < 128) ? g3 : g4, *b = (t < 128) ? b3 : b4;
        const float *m = (t < 128) ? m3 : m4, *v = (t < 128) ? v3 : v4;
        const float s = g[c] * rsqrtf(v[c] + BN_EPS);
        bnBs[t] = s; bnBb[t] = b[c] - m[c]*s;
    }
}

// ---------------- MFMA 3x3 conv, bf16x3 split + folded BN + ReLU -------------
template<int CICH, int NCO>
__global__ __launch_bounds__(256)
void k_convm(const float* __restrict__ xin,
             const char* __restrict__ wtH, const char* __restrict__ wtL,
             const float* __restrict__ bnS, const float* __restrict__ bnBi,
             float* __restrict__ out0, float* __restrict__ out1)
{
    constexpr int NCHNK = CICH / 16;
    constexpr int XPAGE = 66 * 32;            // 2112 B per staged row
    __shared__ __align__(16) char Xs[6*XPAGE];
    char* Xh = Xs;
    char* Xl = Xs + 3*XPAGE;

    const int t   = threadIdx.x;
    const int row = blockIdx.x;               // 0..255 = b*64 + h
    const int cg  = blockIdx.y;               // co half (conv1: 0/1)
    const int bb  = row >> 6, hh = row & 63;
    const int dyLo = (hh == 0)  ? 1 : 0;
    const int dyHi = (hh == 63) ? 1 : 2;
    const int l = t & 63, w = t >> 6;
    const int lo5 = l & 31, hf = l >> 5;
    const int cobase = cg*128 + w*32 + lo5;   // this lane's co row in wt pages

    f32x16 acc[2];
    acc[0] = f16z(); acc[1] = f16z();

    float4 xr[4];
    // ---- prefetch chunk 0 ----
    #pragma unroll
    for (int i = 0; i < 4; ++i) {
        const int u = t + i*256;
        float4 v = make_float4(0.f,0.f,0.f,0.f);
        if (u < 792) {
            const int dyr = u/264, rs = u - dyr*264;
            const int s = rs >> 2, u4 = rs & 3;
            if (dyr >= dyLo && dyr <= dyHi && s >= 1 && s <= 64)
                v = *(const float4*)&xin[
                    (((size_t)bb*Hn + (hh + dyr - 1))*Wn + (s - 1))*CICH + u4*4];
        }
        xr[i] = v;
    }

    for (int c = 0; c < NCHNK; ++c) {
        __syncthreads();                      // previous chunk's reads done
        // ---- write staged X (hi/lo, swizzled) ----
        #pragma unroll
        for (int i = 0; i < 4; ++i) {
            const int u = t + i*256;
            if (u < 792) {
                const int dyr = u/264, rs = u - dyr*264;
                const int s = rs >> 2, u4 = rs & 3;
                if (dyr >= dyLo && dyr <= dyHi) {
                    uint2 vh, vl;
                    split2(xr[i].x, xr[i].y, vh.x, vl.x);
                    split2(xr[i].z, xr[i].w, vh.y, vl.y);
                    const int off = dyr*XPAGE + ((s*32 + u4*8) ^ ((s & 7) << 4));
                    *(uint2*)(Xh + off) = vh;
                    *(uint2*)(Xl + off) = vl;
                }
            }
        }
        __syncthreads();
        // ---- prefetch chunk c+1 (hides under MFMA phase) ----
        if (c + 1 < NCHNK) {
            #pragma unroll
            for (int i = 0; i < 4; ++i) {
                const int u = t + i*256;
                float4 v = make_float4(0.f,0.f,0.f,0.f);
                if (u < 792) {
                    const int dyr = u/264, rs = u - dyr*264;
                    const int s = rs >> 2, u4 = rs & 3;
                    if (dyr >= dyLo && dyr <= dyHi && s >= 1 && s <= 64)
                        v = *(const float4*)&xin[
                            (((size_t)bb*Hn + (hh + dyr - 1))*Wn + (s - 1))*CICH
                            + (c + 1)*16 + u4*4];
                }
                xr[i] = v;
            }
        }
        // ---- compute: 9 taps, W straight from global (L2) ----
        #pragma unroll
        for (int dy = 0; dy < 3; ++dy) {
            if (dy < dyLo || dy > dyHi) continue;   // block-uniform
            const char* Xph = Xh + dy*XPAGE;
            const char* Xpl = Xl + dy*XPAGE;
            #pragma unroll
            for (int dx = 0; dx < 3; ++dx) {
                short8 xfh[2], xfl[2];
                #pragma unroll
                for (int mi = 0; mi < 2; ++mi) {
                    const int s = mi*32 + lo5 + dx;
                    const int xo = (s*32 + hf*16) ^ ((s & 7) << 4);
                    xfh[mi] = *(const short8*)(Xph + xo);
                    xfl[mi] = *(const short8*)(Xpl + xo);
                }
                const size_t wo = ((size_t)(c*9 + dy*3 + dx)*NCO + cobase)*32 + hf*16;
                const short8 wfh = *(const short8*)(wtH + wo);
                const short8 wfl = *(const short8*)(wtL + wo);
                #pragma unroll
                for (int mi = 0; mi < 2; ++mi) {
                    acc[mi] = __builtin_amdgcn_mfma_f32_32x32x16_bf16(wfh, xfh[mi], acc[mi], 0, 0, 0);
                    acc[mi] = __builtin_amdgcn_mfma_f32_32x32x16_bf16(wfh, xfl[mi], acc[mi], 0, 0, 0);
                    acc[mi] = __builtin_amdgcn_mfma_f32_32x32x16_bf16(wfl, xfh[mi], acc[mi], 0, 0, 0);
                }
            }
        }
    }
    // ---- epilogue: folded BN + ReLU ----
    float* dst = (cg == 0) ? out0 : out1;
    #pragma unroll
    for (int mi = 0; mi < 2; ++mi) {
        const int px = mi*32 + lo5;
        const size_t p = (size_t)row*Wn + px;
        #pragma unroll
        for (int r = 0; r < 16; ++r) {
            const int crow = (r & 3) + 8*(r >> 2) + 4*hf;
            const int och = w*32 + crow;
            const int bnidx = cg*128 + och;
            dst[p*CI + och] = fmaxf(fmaf(acc[mi][r], bnS[bnidx], bnBi[bnidx]), 0.f);
        }
    }
}

// ---------------- K2a: q,k 1x1 conv -> bf16 [NPIX][16] each ------------------
__global__ __launch_bounds__(256)
void k_qk(const float* __restrict__ feat1,
          const float* __restrict__ wq, const float* __restrict__ bq,
          const float* __restrict__ wk, const float* __restrict__ bk,
          __hip_bfloat16* __restrict__ qb, __hip_bfloat16* __restrict__ kb)
{
    __shared__ float Al[64*129];
    __shared__ __align__(16) float Wl[128*32];
    const int t = threadIdx.x;
    const int pb = blockIdx.x * 64;
    for (int idx = t; idx < 64*128; idx += 256) {
        const int p = idx >> 7, ci = idx & 127;
        Al[p*129 + ci] = feat1[(size_t)(pb + p)*CI + ci];
    }
    for (int idx = t; idx < 128*32; idx += 256) {
        const int ci = idx >> 5, c = idx & 31;
        Wl[idx] = (c < 16) ? wq[ci*16 + c] : wk[ci*16 + (c - 16)];
    }
    __syncthreads();
    const int p = t & 63, cg = t >> 6, co = cg * 8;
    F8 acc = f8zero();
    #pragma unroll 8
    for (int ci = 0; ci < 128; ++ci) {
        const float a = Al[p*129 + ci];
        const float4 wlo = *(const float4*)&Wl[ci*32 + co];
        const float4 whi = *(const float4*)&Wl[ci*32 + co + 4];
        fma8(acc, a, wlo, whi);
    }
    const float* af = (const float*)&acc;
    #pragma unroll
    for (int j = 0; j < 8; ++j) {
        const int c = co + j;
        if (c < 16) qb[(size_t)(pb + p)*16 + c]        = __float2bfloat16(af[j] + bq[c]);
        else        kb[(size_t)(pb + p)*16 + (c - 16)] = __float2bfloat16(af[j] + bk[c - 16]);
    }
}

// ---------------- K2b: v 1x1 conv -> bf16 TRANSPOSED [b][c][pix] -------------
__global__ __launch_bounds__(256)
void k_v(const float* __restrict__ feat1, const float* __restrict__ wv,
         const float* __restrict__ bv, __hip_bfloat16* __restrict__ vbT)
{
    __shared__ float Al[32*129];
    __shared__ __align__(16) float Wl[64*128];
    const int t = threadIdx.x;
    const int pb = blockIdx.x * 32;
    for (int idx = t; idx < 32*128; idx += 256) {
        const int p = idx >> 7, ci = idx & 127;
        Al[p*129 + ci] = feat1[(size_t)(pb + p)*CI + ci];
    }
    const int px = t & 15, co = (t >> 4) * 8;
    F8 acc0 = f8zero(), acc1 = f8zero();
    for (int ch = 0; ch < 2; ++ch) {
        __syncthreads();
        #pragma unroll
        for (int r = 0; r < 8; ++r) {
            const int i4 = t + r*256;
            const int kk = i4 >> 5, c4 = (i4 & 31) * 4;
            *(float4*)&Wl[kk*128 + c4] = *(const float4*)&wv[(size_t)(ch*64 + kk)*CI + c4];
        }
        __syncthreads();
        #pragma unroll 4
        for (int kk = 0; kk < 64; ++kk) {
            const float a0 = Al[px*129 + ch*64 + kk];
            const float a1 = Al[(px+16)*129 + ch*64 + kk];
            const float4 wlo = *(const float4*)&Wl[kk*128 + co];
            const float4 whi = *(const float4*)&Wl[kk*128 + co + 4];
            fma8(acc0, a0, wlo, whi);
            fma8(acc1, a1, wlo, whi);
        }
    }
    const int p0 = pb + px;
    const int bb = p0 / HWn, pin0 = p0 % HWn;
    const float* a0f = (const float*)&acc0;
    const float* a1f = (const float*)&acc1;
    #pragma unroll
    for (int j = 0; j < 8; ++j) {
        const int c = co + j;
        const size_t rowb = ((size_t)bb*CI + c) * HWn;
        vbT[rowb + pin0]      = __float2bfloat16(a0f[j] + bv[c]);
        vbT[rowb + pin0 + 16] = __float2bfloat16(a1f[j] + bv[c]);
    }
}

// ---------------- K3: PAM flash attention via MFMA ---------------------------
__global__ __launch_bounds__(64)
void k_pam(const __hip_bfloat16* __restrict__ qb, const __hip_bfloat16* __restrict__ kb,
           const __hip_bfloat16* __restrict__ vbT, const float* __restrict__ feat1,
           const float* __restrict__ gamma, float* __restrict__ saf)
{
    __shared__ unsigned Ppk[32*32];   // [key-pair 0..31][q 0..31], bf16x2 packed
    const int l   = threadIdx.x;
    const int lo5 = l & 31, h = l >> 5;
    const int q0  = blockIdx.x * 32;
    const int bb  = q0 / HWn;
    const size_t jb = (size_t)bb * HWn;
    const __hip_bfloat16* vbB = vbT + (size_t)bb * CI * HWn;

    const short8 qfrag = *(const short8*)&qb[(size_t)(q0 + lo5)*16 + 8*h];
    const f32x16 zro = f16z();

    f32x16 o[4];
    #pragma unroll
    for (int cb = 0; cb < 4; ++cb) o[cb] = f16z();

    float m_run = -1e30f, s_run = 0.f;

    for (int k0 = 0; k0 < HWn; k0 += 64) {
        const short8 kf0 = *(const short8*)&kb[(jb + k0 +      lo5)*16 + 8*h];
        const short8 kf1 = *(const short8*)&kb[(jb + k0 + 32 + lo5)*16 + 8*h];
        short8 vf[4][4];
        #pragma unroll
        for (int s = 0; s < 4; ++s)
            #pragma unroll
            for (int cb = 0; cb < 4; ++cb)
                vf[s][cb] = *(const short8*)&vbB[((size_t)(cb*32 + lo5))*HWn + k0 + s*16 + 8*h];

        f32x16 e0 = __builtin_amdgcn_mfma_f32_32x32x16_bf16(kf0, qfrag, zro, 0, 0, 0);
        f32x16 e1 = __builtin_amdgcn_mfma_f32_32x32x16_bf16(kf1, qfrag, zro, 0, 0, 0);

        float mt = fmaxf(e0[0], e1[0]);
        #pragma unroll
        for (int r = 1; r < 16; ++r) mt = fmaxf(mt, fmaxf(e0[r], e1[r]));
        mt = fmaxf(mt, __shfl_xor(mt, 32));

        if (__any(mt > m_run + 8.f)) {
            const float mnew = fmaxf(m_run, mt);
            const float sc = __expf(m_run - mnew);
            s_run *= sc;
            #pragma unroll
            for (int cb = 0; cb < 4; ++cb)
                #pragma unroll
                for (int r = 0; r < 16; ++r) o[cb][r] *= sc;
            m_run = mnew;
        }

        #pragma unroll
        for (int r = 0; r < 16; ++r) {
            e0[r] = __expf(e0[r] - m_run);
            e1[r] = __expf(e1[r] - m_run);
        }
        float ss = 0.f;
        #pragma unroll
        for (int r = 0; r < 16; ++r) ss += e0[r] + e1[r];
        s_run += ss;

        #pragma unroll
        for (int r = 0; r < 16; r += 2) {
            const int pidx = ((r & 3) >> 1) + 4*(r >> 2) + 2*h;
            Ppk[pidx*32 + lo5]        = pack2(e0[r], e0[r+1]);
            Ppk[(16 + pidx)*32 + lo5] = pack2(e1[r], e1[r+1]);
        }
        #pragma unroll
        for (int s = 0; s < 4; ++s) {
            union { unsigned u[4]; short8 s8; } P;
            #pragma unroll
            for (int w = 0; w < 4; ++w)
                P.u[w] = Ppk[(s*8 + 4*h + w)*32 + lo5];
            #pragma unroll
            for (int cb = 0; cb < 4; ++cb)
                o[cb] = __builtin_amdgcn_mfma_f32_32x32x16_bf16(vf[s][cb], P.s8, o[cb], 0, 0, 0);
        }
    }

    const float s_tot = s_run + __shfl_xor(s_run, 32);
    const float inv = 1.f / s_tot;
    const float g = gamma[0];
    const size_t q = (size_t)q0 + lo5;
    #pragma unroll
    for (int cb = 0; cb < 4; ++cb)
        #pragma unroll
        for (int r = 0; r < 16; ++r) {
            const int c = cb*32 + (r & 3) + 8*(r >> 2) + 4*h;
            const size_t idx = q*CI + c;
            saf[idx] = g*(o[cb][r]*inv) + feat1[idx];
        }
}

// ---------------- K4x: transpose feat2 -> bf16 hi/lo [b][c][HW] --------------
__global__ __launch_bounds__(256)
void k_xpose(const float* __restrict__ feat2,
             char* __restrict__ f2TH, char* __restrict__ f2TL)
{
    __shared__ float Xl[64*129];
    const int t = threadIdx.x;
    const int pb = blockIdx.x * 64;
    const int bb = pb / HWn, pin = pb % HWn;
    for (int idx = t; idx < 64*128; idx += 256) {
        const int p = idx >> 7, ci = idx & 127;
        Xl[p*129 + ci] = feat2[(size_t)(pb + p)*CI + ci];
    }
    __syncthreads();
    const int c = t >> 1, half = t & 1;
    const size_t rowb = ((size_t)(bb*CI + c)*HWn + pin + half*32) * 2;
    #pragma unroll
    for (int j = 0; j < 16; ++j) {
        const float a = Xl[(half*32 + 2*j)*129 + c];
        const float b = Xl[(half*32 + 2*j + 1)*129 + c];
        unsigned hi, lo; split2(a, b, hi, lo);
        *(unsigned*)(f2TH + rowb + 4*j) = hi;
        *(unsigned*)(f2TL + rowb + 4*j) = lo;
    }
}

// ---------------- K4a: CAM energy via MFMA, split-K partials -----------------
// grid (32 kslices, Bn), 256 thr / 4 waves. Slice = 128 px of HW. LDS holds
// the slice channel-major [128 c][128 k] bf16 hi/lo (64 KB), granule-swizzled
// (g ^= c&15 on 16B granules -> 2-way bank aliasing = free). Wave w = c-tile
// w, computing all 4 d-tiles. bf16x3: ah*bh + al*bh + ah*bl (~fp32 logits).
// mfma(A=c-rows, B=d-rows) -> D[row=c][col=d] (k_pam-validated map).
__global__ __launch_bounds__(256)
void k_cam_energy_m(const char* __restrict__ f2TH, const char* __restrict__ f2TL,
                    float* __restrict__ epart)
{
    __shared__ __align__(16) char Vh[128*256];
    __shared__ __align__(16) char Vl[128*256];
    const int t = threadIdx.x;
    const int ks = blockIdx.x, bb = blockIdx.y;
    const int l = t & 63, w = t >> 6;
    const int lo5 = l & 31, hf = l >> 5;

    #pragma unroll
    for (int pass = 0; pass < 8; ++pass) {
        const int slot = pass*256 + t;          // 0..2047
        const int c = slot >> 4, g = slot & 15; // 16B granule
        const size_t gaddr = ((size_t)(bb*CI + c)*HWn + ks*128)*2 + g*16;
        const int laddr = c*256 + ((g*16) ^ ((c & 15) << 4));
        *(float4*)(Vh + laddr) = *(const float4*)(f2TH + gaddr);
        *(float4*)(Vl + laddr) = *(const float4*)(f2TL + gaddr);
    }
    __syncthreads();

    f32x16 acc[4];
    #pragma unroll
    for (int nj = 0; nj < 4; ++nj) acc[nj] = f16z();
    const int cA = w*32 + lo5;
    const int swA = (cA & 15) << 4;

    #pragma unroll
    for (int kk = 0; kk < 8; ++kk) {
        const int kb = kk*32 + hf*16;
        const short8 ah = *(const short8*)(Vh + cA*256 + (kb ^ swA));
        const short8 al = *(const short8*)(Vl + cA*256 + (kb ^ swA));
        #pragma unroll
        for (int nj = 0; nj < 4; ++nj) {
            const int dB = nj*32 + lo5;
            const int swB = (dB & 15) << 4;
            const short8 bh = *(const short8*)(Vh + dB*256 + (kb ^ swB));
            const short8 bl = *(const short8*)(Vl + dB*256 + (kb ^ swB));
            acc[nj] = __builtin_amdgcn_mfma_f32_32x32x16_bf16(ah, bh, acc[nj], 0, 0, 0);
            acc[nj] = __builtin_amdgcn_mfma_f32_32x32x16_bf16(al, bh, acc[nj], 0, 0, 0);
            acc[nj] = __builtin_amdgcn_mfma_f32_32x32x16_bf16(ah, bl, acc[nj], 0, 0, 0);
        }
    }
    float* ep = epart + ((size_t)(bb*32 + ks)*CI)*CI;
    #pragma unroll
    for (int nj = 0; nj < 4; ++nj)
        #pragma unroll
        for (int r = 0; r < 16; ++r) {
            const int c = w*32 + (r & 3) + 8*(r >> 2) + 4*hf;
            ep[(size_t)c*CI + nj*32 + lo5] = acc[nj][r];
        }
}

// ---------------- K4b: fused reduce(32 partials) + max-subtract softmax ------
__global__ __launch_bounds__(64)
void k_cam_rs(const float* __restrict__ epart, float* __restrict__ att)
{
    const int lane = threadIdx.x;
    const int row = blockIdx.x;             // b*128 + c
    const int bb = row >> 7, c = row & 127;
    float2 e = make_float2(0.f, 0.f);
    for (int ks = 0; ks < 32; ++ks) {
        const float2 v = *(const float2*)&epart[
            ((size_t)(bb*32 + ks)*CI + c)*CI + lane*2];
        e.x += v.x; e.y += v.y;
    }
    float M = fmaxf(e.x, e.y);
    #pragma unroll
    for (int off = 32; off > 0; off >>= 1) M = fmaxf(M, __shfl_xor(M, off));
    const float en0 = M - e.x, en1 = M - e.y;
    float mx = fmaxf(en0, en1);
    #pragma unroll
    for (int off = 32; off > 0; off >>= 1) mx = fmaxf(mx, __shfl_xor(mx, off));
    const float p0 = __expf(en0 - mx), p1 = __expf(en1 - mx);
    float s = p0 + p1;
    #pragma unroll
    for (int off = 32; off > 0; off >>= 1) s += __shfl_xor(s, off);
    const float inv = 1.f / s;
    float2 o; o.x = p0*inv; o.y = p1*inv;
    *(float2*)&att[(size_t)row*CI + lane*2] = o;
}

// ---------------- K4c: CAM apply: sc = g*(X att^T) + X ----------------------
__global__ __launch_bounds__(256)
void k_cam_apply(const float* __restrict__ feat2, const float* __restrict__ att,
                 const float* __restrict__ gamma, float* __restrict__ sc_feat)
{
    __shared__ float Xl[64*129];
    __shared__ __align__(16) float aT[128*64];
    const int t = threadIdx.x;
    const int pb = blockIdx.x * 64;
    const int bb = pb / HWn;
    const int ch = blockIdx.y * 64;
    for (int idx = t; idx < 64*128; idx += 256) {
        const int p = idx >> 7, ci = idx & 127;
        Xl[p*129 + ci] = feat2[(size_t)(pb + p)*CI + ci];
    }
    for (int idx = t; idx < 128*64; idx += 256) {
        const int d = idx >> 6, cc = idx & 63;
        aT[d*64 + cc] = att[((size_t)bb*CI + ch + cc)*CI + d];
    }
    __syncthreads();
    const int px = t & 63, cg = t >> 6;
    F8 accA = f8zero(), accB = f8zero();
    #pragma unroll 4
    for (int d = 0; d < 128; ++d) {
        const float xv = Xl[px*129 + d];
        const float* ap = &aT[d*64 + cg*16];
        const float4 a0 = *(const float4*)&ap[0];
        const float4 a1 = *(const float4*)&ap[4];
        const float4 a2 = *(const float4*)&ap[8];
        const float4 a3 = *(const float4*)&ap[12];
        fma8(accA, xv, a0, a1);
        fma8(accB, xv, a2, a3);
    }
    const float g = gamma[0];
    const float* fa = (const float*)&accA;
    const float* fb = (const float*)&accB;
    #pragma unroll
    for (int j = 0; j < 8; ++j) {
        const int cA = ch + cg*16 + j;
        const int cB = cA + 8;
        sc_feat[(size_t)(pb + px)*CI + cA] = g*fa[j] + Xl[px*129 + cA];
        sc_feat[(size_t)(pb + px)*CI + cB] = g*fb[j] + Xl[px*129 + cB];
    }
}

// ---------------- K7: final 1x1 conv (sum of two branches) -> out ------------
__global__ __launch_bounds__(256)
void k_final(const float* __restrict__ sa, const float* __restrict__ sc,
             const float* __restrict__ w8, float* __restrict__ out)
{
    __shared__ float Xl[64*129];
    __shared__ float w8l[128*COn];
    const int t = threadIdx.x;
    const int pb = blockIdx.x * 64;
    for (int idx = t; idx < 64*128; idx += 256) {
        const int p = idx >> 7, ci = idx & 127;
        const size_t gi = (size_t)(pb + p)*CI + ci;
        Xl[p*129 + ci] = sa[gi] + sc[gi];
    }
    for (int idx = t; idx < 128*COn; idx += 256) w8l[idx] = w8[idx];
    __syncthreads();
    for (int idx = t; idx < 64*COn; idx += 256) {
        const int p = idx / COn, co = idx - p*COn;
        float acc = 0.f;
        #pragma unroll 8
        for (int ci = 0; ci < 128; ++ci)
            acc = fmaf(Xl[p*129 + ci], w8l[ci*COn + co], acc);
        out[(size_t)(pb + p)*COn + co] = acc;
    }
}

extern "C" void kernel_launch(void* const* d_in, const int* in_sizes, int n_in,
                              void* d_out, int out_size, void* d_ws, size_t ws_size,
                              hipStream_t stream)
{
    const float* x    = (const float*)d_in[0];
    const float* w5a  = (const float*)d_in[1];
    const float* w5c  = (const float*)d_in[2];
    const float* wq   = (const float*)d_in[3];
    const float* bq   = (const float*)d_in[4];
    const float* wk   = (const float*)d_in[5];
    const float* bk   = (const float*)d_in[6];
    const float* wv   = (const float*)d_in[7];
    const float* bv   = (const float*)d_in[8];
    const float* pgam = (const float*)d_in[9];
    const float* cgam = (const float*)d_in[10];
    const float* w51  = (const float*)d_in[11];
    const float* w52  = (const float*)d_in[12];
    const float* w8   = (const float*)d_in[13];
    const float* bn1g = (const float*)d_in[14];
    const float* bn1b = (const float*)d_in[15];
    const float* bn1m = (const float*)d_in[16];
    const float* bn1v = (const float*)d_in[17];
    const float* bn2g = (const float*)d_in[18];
    const float* bn2b = (const float*)d_in[19];
    const float* bn2m = (const float*)d_in[20];
    const float* bn2v = (const float*)d_in[21];
    const float* bn3g = (const float*)d_in[22];
    const float* bn3b = (const float*)d_in[23];
    const float* bn3m = (const float*)d_in[24];
    const float* bn3v = (const float*)d_in[25];
    const float* bn4g = (const float*)d_in[26];
    const float* bn4b = (const float*)d_in[27];
    const float* bn4m = (const float*)d_in[28];
    const float* bn4v = (const float*)d_in[29];

    char* wsb = (char*)d_ws;
    // region [0, 8MB): feat1 (conv1->pam) -> f2TH/f2TL (xpose->energy) -> sa_conv
    float* feat1  = (float*)(wsb + 0);
    char*  f2TH   = wsb + 0;                    // 4 MB
    char*  f2TL   = wsb + 4194304;              // 4 MB
    float* feat2  = (float*)(wsb + 8388608);    // 8 MB (reused as sc_conv)
    float* saf    = (float*)(wsb + 16777216);   // 8 MB
    // region [24MB..32MB): wt1 planes (prep->conv1) -> epart (energy->rs) -> scf
    float* scf    = (float*)(wsb + 25165824);   // 8 MB
    char*  wt1H   = wsb + 25165824;             // 2359296
    char*  wt1L   = wsb + 27525120;             // 2359296 -> 29884416
    float* epart  = (float*)(wsb + 25165824);   // 8 MB (32 slices x 64KB x 4 b)
    float* att    = (float*)(wsb + 33816576);   // 256 KB
    __hip_bfloat16* qb16 = (__hip_bfloat16*)(wsb + 34078720);  // 512 KB
    __hip_bfloat16* kb16 = (__hip_bfloat16*)(wsb + 34603008);  // 512 KB
    __hip_bfloat16* vbT  = (__hip_bfloat16*)(wsb + 35127296);  // 4 MB -> 39321600
    char* wt2aH = wsb + 39321600;               // 294912 -> 39616512
    char* wt2aL = wsb + 39616512;               // 294912 -> 39911424
    char* wt2bH = wsb + 39911424;               // 294912 -> 40206336
    char* wt2bL = wsb + 40206336;               // 294912 -> 40501248
    float* bnAs = (float*)(wsb + 40501248);     // 1 KB each
    float* bnAb = (float*)(wsb + 40502272);
    float* bnBs = (float*)(wsb + 40503296);
    float* bnBb = (float*)(wsb + 40504320);     // high-water 40505344
    float* sa_conv = feat1;                     // feat1/f2T dead after energy
    float* sc_conv = feat2;                     // feat2 dead after cam_apply
    float* out  = (float*)d_out;

    k_prep_w<<<dim3(2880), 256, 0, stream>>>(w5a, w5c, w51, w52,
        wt1H, wt1L, wt2aH, wt2aL, wt2bH, wt2bL);
    k_prep_bn<<<dim3(1), 256, 0, stream>>>(bn1g, bn1b, bn1m, bn1v, bn2g, bn2b, bn2m, bn2v,
                                           bn3g, bn3b, bn3m, bn3v, bn4g, bn4b, bn4m, bn4v,
                                           bnAs, bnAb, bnBs, bnBb);
    k_convm<512, 256><<<dim3(256, 2), 256, 0, stream>>>(x, wt1H, wt1L, bnAs, bnAb, feat1, feat2);
    k_qk<<<dim3(NPIX/64), 256, 0, stream>>>(feat1, wq, bq, wk, bk, qb16, kb16);
    k_v<<<dim3(NPIX/32), 256, 0, stream>>>(feat1, wv, bv, vbT);
    k_pam<<<dim3(NPIX/32), 64, 0, stream>>>(qb16, kb16, vbT, feat1, pgam, saf);
    k_xpose<<<dim3(NPIX/64), 256, 0, stream>>>(feat2, f2TH, f2TL);
    k_cam_energy_m<<<dim3(32, Bn), 256, 0, stream>>>(f2TH, f2TL, epart);
    k_cam_rs<<<dim3(Bn*CI), 64, 0, stream>>>(epart, att);
    k_cam_apply<<<dim3(NPIX/64, 2), 256, 0, stream>>>(feat2, att, cgam, scf);
    k_convm<128, 128><<<dim3(256, 1), 256, 0, stream>>>(saf, wt2aH, wt2aL, bnBs,       bnBb,       sa_conv, nullptr);
    k_convm<128, 128><<<dim3(256, 1), 256, 0, stream>>>(scf, wt2bH, wt2bL, bnBs + 128, bnBb + 128, sc_conv, nullptr);
    k_final<<<dim3(NPIX/64), 256, 0, stream>>>(sa_conv, sc_conv, w8, out);
}

// Round 9
// 364.012 us; speedup vs baseline: 1.8165x; 1.2788x over previous
//
#include <hip/hip_runtime.h>
#include <hip/hip_bf16.h>
#include <math.h>

#define BN_EPS 1e-3f

constexpr int Bn = 4, Hn = 64, Wn = 64, CIN = 512, CI = 128;
constexpr int HWn = Hn * Wn;        // 4096
constexpr int NPIX = Bn * HWn;      // 16384
constexpr int COn = 19;

struct F8 { float4 lo, hi; };

__device__ __forceinline__ F8 f8zero() {
    F8 r; r.lo = make_float4(0.f,0.f,0.f,0.f); r.hi = make_float4(0.f,0.f,0.f,0.f); return r;
}
__device__ __forceinline__ void fma8(F8 &acc, float a, const float4 &wlo, const float4 &whi) {
    acc.lo.x = fmaf(a, wlo.x, acc.lo.x);
    acc.lo.y = fmaf(a, wlo.y, acc.lo.y);
    acc.lo.z = fmaf(a, wlo.z, acc.lo.z);
    acc.lo.w = fmaf(a, wlo.w, acc.lo.w);
    acc.hi.x = fmaf(a, whi.x, acc.hi.x);
    acc.hi.y = fmaf(a, whi.y, acc.hi.y);
    acc.hi.z = fmaf(a, whi.z, acc.hi.z);
    acc.hi.w = fmaf(a, whi.w, acc.hi.w);
}

// ---- MFMA helpers -----------------------------------------------------------
typedef __attribute__((ext_vector_type(8)))  short short8;   // 8 bf16 in 4 VGPRs
typedef __attribute__((ext_vector_type(16))) float f32x16;

__device__ __forceinline__ f32x16 f16z() {
    f32x16 z;
    #pragma unroll
    for (int i = 0; i < 16; ++i) z[i] = 0.f;
    return z;
}
// fp32 -> bf16 (RNE), pure integer ops
__device__ __forceinline__ unsigned f2b(float f) {
    union { float f; unsigned u; } c; c.f = f;
    return (c.u + 0x7FFFu + ((c.u >> 16) & 1u)) >> 16;
}
__device__ __forceinline__ unsigned pack2(float lo, float hi) {
    return (f2b(hi) << 16) | f2b(lo);
}
// split (a,b) into packed bf16 hi words + bf16 lo residuals (a in low half)
__device__ __forceinline__ void split2(float a, float b, unsigned &hi, unsigned &lo) {
    const unsigned ha = f2b(a), hb = f2b(b);
    union { unsigned u; float f; } ua, ub; ua.u = ha << 16; ub.u = hb << 16;
    hi = (hb << 16) | ha;
    lo = pack2(a - ua.f, b - ub.f);
}

// ---------------- prep: weights -> bf16 hi/lo, co-major, LINEAR --------------
__global__ __launch_bounds__(256)
void k_prep_w(const float* __restrict__ w5a, const float* __restrict__ w5c,
              const float* __restrict__ w51, const float* __restrict__ w52,
              char* __restrict__ wt1H, char* __restrict__ wt1L,
              char* __restrict__ wt2aH, char* __restrict__ wt2aL,
              char* __restrict__ wt2bH, char* __restrict__ wt2bL)
{
    int idx = blockIdx.x * 256 + threadIdx.x;
    if (idx < 589824) {                       // 32*9*256*8 pairs
        const int jp = idx & 7, co = (idx >> 3) & 255, ct = idx >> 11; // ct=c*9+tap
        const int tap = ct % 9, c = ct / 9;
        const float* src = (co < 128) ? w5a : w5c;
        const int coc = co & 127;
        const int ci = c*16 + jp*2;
        const float a = src[((size_t)tap*CIN + ci)*CI + coc];
        const float b = src[((size_t)tap*CIN + ci + 1)*CI + coc];
        unsigned hi, lo; split2(a, b, hi, lo);
        const int L = co*32 + jp*4;
        *(unsigned*)(wt1H + (size_t)ct*8192 + L) = hi;
        *(unsigned*)(wt1L + (size_t)ct*8192 + L) = lo;
    } else {
        int k = idx - 589824;                 // 2 * 8*9*128*8 pairs
        if (k >= 147456) return;
        const float* src = (k < 73728) ? w51 : w52;
        char* dstH = (k < 73728) ? wt2aH : wt2bH;
        char* dstL = (k < 73728) ? wt2aL : wt2bL;
        if (k >= 73728) k -= 73728;
        const int jp = k & 7, co = (k >> 3) & 127, ct = k >> 10; // ct=c*9+tap
        const int tap = ct % 9, c = ct / 9;
        const int ci = c*16 + jp*2;
        const float a = src[((size_t)tap*CI + ci)*CI + co];
        const float b = src[((size_t)tap*CI + ci + 1)*CI + co];
        unsigned hi, lo; split2(a, b, hi, lo);
        const int L = co*32 + jp*4;
        *(unsigned*)(dstH + (size_t)ct*4096 + L) = hi;
        *(unsigned*)(dstL + (size_t)ct*4096 + L) = lo;
    }
}

// ---------------- prep: BN -> folded scale/bias tables -----------------------
__global__ __launch_bounds__(256)
void k_prep_bn(const float* g1, const float* b1, const float* m1, const float* v1,
               const float* g2, const float* b2, const float* m2, const float* v2,
               const float* g3, const float* b3, const float* m3, const float* v3,
               const float* g4, const float* b4, const float* m4, const float* v4,
               float* bnAs, float* bnAb, float* bnBs, float* bnBb)
{
    const int t = threadIdx.x, c = t & 127;
    {
        const float *g = (t < 128) ? g1 : g2, *b = (t < 128) ? b1 : b2;
        const float *m = (t < 128) ? m1 : m2, *v = (t < 128) ? v1 : v2;
        const float s = g[c] * rsqrtf(v[c] + BN_EPS);
        bnAs[t] = s; bnAb[t] = b[c] - m[c]*s;
    }
    {
        const float *g = (t < 128) ? g3 : g4, *b = (t < 128) ? b3 : b4;
        const float *m = (t < 128) ? m3 : m4, *v = (t < 128) ? v3 : v4;
        const float s = g[c] * rsqrtf(v[c] + BN_EPS);
        bnBs[t] = s; bnBb[t] = b[c] - m[c]*s;
    }
}

// ---------------- MFMA 3x3 conv, bf16x3 split + folded BN + ReLU -------------
// Linear grid 512: xcd=wgid&7, sel=xcd>>2 (co-half for conv1 / branch for
// conv2), row=(wgid>>3)*4+(xcd&3). Each XCD sees one sel -> W working set
// fits its private L2. Block = one row (64 px) x 128 co, 4 waves; wave =
// 1 M-tile (px half, w>>1) x 2 N-tiles (w&1 -> 64 co), acc 2x f32x16.
// W: global->VGPR, double-buffered per dy-group (12 loads issued at chunk
// top, pre-barrier: the barrier's vmcnt drain absorbs the latency). X: LDS
// bf16 hi/lo, XOR swizzle, xr register prefetch one chunk ahead.
// 3-term product: xh*wh + xl*wh + xh*wl (~fp32 accurate).
// mfma(A=W^T[co][k], B=X[px][k]) -> D[col=px][row=co]  (k_pam-validated map)
template<int CICH, int NCOTOT, int WCOBASE>
__global__ __launch_bounds__(256)
void k_conv(const float* __restrict__ xin0, const float* __restrict__ xin1,
            const char* __restrict__ wtH0, const char* __restrict__ wtL0,
            const char* __restrict__ wtH1, const char* __restrict__ wtL1,
            const float* __restrict__ bnS, const float* __restrict__ bnBi,
            float* __restrict__ out0, float* __restrict__ out1)
{
    constexpr int NCHNK = CICH / 16;
    constexpr int XPAGE = 66 * 32;            // 2112 B per staged row
    __shared__ __align__(16) char Xs[6*XPAGE];
    char* Xh = Xs;
    char* Xl = Xs + 3*XPAGE;

    const int t    = threadIdx.x;
    const int wgid = blockIdx.x;              // 512
    const int xcd  = wgid & 7;
    const int sel  = xcd >> 2;
    const int row  = ((wgid >> 3) << 2) | (xcd & 3);   // 0..255 = b*64 + h
    const float* xin = sel ? xin1 : xin0;
    const char*  wtH = sel ? wtH1 : wtH0;
    const char*  wtL = sel ? wtL1 : wtL0;
    float*       dst = sel ? out1 : out0;

    const int bb  = row >> 6, hh = row & 63;
    const int dyLo = (hh == 0)  ? 1 : 0;
    const int dyHi = (hh == 63) ? 1 : 2;
    const int l = t & 63, w = t >> 6;
    const int lo5 = l & 31, hf = l >> 5;
    const int mi = w >> 1, nw = w & 1;
    int corow[2];
    corow[0] = WCOBASE*sel + nw*64 + lo5;
    corow[1] = corow[0] + 32;

    f32x16 acc[2];
    acc[0] = f16z(); acc[1] = f16z();

    short8 whA[3][2], wlA[3][2], whB[3][2], wlB[3][2];

    auto issueW = [&](int c, int dy, short8 (&h)[3][2], short8 (&lw)[3][2]) {
        #pragma unroll
        for (int dx = 0; dx < 3; ++dx)
            #pragma unroll
            for (int tl = 0; tl < 2; ++tl) {
                const size_t wo = ((size_t)(c*9 + dy*3 + dx)*NCOTOT + corow[tl])*32 + hf*16;
                h[dx][tl]  = *(const short8*)(wtH + wo);
                lw[dx][tl] = *(const short8*)(wtL + wo);
            }
    };
    auto compDy = [&](int dy, const short8 (&h)[3][2], const short8 (&lw)[3][2]) {
        const char* Xph = Xh + dy*XPAGE;
        const char* Xpl = Xl + dy*XPAGE;
        #pragma unroll
        for (int dx = 0; dx < 3; ++dx) {
            const int s = mi*32 + lo5 + dx;
            const int xo = (s*32 + hf*16) ^ ((s & 7) << 4);
            const short8 xfh = *(const short8*)(Xph + xo);
            const short8 xfl = *(const short8*)(Xpl + xo);
            #pragma unroll
            for (int tl = 0; tl < 2; ++tl) {
                acc[tl] = __builtin_amdgcn_mfma_f32_32x32x16_bf16(h[dx][tl],  xfh, acc[tl], 0, 0, 0);
                acc[tl] = __builtin_amdgcn_mfma_f32_32x32x16_bf16(h[dx][tl],  xfl, acc[tl], 0, 0, 0);
                acc[tl] = __builtin_amdgcn_mfma_f32_32x32x16_bf16(lw[dx][tl], xfh, acc[tl], 0, 0, 0);
            }
        }
    };

    float4 xr[4];
    // ---- prefetch chunk 0's X ----
    #pragma unroll
    for (int i = 0; i < 4; ++i) {
        const int u = t + i*256;
        float4 v = make_float4(0.f,0.f,0.f,0.f);
        if (u < 792) {
            const int dyr = u/264, rs = u - dyr*264;
            const int s = rs >> 2, u4 = rs & 3;
            if (dyr >= dyLo && dyr <= dyHi && s >= 1 && s <= 64)
                v = *(const float4*)&xin[
                    (((size_t)bb*Hn + (hh + dyr - 1))*Wn + (s - 1))*CICH + u4*4];
        }
        xr[i] = v;
    }

    for (int c = 0; c < NCHNK; ++c) {
        // ---- issue W for first two dy-groups (latency absorbed by barrier) --
        issueW(c, dyLo, whA, wlA);
        if (dyLo + 1 <= dyHi) issueW(c, dyLo + 1, whB, wlB);
        __syncthreads();                      // previous chunk's reads done
        // ---- write staged X (hi/lo, swizzled) ----
        #pragma unroll
        for (int i = 0; i < 4; ++i) {
            const int u = t + i*256;
            if (u < 792) {
                const int dyr = u/264, rs = u - dyr*264;
                const int s = rs >> 2, u4 = rs & 3;
                if (dyr >= dyLo && dyr <= dyHi) {
                    uint2 vh, vl;
                    split2(xr[i].x, xr[i].y, vh.x, vl.x);
                    split2(xr[i].z, xr[i].w, vh.y, vl.y);
                    const int off = dyr*XPAGE + ((s*32 + u4*8) ^ ((s & 7) << 4));
                    *(uint2*)(Xh + off) = vh;
                    *(uint2*)(Xl + off) = vl;
                }
            }
        }
        __syncthreads();
        // ---- prefetch chunk c+1's X (hides under MFMA phase) ----
        if (c + 1 < NCHNK) {
            #pragma unroll
            for (int i = 0; i < 4; ++i) {
                const int u = t + i*256;
                float4 v = make_float4(0.f,0.f,0.f,0.f);
                if (u < 792) {
                    const int dyr = u/264, rs = u - dyr*264;
                    const int s = rs >> 2, u4 = rs & 3;
                    if (dyr >= dyLo && dyr <= dyHi && s >= 1 && s <= 64)
                        v = *(const float4*)&xin[
                            (((size_t)bb*Hn + (hh + dyr - 1))*Wn + (s - 1))*CICH
                            + (c + 1)*16 + u4*4];
                }
                xr[i] = v;
            }
        }
        // ---- compute dy-groups, rolling W double-buffer ----
        compDy(dyLo, whA, wlA);
        if (dyLo + 1 <= dyHi) {
            if (dyLo + 2 <= dyHi) issueW(c, dyLo + 2, whA, wlA);
            compDy(dyLo + 1, whB, wlB);
            if (dyLo + 2 <= dyHi) compDy(dyLo + 2, whA, wlA);
        }
    }
    // ---- epilogue: folded BN + ReLU ----
    const int px = mi*32 + lo5;
    const size_t p = (size_t)row*Wn + px;
    #pragma unroll
    for (int tl = 0; tl < 2; ++tl) {
        #pragma unroll
        for (int r = 0; r < 16; ++r) {
            const int crow = (r & 3) + 8*(r >> 2) + 4*hf;
            const int och = nw*64 + tl*32 + crow;
            const int bnidx = sel*128 + och;
            dst[p*CI + och] = fmaxf(fmaf(acc[tl][r], bnS[bnidx], bnBi[bnidx]), 0.f);
        }
    }
}

// ---------------- K2a: q,k 1x1 conv -> bf16 [NPIX][16] each ------------------
__global__ __launch_bounds__(256)
void k_qk(const float* __restrict__ feat1,
          const float* __restrict__ wq, const float* __restrict__ bq,
          const float* __restrict__ wk, const float* __restrict__ bk,
          __hip_bfloat16* __restrict__ qb, __hip_bfloat16* __restrict__ kb)
{
    __shared__ float Al[64*129];
    __shared__ __align__(16) float Wl[128*32];
    const int t = threadIdx.x;
    const int pb = blockIdx.x * 64;
    for (int idx = t; idx < 64*128; idx += 256) {
        const int p = idx >> 7, ci = idx & 127;
        Al[p*129 + ci] = feat1[(size_t)(pb + p)*CI + ci];
    }
    for (int idx = t; idx < 128*32; idx += 256) {
        const int ci = idx >> 5, c = idx & 31;
        Wl[idx] = (c < 16) ? wq[ci*16 + c] : wk[ci*16 + (c - 16)];
    }
    __syncthreads();
    const int p = t & 63, cg = t >> 6, co = cg * 8;
    F8 acc = f8zero();
    #pragma unroll 8
    for (int ci = 0; ci < 128; ++ci) {
        const float a = Al[p*129 + ci];
        const float4 wlo = *(const float4*)&Wl[ci*32 + co];
        const float4 whi = *(const float4*)&Wl[ci*32 + co + 4];
        fma8(acc, a, wlo, whi);
    }
    const float* af = (const float*)&acc;
    #pragma unroll
    for (int j = 0; j < 8; ++j) {
        const int c = co + j;
        if (c < 16) qb[(size_t)(pb + p)*16 + c]        = __float2bfloat16(af[j] + bq[c]);
        else        kb[(size_t)(pb + p)*16 + (c - 16)] = __float2bfloat16(af[j] + bk[c - 16]);
    }
}

// ---------------- K2b: v 1x1 conv -> bf16 TRANSPOSED [b][c][pix] -------------
__global__ __launch_bounds__(256)
void k_v(const float* __restrict__ feat1, const float* __restrict__ wv,
         const float* __restrict__ bv, __hip_bfloat16* __restrict__ vbT)
{
    __shared__ float Al[32*129];
    __shared__ __align__(16) float Wl[64*128];
    const int t = threadIdx.x;
    const int pb = blockIdx.x * 32;
    for (int idx = t; idx < 32*128; idx += 256) {
        const int p = idx >> 7, ci = idx & 127;
        Al[p*129 + ci] = feat1[(size_t)(pb + p)*CI + ci];
    }
    const int px = t & 15, co = (t >> 4) * 8;
    F8 acc0 = f8zero(), acc1 = f8zero();
    for (int ch = 0; ch < 2; ++ch) {
        __syncthreads();
        #pragma unroll
        for (int r = 0; r < 8; ++r) {
            const int i4 = t + r*256;
            const int kk = i4 >> 5, c4 = (i4 & 31) * 4;
            *(float4*)&Wl[kk*128 + c4] = *(const float4*)&wv[(size_t)(ch*64 + kk)*CI + c4];
        }
        __syncthreads();
        #pragma unroll 4
        for (int kk = 0; kk < 64; ++kk) {
            const float a0 = Al[px*129 + ch*64 + kk];
            const float a1 = Al[(px+16)*129 + ch*64 + kk];
            const float4 wlo = *(const float4*)&Wl[kk*128 + co];
            const float4 whi = *(const float4*)&Wl[kk*128 + co + 4];
            fma8(acc0, a0, wlo, whi);
            fma8(acc1, a1, wlo, whi);
        }
    }
    const int p0 = pb + px;
    const int bb = p0 / HWn, pin0 = p0 % HWn;
    const float* a0f = (const float*)&acc0;
    const float* a1f = (const float*)&acc1;
    #pragma unroll
    for (int j = 0; j < 8; ++j) {
        const int c = co + j;
        const size_t rowb = ((size_t)bb*CI + c) * HWn;
        vbT[rowb + pin0]      = __float2bfloat16(a0f[j] + bv[c]);
        vbT[rowb + pin0 + 16] = __float2bfloat16(a1f[j] + bv[c]);
    }
}

// ---------------- K3: PAM flash attention via MFMA ---------------------------
__global__ __launch_bounds__(64)
void k_pam(const __hip_bfloat16* __restrict__ qb, const __hip_bfloat16* __restrict__ kb,
           const __hip_bfloat16* __restrict__ vbT, const float* __restrict__ feat1,
           const float* __restrict__ gamma, float* __restrict__ saf)
{
    __shared__ unsigned Ppk[32*32];   // [key-pair 0..31][q 0..31], bf16x2 packed
    const int l   = threadIdx.x;
    const int lo5 = l & 31, h = l >> 5;
    const int q0  = blockIdx.x * 32;
    const int bb  = q0 / HWn;
    const size_t jb = (size_t)bb * HWn;
    const __hip_bfloat16* vbB = vbT + (size_t)bb * CI * HWn;

    const short8 qfrag = *(const short8*)&qb[(size_t)(q0 + lo5)*16 + 8*h];
    const f32x16 zro = f16z();

    f32x16 o[4];
    #pragma unroll
    for (int cb = 0; cb < 4; ++cb) o[cb] = f16z();

    float m_run = -1e30f, s_run = 0.f;

    for (int k0 = 0; k0 < HWn; k0 += 64) {
        const short8 kf0 = *(const short8*)&kb[(jb + k0 +      lo5)*16 + 8*h];
        const short8 kf1 = *(const short8*)&kb[(jb + k0 + 32 + lo5)*16 + 8*h];
        short8 vf[4][4];
        #pragma unroll
        for (int s = 0; s < 4; ++s)
            #pragma unroll
            for (int cb = 0; cb < 4; ++cb)
                vf[s][cb] = *(const short8*)&vbB[((size_t)(cb*32 + lo5))*HWn + k0 + s*16 + 8*h];

        f32x16 e0 = __builtin_amdgcn_mfma_f32_32x32x16_bf16(kf0, qfrag, zro, 0, 0, 0);
        f32x16 e1 = __builtin_amdgcn_mfma_f32_32x32x16_bf16(kf1, qfrag, zro, 0, 0, 0);

        float mt = fmaxf(e0[0], e1[0]);
        #pragma unroll
        for (int r = 1; r < 16; ++r) mt = fmaxf(mt, fmaxf(e0[r], e1[r]));
        mt = fmaxf(mt, __shfl_xor(mt, 32));

        if (__any(mt > m_run + 8.f)) {
            const float mnew = fmaxf(m_run, mt);
            const float sc = __expf(m_run - mnew);
            s_run *= sc;
            #pragma unroll
            for (int cb = 0; cb < 4; ++cb)
                #pragma unroll
                for (int r = 0; r < 16; ++r) o[cb][r] *= sc;
            m_run = mnew;
        }

        #pragma unroll
        for (int r = 0; r < 16; ++r) {
            e0[r] = __expf(e0[r] - m_run);
            e1[r] = __expf(e1[r] - m_run);
        }
        float ss = 0.f;
        #pragma unroll
        for (int r = 0; r < 16; ++r) ss += e0[r] + e1[r];
        s_run += ss;

        #pragma unroll
        for (int r = 0; r < 16; r += 2) {
            const int pidx = ((r & 3) >> 1) + 4*(r >> 2) + 2*h;
            Ppk[pidx*32 + lo5]        = pack2(e0[r], e0[r+1]);
            Ppk[(16 + pidx)*32 + lo5] = pack2(e1[r], e1[r+1]);
        }
        #pragma unroll
        for (int s = 0; s < 4; ++s) {
            union { unsigned u[4]; short8 s8; } P;
            #pragma unroll
            for (int w = 0; w < 4; ++w)
                P.u[w] = Ppk[(s*8 + 4*h + w)*32 + lo5];
            #pragma unroll
            for (int cb = 0; cb < 4; ++cb)
                o[cb] = __builtin_amdgcn_mfma_f32_32x32x16_bf16(vf[s][cb], P.s8, o[cb], 0, 0, 0);
        }
    }

    const float s_tot = s_run + __shfl_xor(s_run, 32);
    const float inv = 1.f / s_tot;
    const float g = gamma[0];
    const size_t q = (size_t)q0 + lo5;
    #pragma unroll
    for (int cb = 0; cb < 4; ++cb)
        #pragma unroll
        for (int r = 0; r < 16; ++r) {
            const int c = cb*32 + (r & 3) + 8*(r >> 2) + 4*h;
            const size_t idx = q*CI + c;
            saf[idx] = g*(o[cb][r]*inv) + feat1[idx];
        }
}

// ---------------- K4x: transpose feat2 -> bf16 hi/lo [b][c][HW] --------------
__global__ __launch_bounds__(256)
void k_xpose(const float* __restrict__ feat2,
             char* __restrict__ f2TH, char* __restrict__ f2TL)
{
    __shared__ float Xl[64*129];
    const int t = threadIdx.x;
    const int pb = blockIdx.x * 64;
    const int bb = pb / HWn, pin = pb % HWn;
    for (int idx = t; idx < 64*128; idx += 256) {
        const int p = idx >> 7, ci = idx & 127;
        Xl[p*129 + ci] = feat2[(size_t)(pb + p)*CI + ci];
    }
    __syncthreads();
    const int c = t >> 1, half = t & 1;
    const size_t rowb = ((size_t)(bb*CI + c)*HWn + pin + half*32) * 2;
    #pragma unroll
    for (int j = 0; j < 16; ++j) {
        const float a = Xl[(half*32 + 2*j)*129 + c];
        const float b = Xl[(half*32 + 2*j + 1)*129 + c];
        unsigned hi, lo; split2(a, b, hi, lo);
        *(unsigned*)(f2TH + rowb + 4*j) = hi;
        *(unsigned*)(f2TL + rowb + 4*j) = lo;
    }
}

// ---------------- K4a: CAM energy via MFMA, split-K partials -----------------
__global__ __launch_bounds__(256)
void k_cam_energy_m(const char* __restrict__ f2TH, const char* __restrict__ f2TL,
                    float* __restrict__ epart)
{
    __shared__ __align__(16) char Vh[128*256];
    __shared__ __align__(16) char Vl[128*256];
    const int t = threadIdx.x;
    const int ks = blockIdx.x, bb = blockIdx.y;
    const int l = t & 63, w = t >> 6;
    const int lo5 = l & 31, hf = l >> 5;

    #pragma unroll
    for (int pass = 0; pass < 8; ++pass) {
        const int slot = pass*256 + t;          // 0..2047
        const int c = slot >> 4, g = slot & 15; // 16B granule
        const size_t gaddr = ((size_t)(bb*CI + c)*HWn + ks*128)*2 + g*16;
        const int laddr = c*256 + ((g*16) ^ ((c & 15) << 4));
        *(float4*)(Vh + laddr) = *(const float4*)(f2TH + gaddr);
        *(float4*)(Vl + laddr) = *(const float4*)(f2TL + gaddr);
    }
    __syncthreads();

    f32x16 acc[4];
    #pragma unroll
    for (int nj = 0; nj < 4; ++nj) acc[nj] = f16z();
    const int cA = w*32 + lo5;
    const int swA = (cA & 15) << 4;

    #pragma unroll
    for (int kk = 0; kk < 8; ++kk) {
        const int kb = kk*32 + hf*16;
        const short8 ah = *(const short8*)(Vh + cA*256 + (kb ^ swA));
        const short8 al = *(const short8*)(Vl + cA*256 + (kb ^ swA));
        #pragma unroll
        for (int nj = 0; nj < 4; ++nj) {
            const int dB = nj*32 + lo5;
            const int swB = (dB & 15) << 4;
            const short8 bh = *(const short8*)(Vh + dB*256 + (kb ^ swB));
            const short8 bl = *(const short8*)(Vl + dB*256 + (kb ^ swB));
            acc[nj] = __builtin_amdgcn_mfma_f32_32x32x16_bf16(ah, bh, acc[nj], 0, 0, 0);
            acc[nj] = __builtin_amdgcn_mfma_f32_32x32x16_bf16(al, bh, acc[nj], 0, 0, 0);
            acc[nj] = __builtin_amdgcn_mfma_f32_32x32x16_bf16(ah, bl, acc[nj], 0, 0, 0);
        }
    }
    float* ep = epart + ((size_t)(bb*32 + ks)*CI)*CI;
    #pragma unroll
    for (int nj = 0; nj < 4; ++nj)
        #pragma unroll
        for (int r = 0; r < 16; ++r) {
            const int c = w*32 + (r & 3) + 8*(r >> 2) + 4*hf;
            ep[(size_t)c*CI + nj*32 + lo5] = acc[nj][r];
        }
}

// ---------------- K4b: fused reduce(32 partials) + max-subtract softmax ------
__global__ __launch_bounds__(64)
void k_cam_rs(const float* __restrict__ epart, float* __restrict__ att)
{
    const int lane = threadIdx.x;
    const int row = blockIdx.x;             // b*128 + c
    const int bb = row >> 7, c = row & 127;
    float2 e = make_float2(0.f, 0.f);
    for (int ks = 0; ks < 32; ++ks) {
        const float2 v = *(const float2*)&epart[
            ((size_t)(bb*32 + ks)*CI + c)*CI + lane*2];
        e.x += v.x; e.y += v.y;
    }
    float M = fmaxf(e.x, e.y);
    #pragma unroll
    for (int off = 32; off > 0; off >>= 1) M = fmaxf(M, __shfl_xor(M, off));
    const float en0 = M - e.x, en1 = M - e.y;
    float mx = fmaxf(en0, en1);
    #pragma unroll
    for (int off = 32; off > 0; off >>= 1) mx = fmaxf(mx, __shfl_xor(mx, off));
    const float p0 = __expf(en0 - mx), p1 = __expf(en1 - mx);
    float s = p0 + p1;
    #pragma unroll
    for (int off = 32; off > 0; off >>= 1) s += __shfl_xor(s, off);
    const float inv = 1.f / s;
    float2 o; o.x = p0*inv; o.y = p1*inv;
    *(float2*)&att[(size_t)row*CI + lane*2] = o;
}

// ---------------- K4c: CAM apply: sc = g*(X att^T) + X ----------------------
__global__ __launch_bounds__(256)
void k_cam_apply(const float* __restrict__ feat2, const float* __restrict__ att,
                 const float* __restrict__ gamma, float* __restrict__ sc_feat)
{
    __shared__ float Xl[64*129];
    __shared__ __align__(16) float aT[128*64];
    const int t = threadIdx.x;
    const int pb = blockIdx.x * 64;
    const int bb = pb / HWn;
    const int ch = blockIdx.y * 64;
    for (int idx = t; idx < 64*128; idx += 256) {
        const int p = idx >> 7, ci = idx & 127;
        Xl[p*129 + ci] = feat2[(size_t)(pb + p)*CI + ci];
    }
    for (int idx = t; idx < 128*64; idx += 256) {
        const int d = idx >> 6, cc = idx & 63;
        aT[d*64 + cc] = att[((size_t)bb*CI + ch + cc)*CI + d];
    }
    __syncthreads();
    const int px = t & 63, cg = t >> 6;
    F8 accA = f8zero(), accB = f8zero();
    #pragma unroll 4
    for (int d = 0; d < 128; ++d) {
        const float xv = Xl[px*129 + d];
        const float* ap = &aT[d*64 + cg*16];
        const float4 a0 = *(const float4*)&ap[0];
        const float4 a1 = *(const float4*)&ap[4];
        const float4 a2 = *(const float4*)&ap[8];
        const float4 a3 = *(const float4*)&ap[12];
        fma8(accA, xv, a0, a1);
        fma8(accB, xv, a2, a3);
    }
    const float g = gamma[0];
    const float* fa = (const float*)&accA;
    const float* fb = (const float*)&accB;
    #pragma unroll
    for (int j = 0; j < 8; ++j) {
        const int cA = ch + cg*16 + j;
        const int cB = cA + 8;
        sc_feat[(size_t)(pb + px)*CI + cA] = g*fa[j] + Xl[px*129 + cA];
        sc_feat[(size_t)(pb + px)*CI + cB] = g*fb[j] + Xl[px*129 + cB];
    }
}

// ---------------- K7: final 1x1 conv (sum of two branches) -> out ------------
__global__ __launch_bounds__(256)
void k_final(const float* __restrict__ sa, const float* __restrict__ sc,
             const float* __restrict__ w8, float* __restrict__ out)
{
    __shared__ float Xl[64*129];
    __shared__ float w8l[128*COn];
    const int t = threadIdx.x;
    const int pb = blockIdx.x * 64;
    for (int idx = t; idx < 64*128; idx += 256) {
        const int p = idx >> 7, ci = idx & 127;
        const size_t gi = (size_t)(pb + p)*CI + ci;
        Xl[p*129 + ci] = sa[gi] + sc[gi];
    }
    for (int idx = t; idx < 128*COn; idx += 256) w8l[idx] = w8[idx];
    __syncthreads();
    for (int idx = t; idx < 64*COn; idx += 256) {
        const int p = idx / COn, co = idx - p*COn;
        float acc = 0.f;
        #pragma unroll 8
        for (int ci = 0; ci < 128; ++ci)
            acc = fmaf(Xl[p*129 + ci], w8l[ci*COn + co], acc);
        out[(size_t)(pb + p)*COn + co] = acc;
    }
}

extern "C" void kernel_launch(void* const* d_in, const int* in_sizes, int n_in,
                              void* d_out, int out_size, void* d_ws, size_t ws_size,
                              hipStream_t stream)
{
    const float* x    = (const float*)d_in[0];
    const float* w5a  = (const float*)d_in[1];
    const float* w5c  = (const float*)d_in[2];
    const float* wq   = (const float*)d_in[3];
    const float* bq   = (const float*)d_in[4];
    const float* wk   = (const float*)d_in[5];
    const float* bk   = (const float*)d_in[6];
    const float* wv   = (const float*)d_in[7];
    const float* bv   = (const float*)d_in[8];
    const float* pgam = (const float*)d_in[9];
    const float* cgam = (const float*)d_in[10];
    const float* w51  = (const float*)d_in[11];
    const float* w52  = (const float*)d_in[12];
    const float* w8   = (const float*)d_in[13];
    const float* bn1g = (const float*)d_in[14];
    const float* bn1b = (const float*)d_in[15];
    const float* bn1m = (const float*)d_in[16];
    const float* bn1v = (const float*)d_in[17];
    const float* bn2g = (const float*)d_in[18];
    const float* bn2b = (const float*)d_in[19];
    const float* bn2m = (const float*)d_in[20];
    const float* bn2v = (const float*)d_in[21];
    const float* bn3g = (const float*)d_in[22];
    const float* bn3b = (const float*)d_in[23];
    const float* bn3m = (const float*)d_in[24];
    const float* bn3v = (const float*)d_in[25];
    const float* bn4g = (const float*)d_in[26];
    const float* bn4b = (const float*)d_in[27];
    const float* bn4m = (const float*)d_in[28];
    const float* bn4v = (const float*)d_in[29];

    char* wsb = (char*)d_ws;
    // region [0, 8MB): feat1 (conv1->pam) -> f2TH/f2TL (xpose->energy) -> sa_conv
    float* feat1  = (float*)(wsb + 0);
    char*  f2TH   = wsb + 0;                    // 4 MB
    char*  f2TL   = wsb + 4194304;              // 4 MB
    float* feat2  = (float*)(wsb + 8388608);    // 8 MB (reused as sc_conv)
    float* saf    = (float*)(wsb + 16777216);   // 8 MB
    // region [24MB..32MB): wt1 planes (prep->conv1) -> epart (energy->rs) -> scf
    float* scf    = (float*)(wsb + 25165824);   // 8 MB
    char*  wt1H   = wsb + 25165824;             // 2359296
    char*  wt1L   = wsb + 27525120;             // 2359296 -> 29884416
    float* epart  = (float*)(wsb + 25165824);   // 8 MB (32 slices x 64KB x 4 b)
    float* att    = (float*)(wsb + 33816576);   // 256 KB
    __hip_bfloat16* qb16 = (__hip_bfloat16*)(wsb + 34078720);  // 512 KB
    __hip_bfloat16* kb16 = (__hip_bfloat16*)(wsb + 34603008);  // 512 KB
    __hip_bfloat16* vbT  = (__hip_bfloat16*)(wsb + 35127296);  // 4 MB -> 39321600
    char* wt2aH = wsb + 39321600;               // 294912 -> 39616512
    char* wt2aL = wsb + 39616512;               // 294912 -> 39911424
    char* wt2bH = wsb + 39911424;               // 294912 -> 40206336
    char* wt2bL = wsb + 40206336;               // 294912 -> 40501248
    float* bnAs = (float*)(wsb + 40501248);     // 1 KB each
    float* bnAb = (float*)(wsb + 40502272);
    float* bnBs = (float*)(wsb + 40503296);
    float* bnBb = (float*)(wsb + 40504320);     // high-water 40505344
    float* sa_conv = feat1;                     // feat1/f2T dead after energy
    float* sc_conv = feat2;                     // feat2 dead after cam_apply
    float* out  = (float*)d_out;

    k_prep_w<<<dim3(2880), 256, 0, stream>>>(w5a, w5c, w51, w52,
        wt1H, wt1L, wt2aH, wt2aL, wt2bH, wt2bL);
    k_prep_bn<<<dim3(1), 256, 0, stream>>>(bn1g, bn1b, bn1m, bn1v, bn2g, bn2b, bn2m, bn2v,
                                           bn3g, bn3b, bn3m, bn3v, bn4g, bn4b, bn4m, bn4v,
                                           bnAs, bnAb, bnBs, bnBb);
    k_conv<512, 256, 128><<<dim3(512), 256, 0, stream>>>(
        x, x, wt1H, wt1L, wt1H, wt1L, bnAs, bnAb, feat1, feat2);
    k_qk<<<dim3(NPIX/64), 256, 0, stream>>>(feat1, wq, bq, wk, bk, qb16, kb16);
    k_v<<<dim3(NPIX/32), 256, 0, stream>>>(feat1, wv, bv, vbT);
    k_pam<<<dim3(NPIX/32), 64, 0, stream>>>(qb16, kb16, vbT, feat1, pgam, saf);
    k_xpose<<<dim3(NPIX/64), 256, 0, stream>>>(feat2, f2TH, f2TL);
    k_cam_energy_m<<<dim3(32, Bn), 256, 0, stream>>>(f2TH, f2TL, epart);
    k_cam_rs<<<dim3(Bn*CI), 64, 0, stream>>>(epart, att);
    k_cam_apply<<<dim3(NPIX/64, 2), 256, 0, stream>>>(feat2, att, cgam, scf);
    k_conv<128, 128, 0><<<dim3(512), 256, 0, stream>>>(
        saf, scf, wt2aH, wt2aL, wt2bH, wt2bL, bnBs, bnBb, sa_conv, sc_conv);
    k_final<<<dim3(NPIX/64), 256, 0, stream>>>(sa_conv, sc_conv, w8, out);
}

// Round 10
// 348.653 us; speedup vs baseline: 1.8965x; 1.0441x over previous
//
#include <hip/hip_runtime.h>
#include <hip/hip_bf16.h>
#include <math.h>

#define BN_EPS 1e-3f

constexpr int Bn = 4, Hn = 64, Wn = 64, CIN = 512, CI = 128;
constexpr int HWn = Hn * Wn;        // 4096
constexpr int NPIX = Bn * HWn;      // 16384
constexpr int COn = 19;

struct F8 { float4 lo, hi; };

__device__ __forceinline__ F8 f8zero() {
    F8 r; r.lo = make_float4(0.f,0.f,0.f,0.f); r.hi = make_float4(0.f,0.f,0.f,0.f); return r;
}
__device__ __forceinline__ void fma8(F8 &acc, float a, const float4 &wlo, const float4 &whi) {
    acc.lo.x = fmaf(a, wlo.x, acc.lo.x);
    acc.lo.y = fmaf(a, wlo.y, acc.lo.y);
    acc.lo.z = fmaf(a, wlo.z, acc.lo.z);
    acc.lo.w = fmaf(a, wlo.w, acc.lo.w);
    acc.hi.x = fmaf(a, whi.x, acc.hi.x);
    acc.hi.y = fmaf(a, whi.y, acc.hi.y);
    acc.hi.z = fmaf(a, whi.z, acc.hi.z);
    acc.hi.w = fmaf(a, whi.w, acc.hi.w);
}

// ---- MFMA helpers -----------------------------------------------------------
typedef __attribute__((ext_vector_type(8)))  short short8;   // 8 bf16 in 4 VGPRs
typedef __attribute__((ext_vector_type(16))) float f32x16;

__device__ __forceinline__ f32x16 f16z() {
    f32x16 z;
    #pragma unroll
    for (int i = 0; i < 16; ++i) z[i] = 0.f;
    return z;
}
// fp32 -> bf16 (RNE), pure integer ops
__device__ __forceinline__ unsigned f2b(float f) {
    union { float f; unsigned u; } c; c.f = f;
    return (c.u + 0x7FFFu + ((c.u >> 16) & 1u)) >> 16;
}
__device__ __forceinline__ unsigned pack2(float lo, float hi) {
    return (f2b(hi) << 16) | f2b(lo);
}
// split (a,b) into packed bf16 hi words + bf16 lo residuals (a in low half)
__device__ __forceinline__ void split2(float a, float b, unsigned &hi, unsigned &lo) {
    const unsigned ha = f2b(a), hb = f2b(b);
    union { unsigned u; float f; } ua, ub; ua.u = ha << 16; ub.u = hb << 16;
    hi = (hb << 16) | ha;
    lo = pack2(a - ua.f, b - ub.f);
}

// ---------------- prep: weights -> bf16 hi/lo, co-major, LINEAR --------------
__global__ __launch_bounds__(256)
void k_prep_w(const float* __restrict__ w5a, const float* __restrict__ w5c,
              const float* __restrict__ w51, const float* __restrict__ w52,
              char* __restrict__ wt1H, char* __restrict__ wt1L,
              char* __restrict__ wt2aH, char* __restrict__ wt2aL,
              char* __restrict__ wt2bH, char* __restrict__ wt2bL)
{
    int idx = blockIdx.x * 256 + threadIdx.x;
    if (idx < 589824) {                       // 32*9*256*8 pairs
        const int jp = idx & 7, co = (idx >> 3) & 255, ct = idx >> 11; // ct=c*9+tap
        const int tap = ct % 9, c = ct / 9;
        const float* src = (co < 128) ? w5a : w5c;
        const int coc = co & 127;
        const int ci = c*16 + jp*2;
        const float a = src[((size_t)tap*CIN + ci)*CI + coc];
        const float b = src[((size_t)tap*CIN + ci + 1)*CI + coc];
        unsigned hi, lo; split2(a, b, hi, lo);
        const int L = co*32 + jp*4;
        *(unsigned*)(wt1H + (size_t)ct*8192 + L) = hi;
        *(unsigned*)(wt1L + (size_t)ct*8192 + L) = lo;
    } else {
        int k = idx - 589824;                 // 2 * 8*9*128*8 pairs
        if (k >= 147456) return;
        const float* src = (k < 73728) ? w51 : w52;
        char* dstH = (k < 73728) ? wt2aH : wt2bH;
        char* dstL = (k < 73728) ? wt2aL : wt2bL;
        if (k >= 73728) k -= 73728;
        const int jp = k & 7, co = (k >> 3) & 127, ct = k >> 10; // ct=c*9+tap
        const int tap = ct % 9, c = ct / 9;
        const int ci = c*16 + jp*2;
        const float a = src[((size_t)tap*CI + ci)*CI + co];
        const float b = src[((size_t)tap*CI + ci + 1)*CI + co];
        unsigned hi, lo; split2(a, b, hi, lo);
        const int L = co*32 + jp*4;
        *(unsigned*)(dstH + (size_t)ct*4096 + L) = hi;
        *(unsigned*)(dstL + (size_t)ct*4096 + L) = lo;
    }
}

// ---------------- prep: BN -> folded scale/bias tables -----------------------
__global__ __launch_bounds__(256)
void k_prep_bn(const float* g1, const float* b1, const float* m1, const float* v1,
               const float* g2, const float* b2, const float* m2, const float* v2,
               const float* g3, const float* b3, const float* m3, const float* v3,
               const float* g4, const float* b4, const float* m4, const float* v4,
               float* bnAs, float* bnAb, float* bnBs, float* bnBb)
{
    const int t = threadIdx.x, c = t & 127;
    {
        const float *g = (t < 128) ? g1 : g2, *b = (t < 128) ? b1 : b2;
        const float *m = (t < 128) ? m1 : m2, *v = (t < 128) ? v1 : v2;
        const float s = g[c] * rsqrtf(v[c] + BN_EPS);
        bnAs[t] = s; bnAb[t] = b[c] - m[c]*s;
    }
    {
        const float *g = (t < 128) ? g3 : g4, *b = (t < 128) ? b3 : b4;
        const float *m = (t < 128) ? m3 : m4, *v = (t < 128) ? v3 : v4;
        const float s = g[c] * rsqrtf(v[c] + BN_EPS);
        bnBs[t] = s; bnBb[t] = b[c] - m[c]*s;
    }
}

// ---------------- MFMA 3x3 conv, bf16x3 split + folded BN + ReLU -------------
// Grid 1024: xcd=wgid&7 -> sel=xcd>>2 (input/branch), ch2=(xcd>>1)&1 (co-64
// half), row=((wgid>>3)<<1)|(xcd&1). Each XCD sees one (sel,ch2) -> W working
// set 1.18 MB, L2-resident. Block = one row (64 px) x 64 co, 4 waves; wave =
// (mi=px-half, nt=co-32-tile), acc = 1 f32x16 -> 4 blocks/CU, 16 waves/CU.
// W: global->VGPR, double-buffered per dy-group (pre-barrier issue: the
// barrier's vmcnt drain absorbs latency). X: LDS bf16 hi/lo, XOR swizzle,
// register prefetch one chunk ahead. 3-term: xh*wh + xl*wh + xh*wl.
// mfma(A=W^T[co][k], B=X[px][k]) -> D[col=px][row=co]  (k_pam-validated map)
template<int CICH, int NCOTOT, int WCOBASE>
__global__ __launch_bounds__(256)
void k_conv(const float* __restrict__ xin0, const float* __restrict__ xin1,
            const char* __restrict__ wtH0, const char* __restrict__ wtL0,
            const char* __restrict__ wtH1, const char* __restrict__ wtL1,
            const float* __restrict__ bnS, const float* __restrict__ bnBi,
            float* __restrict__ out0, float* __restrict__ out1)
{
    constexpr int NCHNK = CICH / 16;
    constexpr int XPAGE = 66 * 32;            // 2112 B per staged row
    __shared__ __align__(16) char Xs[6*XPAGE];
    char* Xh = Xs;
    char* Xl = Xs + 3*XPAGE;

    const int t    = threadIdx.x;
    const int wgid = blockIdx.x;              // 1024
    const int xcd  = wgid & 7;
    const int sel  = xcd >> 2;
    const int ch2  = (xcd >> 1) & 1;
    const int row  = ((wgid >> 3) << 1) | (xcd & 1);   // 0..255 = b*64 + h
    const float* xin = sel ? xin1 : xin0;
    const char*  wtH = sel ? wtH1 : wtH0;
    const char*  wtL = sel ? wtL1 : wtL0;
    float*       dst = sel ? out1 : out0;

    const int bb  = row >> 6, hh = row & 63;
    const int dyLo = (hh == 0)  ? 1 : 0;
    const int dyHi = (hh == 63) ? 1 : 2;
    const int l = t & 63, w = t >> 6;
    const int lo5 = l & 31, hf = l >> 5;
    const int mi = w >> 1, nt = w & 1;
    const int corow = WCOBASE*sel + ch2*64 + nt*32 + lo5;

    f32x16 acc = f16z();

    short8 whA[3], wlA[3], whB[3], wlB[3];

    auto issueW = [&](int c, int dy, short8 (&h)[3], short8 (&lw)[3]) {
        #pragma unroll
        for (int dx = 0; dx < 3; ++dx) {
            const size_t wo = ((size_t)(c*9 + dy*3 + dx)*NCOTOT + corow)*32 + hf*16;
            h[dx]  = *(const short8*)(wtH + wo);
            lw[dx] = *(const short8*)(wtL + wo);
        }
    };
    auto compDy = [&](int dy, const short8 (&h)[3], const short8 (&lw)[3]) {
        const char* Xph = Xh + dy*XPAGE;
        const char* Xpl = Xl + dy*XPAGE;
        #pragma unroll
        for (int dx = 0; dx < 3; ++dx) {
            const int s = mi*32 + lo5 + dx;
            const int xo = (s*32 + hf*16) ^ ((s & 7) << 4);
            const short8 xfh = *(const short8*)(Xph + xo);
            const short8 xfl = *(const short8*)(Xpl + xo);
            acc = __builtin_amdgcn_mfma_f32_32x32x16_bf16(h[dx],  xfh, acc, 0, 0, 0);
            acc = __builtin_amdgcn_mfma_f32_32x32x16_bf16(h[dx],  xfl, acc, 0, 0, 0);
            acc = __builtin_amdgcn_mfma_f32_32x32x16_bf16(lw[dx], xfh, acc, 0, 0, 0);
        }
    };

    float4 xr[4];
    // ---- prefetch chunk 0's X ----
    #pragma unroll
    for (int i = 0; i < 4; ++i) {
        const int u = t + i*256;
        float4 v = make_float4(0.f,0.f,0.f,0.f);
        if (u < 792) {
            const int dyr = u/264, rs = u - dyr*264;
            const int s = rs >> 2, u4 = rs & 3;
            if (dyr >= dyLo && dyr <= dyHi && s >= 1 && s <= 64)
                v = *(const float4*)&xin[
                    (((size_t)bb*Hn + (hh + dyr - 1))*Wn + (s - 1))*CICH + u4*4];
        }
        xr[i] = v;
    }

    for (int c = 0; c < NCHNK; ++c) {
        // ---- issue W for first two dy-groups (latency absorbed by barrier) --
        issueW(c, dyLo, whA, wlA);
        if (dyLo + 1 <= dyHi) issueW(c, dyLo + 1, whB, wlB);
        __syncthreads();                      // previous chunk's reads done
        // ---- write staged X (hi/lo, swizzled) ----
        #pragma unroll
        for (int i = 0; i < 4; ++i) {
            const int u = t + i*256;
            if (u < 792) {
                const int dyr = u/264, rs = u - dyr*264;
                const int s = rs >> 2, u4 = rs & 3;
                if (dyr >= dyLo && dyr <= dyHi) {
                    uint2 vh, vl;
                    split2(xr[i].x, xr[i].y, vh.x, vl.x);
                    split2(xr[i].z, xr[i].w, vh.y, vl.y);
                    const int off = dyr*XPAGE + ((s*32 + u4*8) ^ ((s & 7) << 4));
                    *(uint2*)(Xh + off) = vh;
                    *(uint2*)(Xl + off) = vl;
                }
            }
        }
        __syncthreads();
        // ---- prefetch chunk c+1's X (hides under MFMA phase) ----
        if (c + 1 < NCHNK) {
            #pragma unroll
            for (int i = 0; i < 4; ++i) {
                const int u = t + i*256;
                float4 v = make_float4(0.f,0.f,0.f,0.f);
                if (u < 792) {
                    const int dyr = u/264, rs = u - dyr*264;
                    const int s = rs >> 2, u4 = rs & 3;
                    if (dyr >= dyLo && dyr <= dyHi && s >= 1 && s <= 64)
                        v = *(const float4*)&xin[
                            (((size_t)bb*Hn + (hh + dyr - 1))*Wn + (s - 1))*CICH
                            + (c + 1)*16 + u4*4];
                }
                xr[i] = v;
            }
        }
        // ---- compute dy-groups, rolling W double-buffer ----
        compDy(dyLo, whA, wlA);
        if (dyLo + 1 <= dyHi) {
            if (dyLo + 2 <= dyHi) issueW(c, dyLo + 2, whA, wlA);
            compDy(dyLo + 1, whB, wlB);
            if (dyLo + 2 <= dyHi) compDy(dyLo + 2, whA, wlA);
        }
    }
    // ---- epilogue: folded BN + ReLU ----
    const int px = mi*32 + lo5;
    const size_t p = (size_t)row*Wn + px;
    #pragma unroll
    for (int r = 0; r < 16; ++r) {
        const int crow = (r & 3) + 8*(r >> 2) + 4*hf;
        const int och = ch2*64 + nt*32 + crow;
        const int bnidx = sel*128 + och;
        dst[p*CI + och] = fmaxf(fmaf(acc[r], bnS[bnidx], bnBi[bnidx]), 0.f);
    }
}

// ---------------- K2a: q,k 1x1 conv -> bf16 [NPIX][16] each ------------------
__global__ __launch_bounds__(256)
void k_qk(const float* __restrict__ feat1,
          const float* __restrict__ wq, const float* __restrict__ bq,
          const float* __restrict__ wk, const float* __restrict__ bk,
          __hip_bfloat16* __restrict__ qb, __hip_bfloat16* __restrict__ kb)
{
    __shared__ float Al[64*129];
    __shared__ __align__(16) float Wl[128*32];
    const int t = threadIdx.x;
    const int pb = blockIdx.x * 64;
    for (int idx = t; idx < 64*128; idx += 256) {
        const int p = idx >> 7, ci = idx & 127;
        Al[p*129 + ci] = feat1[(size_t)(pb + p)*CI + ci];
    }
    for (int idx = t; idx < 128*32; idx += 256) {
        const int ci = idx >> 5, c = idx & 31;
        Wl[idx] = (c < 16) ? wq[ci*16 + c] : wk[ci*16 + (c - 16)];
    }
    __syncthreads();
    const int p = t & 63, cg = t >> 6, co = cg * 8;
    F8 acc = f8zero();
    #pragma unroll 8
    for (int ci = 0; ci < 128; ++ci) {
        const float a = Al[p*129 + ci];
        const float4 wlo = *(const float4*)&Wl[ci*32 + co];
        const float4 whi = *(const float4*)&Wl[ci*32 + co + 4];
        fma8(acc, a, wlo, whi);
    }
    const float* af = (const float*)&acc;
    #pragma unroll
    for (int j = 0; j < 8; ++j) {
        const int c = co + j;
        if (c < 16) qb[(size_t)(pb + p)*16 + c]        = __float2bfloat16(af[j] + bq[c]);
        else        kb[(size_t)(pb + p)*16 + (c - 16)] = __float2bfloat16(af[j] + bk[c - 16]);
    }
}

// ---------------- K2b: v 1x1 conv -> bf16 TRANSPOSED [b][c][pix] -------------
__global__ __launch_bounds__(256)
void k_v(const float* __restrict__ feat1, const float* __restrict__ wv,
         const float* __restrict__ bv, __hip_bfloat16* __restrict__ vbT)
{
    __shared__ float Al[32*129];
    __shared__ __align__(16) float Wl[64*128];
    const int t = threadIdx.x;
    const int pb = blockIdx.x * 32;
    for (int idx = t; idx < 32*128; idx += 256) {
        const int p = idx >> 7, ci = idx & 127;
        Al[p*129 + ci] = feat1[(size_t)(pb + p)*CI + ci];
    }
    const int px = t & 15, co = (t >> 4) * 8;
    F8 acc0 = f8zero(), acc1 = f8zero();
    for (int ch = 0; ch < 2; ++ch) {
        __syncthreads();
        #pragma unroll
        for (int r = 0; r < 8; ++r) {
            const int i4 = t + r*256;
            const int kk = i4 >> 5, c4 = (i4 & 31) * 4;
            *(float4*)&Wl[kk*128 + c4] = *(const float4*)&wv[(size_t)(ch*64 + kk)*CI + c4];
        }
        __syncthreads();
        #pragma unroll 4
        for (int kk = 0; kk < 64; ++kk) {
            const float a0 = Al[px*129 + ch*64 + kk];
            const float a1 = Al[(px+16)*129 + ch*64 + kk];
            const float4 wlo = *(const float4*)&Wl[kk*128 + co];
            const float4 whi = *(const float4*)&Wl[kk*128 + co + 4];
            fma8(acc0, a0, wlo, whi);
            fma8(acc1, a1, wlo, whi);
        }
    }
    const int p0 = pb + px;
    const int bb = p0 / HWn, pin0 = p0 % HWn;
    const float* a0f = (const float*)&acc0;
    const float* a1f = (const float*)&acc1;
    #pragma unroll
    for (int j = 0; j < 8; ++j) {
        const int c = co + j;
        const size_t rowb = ((size_t)bb*CI + c) * HWn;
        vbT[rowb + pin0]      = __float2bfloat16(a0f[j] + bv[c]);
        vbT[rowb + pin0 + 16] = __float2bfloat16(a1f[j] + bv[c]);
    }
}

// ---------------- K3: PAM flash attention, 4-wave K-split --------------------
// Block = 32 q rows, 256 thr / 4 waves; wave wv owns keys [wv*1024, +1024).
// Per-wave flash state (swapped QK^T, lane-local softmax, LDS-keyed P
// hand-off into per-wave Ppk region). Final flash-merge across waves via LDS:
// M = max_w m_w; o = SUM exp(m_w-M) o_w; s = SUM exp(m_w-M) s_w. osum is
// padded [32][132] (4-way bank aliasing) and aliases the dead Ppk regions.
__global__ __launch_bounds__(256)
void k_pam(const __hip_bfloat16* __restrict__ qb, const __hip_bfloat16* __restrict__ kb,
           const __hip_bfloat16* __restrict__ vbT, const float* __restrict__ feat1,
           const float* __restrict__ gamma, float* __restrict__ saf)
{
    __shared__ __align__(16) char pbuf[16896];   // Ppk[4][1024 u32] -> osum[32][132] f32
    __shared__ float msArr[4][32];
    __shared__ float ssArr[4][32];
    __shared__ float ssum[32];
    const int t  = threadIdx.x;
    const int wv = t >> 6, l = t & 63;
    const int lo5 = l & 31, h = l >> 5;
    unsigned* Ppk = (unsigned*)(pbuf + wv*4096);
    float* osum = (float*)pbuf;

    const int q0 = blockIdx.x * 32;
    const int bb = q0 / HWn;
    const size_t jb = (size_t)bb * HWn;
    const __hip_bfloat16* vbB = vbT + (size_t)bb * CI * HWn;

    const short8 qfrag = *(const short8*)&qb[(size_t)(q0 + lo5)*16 + 8*h];
    const f32x16 zro = f16z();

    f32x16 o[4];
    #pragma unroll
    for (int cb = 0; cb < 4; ++cb) o[cb] = f16z();

    float m_run = -1e30f, s_run = 0.f;

    for (int k0 = wv*1024; k0 < wv*1024 + 1024; k0 += 64) {
        const short8 kf0 = *(const short8*)&kb[(jb + k0 +      lo5)*16 + 8*h];
        const short8 kf1 = *(const short8*)&kb[(jb + k0 + 32 + lo5)*16 + 8*h];
        short8 vf[4][4];
        #pragma unroll
        for (int s = 0; s < 4; ++s)
            #pragma unroll
            for (int cb = 0; cb < 4; ++cb)
                vf[s][cb] = *(const short8*)&vbB[((size_t)(cb*32 + lo5))*HWn + k0 + s*16 + 8*h];

        f32x16 e0 = __builtin_amdgcn_mfma_f32_32x32x16_bf16(kf0, qfrag, zro, 0, 0, 0);
        f32x16 e1 = __builtin_amdgcn_mfma_f32_32x32x16_bf16(kf1, qfrag, zro, 0, 0, 0);

        float mt = fmaxf(e0[0], e1[0]);
        #pragma unroll
        for (int r = 1; r < 16; ++r) mt = fmaxf(mt, fmaxf(e0[r], e1[r]));
        mt = fmaxf(mt, __shfl_xor(mt, 32));

        if (__any(mt > m_run + 8.f)) {
            const float mnew = fmaxf(m_run, mt);
            const float sc = __expf(m_run - mnew);
            s_run *= sc;
            #pragma unroll
            for (int cb = 0; cb < 4; ++cb)
                #pragma unroll
                for (int r = 0; r < 16; ++r) o[cb][r] *= sc;
            m_run = mnew;
        }

        #pragma unroll
        for (int r = 0; r < 16; ++r) {
            e0[r] = __expf(e0[r] - m_run);
            e1[r] = __expf(e1[r] - m_run);
        }
        float ss = 0.f;
        #pragma unroll
        for (int r = 0; r < 16; ++r) ss += e0[r] + e1[r];
        s_run += ss;

        #pragma unroll
        for (int r = 0; r < 16; r += 2) {
            const int pidx = ((r & 3) >> 1) + 4*(r >> 2) + 2*h;
            Ppk[pidx*32 + lo5]        = pack2(e0[r], e0[r+1]);
            Ppk[(16 + pidx)*32 + lo5] = pack2(e1[r], e1[r+1]);
        }
        #pragma unroll
        for (int s = 0; s < 4; ++s) {
            union { unsigned u[4]; short8 s8; } P;
            #pragma unroll
            for (int w = 0; w < 4; ++w)
                P.u[w] = Ppk[(s*8 + 4*h + w)*32 + lo5];
            #pragma unroll
            for (int cb = 0; cb < 4; ++cb)
                o[cb] = __builtin_amdgcn_mfma_f32_32x32x16_bf16(vf[s][cb], P.s8, o[cb], 0, 0, 0);
        }
    }

    // ---- publish per-wave (m, s) ----
    const float s_w = s_run + __shfl_xor(s_run, 32);
    if (h == 0) { msArr[wv][lo5] = m_run; ssArr[wv][lo5] = s_w; }
    __syncthreads();                          // all waves done with Ppk too

    // ---- merge: global max, total denominator, per-wave rescale ----
    float M = msArr[0][lo5];
    #pragma unroll
    for (int w = 1; w < 4; ++w) M = fmaxf(M, msArr[w][lo5]);
    float stot = 0.f;
    #pragma unroll
    for (int w = 0; w < 4; ++w) stot += __expf(msArr[w][lo5] - M) * ssArr[w][lo5];
    if (wv == 0 && h == 0) ssum[lo5] = stot;
    const float myscale = __expf(m_run - M);
    #pragma unroll
    for (int cb = 0; cb < 4; ++cb)
        #pragma unroll
        for (int r = 0; r < 16; ++r) o[cb][r] *= myscale;

    // ---- accumulate o across waves into osum (aliases Ppk; 4 passes) ----
    for (int w = 0; w < 4; ++w) {
        if (wv == w) {
            #pragma unroll
            for (int cb = 0; cb < 4; ++cb)
                #pragma unroll
                for (int r = 0; r < 16; ++r) {
                    const int c = cb*32 + (r & 3) + 8*(r >> 2) + 4*h;
                    float* p = &osum[lo5*132 + c];
                    if (w == 0) *p = o[cb][r]; else *p += o[cb][r];
                }
        }
        __syncthreads();
    }

    // ---- normalize + residual, coalesced write ----
    const float g = gamma[0];
    const int q = t >> 3, c0 = (t & 7) * 16;
    const float inv = 1.f / ssum[q];
    const size_t base = (size_t)(q0 + q)*CI + c0;
    #pragma unroll
    for (int j = 0; j < 16; ++j)
        saf[base + j] = g*(osum[q*132 + c0 + j]*inv) + feat1[base + j];
}

// ---------------- K4x: transpose feat2 -> bf16 hi/lo [b][c][HW] --------------
__global__ __launch_bounds__(256)
void k_xpose(const float* __restrict__ feat2,
             char* __restrict__ f2TH, char* __restrict__ f2TL)
{
    __shared__ float Xl[64*129];
    const int t = threadIdx.x;
    const int pb = blockIdx.x * 64;
    const int bb = pb / HWn, pin = pb % HWn;
    for (int idx = t; idx < 64*128; idx += 256) {
        const int p = idx >> 7, ci = idx & 127;
        Xl[p*129 + ci] = feat2[(size_t)(pb + p)*CI + ci];
    }
    __syncthreads();
    const int c = t >> 1, half = t & 1;
    const size_t rowb = ((size_t)(bb*CI + c)*HWn + pin + half*32) * 2;
    #pragma unroll
    for (int j = 0; j < 16; ++j) {
        const float a = Xl[(half*32 + 2*j)*129 + c];
        const float b = Xl[(half*32 + 2*j + 1)*129 + c];
        unsigned hi, lo; split2(a, b, hi, lo);
        *(unsigned*)(f2TH + rowb + 4*j) = hi;
        *(unsigned*)(f2TL + rowb + 4*j) = lo;
    }
}

// ---------------- K4a: CAM energy via MFMA, split-K partials -----------------
__global__ __launch_bounds__(256)
void k_cam_energy_m(const char* __restrict__ f2TH, const char* __restrict__ f2TL,
                    float* __restrict__ epart)
{
    __shared__ __align__(16) char Vh[128*256];
    __shared__ __align__(16) char Vl[128*256];
    const int t = threadIdx.x;
    const int ks = blockIdx.x, bb = blockIdx.y;
    const int l = t & 63, w = t >> 6;
    const int lo5 = l & 31, hf = l >> 5;

    #pragma unroll
    for (int pass = 0; pass < 8; ++pass) {
        const int slot = pass*256 + t;          // 0..2047
        const int c = slot >> 4, g = slot & 15; // 16B granule
        const size_t gaddr = ((size_t)(bb*CI + c)*HWn + ks*128)*2 + g*16;
        const int laddr = c*256 + ((g*16) ^ ((c & 15) << 4));
        *(float4*)(Vh + laddr) = *(const float4*)(f2TH + gaddr);
        *(float4*)(Vl + laddr) = *(const float4*)(f2TL + gaddr);
    }
    __syncthreads();

    f32x16 acc[4];
    #pragma unroll
    for (int nj = 0; nj < 4; ++nj) acc[nj] = f16z();
    const int cA = w*32 + lo5;
    const int swA = (cA & 15) << 4;

    #pragma unroll
    for (int kk = 0; kk < 8; ++kk) {
        const int kb = kk*32 + hf*16;
        const short8 ah = *(const short8*)(Vh + cA*256 + (kb ^ swA));
        const short8 al = *(const short8*)(Vl + cA*256 + (kb ^ swA));
        #pragma unroll
        for (int nj = 0; nj < 4; ++nj) {
            const int dB = nj*32 + lo5;
            const int swB = (dB & 15) << 4;
            const short8 bh = *(const short8*)(Vh + dB*256 + (kb ^ swB));
            const short8 bl = *(const short8*)(Vl + dB*256 + (kb ^ swB));
            acc[nj] = __builtin_amdgcn_mfma_f32_32x32x16_bf16(ah, bh, acc[nj], 0, 0, 0);
            acc[nj] = __builtin_amdgcn_mfma_f32_32x32x16_bf16(al, bh, acc[nj], 0, 0, 0);
            acc[nj] = __builtin_amdgcn_mfma_f32_32x32x16_bf16(ah, bl, acc[nj], 0, 0, 0);
        }
    }
    float* ep = epart + ((size_t)(bb*32 + ks)*CI)*CI;
    #pragma unroll
    for (int nj = 0; nj < 4; ++nj)
        #pragma unroll
        for (int r = 0; r < 16; ++r) {
            const int c = w*32 + (r & 3) + 8*(r >> 2) + 4*hf;
            ep[(size_t)c*CI + nj*32 + lo5] = acc[nj][r];
        }
}

// ---------------- K4b: fused reduce(32 partials) + max-subtract softmax ------
__global__ __launch_bounds__(64)
void k_cam_rs(const float* __restrict__ epart, float* __restrict__ att)
{
    const int lane = threadIdx.x;
    const int row = blockIdx.x;             // b*128 + c
    const int bb = row >> 7, c = row & 127;
    float2 e = make_float2(0.f, 0.f);
    for (int ks = 0; ks < 32; ++ks) {
        const float2 v = *(const float2*)&epart[
            ((size_t)(bb*32 + ks)*CI + c)*CI + lane*2];
        e.x += v.x; e.y += v.y;
    }
    float M = fmaxf(e.x, e.y);
    #pragma unroll
    for (int off = 32; off > 0; off >>= 1) M = fmaxf(M, __shfl_xor(M, off));
    const float en0 = M - e.x, en1 = M - e.y;
    float mx = fmaxf(en0, en1);
    #pragma unroll
    for (int off = 32; off > 0; off >>= 1) mx = fmaxf(mx, __shfl_xor(mx, off));
    const float p0 = __expf(en0 - mx), p1 = __expf(en1 - mx);
    float s = p0 + p1;
    #pragma unroll
    for (int off = 32; off > 0; off >>= 1) s += __shfl_xor(s, off);
    const float inv = 1.f / s;
    float2 o; o.x = p0*inv; o.y = p1*inv;
    *(float2*)&att[(size_t)row*CI + lane*2] = o;
}

// ---------------- K4c: CAM apply: sc = g*(X att^T) + X ----------------------
__global__ __launch_bounds__(256)
void k_cam_apply(const float* __restrict__ feat2, const float* __restrict__ att,
                 const float* __restrict__ gamma, float* __restrict__ sc_feat)
{
    __shared__ float Xl[64*129];
    __shared__ __align__(16) float aT[128*64];
    const int t = threadIdx.x;
    const int pb = blockIdx.x * 64;
    const int bb = pb / HWn;
    const int ch = blockIdx.y * 64;
    for (int idx = t; idx < 64*128; idx += 256) {
        const int p = idx >> 7, ci = idx & 127;
        Xl[p*129 + ci] = feat2[(size_t)(pb + p)*CI + ci];
    }
    for (int idx = t; idx < 128*64; idx += 256) {
        const int d = idx >> 6, cc = idx & 63;
        aT[d*64 + cc] = att[((size_t)bb*CI + ch + cc)*CI + d];
    }
    __syncthreads();
    const int px = t & 63, cg = t >> 6;
    F8 accA = f8zero(), accB = f8zero();
    #pragma unroll 4
    for (int d = 0; d < 128; ++d) {
        const float xv = Xl[px*129 + d];
        const float* ap = &aT[d*64 + cg*16];
        const float4 a0 = *(const float4*)&ap[0];
        const float4 a1 = *(const float4*)&ap[4];
        const float4 a2 = *(const float4*)&ap[8];
        const float4 a3 = *(const float4*)&ap[12];
        fma8(accA, xv, a0, a1);
        fma8(accB, xv, a2, a3);
    }
    const float g = gamma[0];
    const float* fa = (const float*)&accA;
    const float* fb = (const float*)&accB;
    #pragma unroll
    for (int j = 0; j < 8; ++j) {
        const int cA = ch + cg*16 + j;
        const int cB = cA + 8;
        sc_feat[(size_t)(pb + px)*CI + cA] = g*fa[j] + Xl[px*129 + cA];
        sc_feat[(size_t)(pb + px)*CI + cB] = g*fb[j] + Xl[px*129 + cB];
    }
}

// ---------------- K7: final 1x1 conv (sum of two branches) -> out ------------
__global__ __launch_bounds__(256)
void k_final(const float* __restrict__ sa, const float* __restrict__ sc,
             const float* __restrict__ w8, float* __restrict__ out)
{
    __shared__ float Xl[64*129];
    __shared__ float w8l[128*COn];
    const int t = threadIdx.x;
    const int pb = blockIdx.x * 64;
    for (int idx = t; idx < 64*128; idx += 256) {
        const int p = idx >> 7, ci = idx & 127;
        const size_t gi = (size_t)(pb + p)*CI + ci;
        Xl[p*129 + ci] = sa[gi] + sc[gi];
    }
    for (int idx = t; idx < 128*COn; idx += 256) w8l[idx] = w8[idx];
    __syncthreads();
    for (int idx = t; idx < 64*COn; idx += 256) {
        const int p = idx / COn, co = idx - p*COn;
        float acc = 0.f;
        #pragma unroll 8
        for (int ci = 0; ci < 128; ++ci)
            acc = fmaf(Xl[p*129 + ci], w8l[ci*COn + co], acc);
        out[(size_t)(pb + p)*COn + co] = acc;
    }
}

extern "C" void kernel_launch(void* const* d_in, const int* in_sizes, int n_in,
                              void* d_out, int out_size, void* d_ws, size_t ws_size,
                              hipStream_t stream)
{
    const float* x    = (const float*)d_in[0];
    const float* w5a  = (const float*)d_in[1];
    const float* w5c  = (const float*)d_in[2];
    const float* wq   = (const float*)d_in[3];
    const float* bq   = (const float*)d_in[4];
    const float* wk   = (const float*)d_in[5];
    const float* bk   = (const float*)d_in[6];
    const float* wv   = (const float*)d_in[7];
    const float* bv   = (const float*)d_in[8];
    const float* pgam = (const float*)d_in[9];
    const float* cgam = (const float*)d_in[10];
    const float* w51  = (const float*)d_in[11];
    const float* w52  = (const float*)d_in[12];
    const float* w8   = (const float*)d_in[13];
    const float* bn1g = (const float*)d_in[14];
    const float* bn1b = (const float*)d_in[15];
    const float* bn1m = (const float*)d_in[16];
    const float* bn1v = (const float*)d_in[17];
    const float* bn2g = (const float*)d_in[18];
    const float* bn2b = (const float*)d_in[19];
    const float* bn2m = (const float*)d_in[20];
    const float* bn2v = (const float*)d_in[21];
    const float* bn3g = (const float*)d_in[22];
    const float* bn3b = (const float*)d_in[23];
    const float* bn3m = (const float*)d_in[24];
    const float* bn3v = (const float*)d_in[25];
    const float* bn4g = (const float*)d_in[26];
    const float* bn4b = (const float*)d_in[27];
    const float* bn4m = (const float*)d_in[28];
    const float* bn4v = (const float*)d_in[29];

    char* wsb = (char*)d_ws;
    // region [0, 8MB): feat1 (conv1->pam) -> f2TH/f2TL (xpose->energy) -> sa_conv
    float* feat1  = (float*)(wsb + 0);
    char*  f2TH   = wsb + 0;                    // 4 MB
    char*  f2TL   = wsb + 4194304;              // 4 MB
    float* feat2  = (float*)(wsb + 8388608);    // 8 MB (reused as sc_conv)
    float* saf    = (float*)(wsb + 16777216);   // 8 MB
    // region [24MB..32MB): wt1 planes (prep->conv1) -> epart (energy->rs) -> scf
    float* scf    = (float*)(wsb + 25165824);   // 8 MB
    char*  wt1H   = wsb + 25165824;             // 2359296
    char*  wt1L   = wsb + 27525120;             // 2359296 -> 29884416
    float* epart  = (float*)(wsb + 25165824);   // 8 MB (32 slices x 64KB x 4 b)
    float* att    = (float*)(wsb + 33816576);   // 256 KB
    __hip_bfloat16* qb16 = (__hip_bfloat16*)(wsb + 34078720);  // 512 KB
    __hip_bfloat16* kb16 = (__hip_bfloat16*)(wsb + 34603008);  // 512 KB
    __hip_bfloat16* vbT  = (__hip_bfloat16*)(wsb + 35127296);  // 4 MB -> 39321600
    char* wt2aH = wsb + 39321600;               // 294912 -> 39616512
    char* wt2aL = wsb + 39616512;               // 294912 -> 39911424
    char* wt2bH = wsb + 39911424;               // 294912 -> 40206336
    char* wt2bL = wsb + 40206336;               // 294912 -> 40501248
    float* bnAs = (float*)(wsb + 40501248);     // 1 KB each
    float* bnAb = (float*)(wsb + 40502272);
    float* bnBs = (float*)(wsb + 40503296);
    float* bnBb = (float*)(wsb + 40504320);     // high-water 40505344
    float* sa_conv = feat1;                     // feat1/f2T dead after energy
    float* sc_conv = feat2;                     // feat2 dead after cam_apply
    float* out  = (float*)d_out;

    k_prep_w<<<dim3(2880), 256, 0, stream>>>(w5a, w5c, w51, w52,
        wt1H, wt1L, wt2aH, wt2aL, wt2bH, wt2bL);
    k_prep_bn<<<dim3(1), 256, 0, stream>>>(bn1g, bn1b, bn1m, bn1v, bn2g, bn2b, bn2m, bn2v,
                                           bn3g, bn3b, bn3m, bn3v, bn4g, bn4b, bn4m, bn4v,
                                           bnAs, bnAb, bnBs, bnBb);
    k_conv<512, 256, 128><<<dim3(1024), 256, 0, stream>>>(
        x, x, wt1H, wt1L, wt1H, wt1L, bnAs, bnAb, feat1, feat2);
    k_qk<<<dim3(NPIX/64), 256, 0, stream>>>(feat1, wq, bq, wk, bk, qb16, kb16);
    k_v<<<dim3(NPIX/32), 256, 0, stream>>>(feat1, wv, bv, vbT);
    k_pam<<<dim3(NPIX/32), 256, 0, stream>>>(qb16, kb16, vbT, feat1, pgam, saf);
    k_xpose<<<dim3(NPIX/64), 256, 0, stream>>>(feat2, f2TH, f2TL);
    k_cam_energy_m<<<dim3(32, Bn), 256, 0, stream>>>(f2TH, f2TL, epart);
    k_cam_rs<<<dim3(Bn*CI), 64, 0, stream>>>(epart, att);
    k_cam_apply<<<dim3(NPIX/64, 2), 256, 0, stream>>>(feat2, att, cgam, scf);
    k_conv<128, 128, 0><<<dim3(1024), 256, 0, stream>>>(
        saf, scf, wt2aH, wt2aL, wt2bH, wt2bL, bnBs, bnBb, sa_conv, sc_conv);
    k_final<<<dim3(NPIX/64), 256, 0, stream>>>(sa_conv, sc_conv, w8, out);
}

// Round 11
// 341.859 us; speedup vs baseline: 1.9342x; 1.0199x over previous
//
#include <hip/hip_runtime.h>
#include <hip/hip_bf16.h>
#include <math.h>

#define BN_EPS 1e-3f

constexpr int Bn = 4, Hn = 64, Wn = 64, CIN = 512, CI = 128;
constexpr int HWn = Hn * Wn;        // 4096
constexpr int NPIX = Bn * HWn;      // 16384
constexpr int COn = 19;

struct F8 { float4 lo, hi; };

__device__ __forceinline__ F8 f8zero() {
    F8 r; r.lo = make_float4(0.f,0.f,0.f,0.f); r.hi = make_float4(0.f,0.f,0.f,0.f); return r;
}
__device__ __forceinline__ void fma8(F8 &acc, float a, const float4 &wlo, const float4 &whi) {
    acc.lo.x = fmaf(a, wlo.x, acc.lo.x);
    acc.lo.y = fmaf(a, wlo.y, acc.lo.y);
    acc.lo.z = fmaf(a, wlo.z, acc.lo.z);
    acc.lo.w = fmaf(a, wlo.w, acc.lo.w);
    acc.hi.x = fmaf(a, whi.x, acc.hi.x);
    acc.hi.y = fmaf(a, whi.y, acc.hi.y);
    acc.hi.z = fmaf(a, whi.z, acc.hi.z);
    acc.hi.w = fmaf(a, whi.w, acc.hi.w);
}

// ---- MFMA helpers -----------------------------------------------------------
typedef __attribute__((ext_vector_type(8)))  short short8;   // 8 bf16 in 4 VGPRs
typedef __attribute__((ext_vector_type(16))) float f32x16;

__device__ __forceinline__ f32x16 f16z() {
    f32x16 z;
    #pragma unroll
    for (int i = 0; i < 16; ++i) z[i] = 0.f;
    return z;
}
// fp32 -> bf16 (RNE), pure integer ops (used by prep kernels)
__device__ __forceinline__ unsigned f2b(float f) {
    union { float f; unsigned u; } c; c.f = f;
    return (c.u + 0x7FFFu + ((c.u >> 16) & 1u)) >> 16;
}
__device__ __forceinline__ unsigned pack2(float lo, float hi) {
    return (f2b(hi) << 16) | f2b(lo);
}
// split (a,b) into packed bf16 hi words + bf16 lo residuals (a in low half)
__device__ __forceinline__ void split2(float a, float b, unsigned &hi, unsigned &lo) {
    const unsigned ha = f2b(a), hb = f2b(b);
    union { unsigned u; float f; } ua, ub; ua.u = ha << 16; ub.u = hb << 16;
    hi = (hb << 16) | ha;
    lo = pack2(a - ua.f, b - ub.f);
}
// cvt-based split (hot path): compiler emits v_cvt for __float2bfloat16
__device__ __forceinline__ void split2c(float a, float b, unsigned &hi, unsigned &lo) {
    __hip_bfloat16 ha = __float2bfloat16(a);
    __hip_bfloat16 hb = __float2bfloat16(b);
    const unsigned ua = *(unsigned short*)&ha, ub = *(unsigned short*)&hb;
    hi = (ub << 16) | ua;
    const float fa = __uint_as_float(ua << 16), fb = __uint_as_float(ub << 16);
    __hip_bfloat16 la = __float2bfloat16(a - fa);
    __hip_bfloat16 lb = __float2bfloat16(b - fb);
    lo = ((unsigned)*(unsigned short*)&lb << 16) | *(unsigned short*)&la;
}

// ---------------- prep: weights -> bf16 hi/lo, co-major, LINEAR --------------
__global__ __launch_bounds__(256)
void k_prep_w(const float* __restrict__ w5a, const float* __restrict__ w5c,
              const float* __restrict__ w51, const float* __restrict__ w52,
              char* __restrict__ wt1H, char* __restrict__ wt1L,
              char* __restrict__ wt2aH, char* __restrict__ wt2aL,
              char* __restrict__ wt2bH, char* __restrict__ wt2bL)
{
    int idx = blockIdx.x * 256 + threadIdx.x;
    if (idx < 589824) {                       // 32*9*256*8 pairs
        const int jp = idx & 7, co = (idx >> 3) & 255, ct = idx >> 11; // ct=c*9+tap
        const int tap = ct % 9, c = ct / 9;
        const float* src = (co < 128) ? w5a : w5c;
        const int coc = co & 127;
        const int ci = c*16 + jp*2;
        const float a = src[((size_t)tap*CIN + ci)*CI + coc];
        const float b = src[((size_t)tap*CIN + ci + 1)*CI + coc];
        unsigned hi, lo; split2(a, b, hi, lo);
        const int L = co*32 + jp*4;
        *(unsigned*)(wt1H + (size_t)ct*8192 + L) = hi;
        *(unsigned*)(wt1L + (size_t)ct*8192 + L) = lo;
    } else {
        int k = idx - 589824;                 // 2 * 8*9*128*8 pairs
        if (k >= 147456) return;
        const float* src = (k < 73728) ? w51 : w52;
        char* dstH = (k < 73728) ? wt2aH : wt2bH;
        char* dstL = (k < 73728) ? wt2aL : wt2bL;
        if (k >= 73728) k -= 73728;
        const int jp = k & 7, co = (k >> 3) & 127, ct = k >> 10; // ct=c*9+tap
        const int tap = ct % 9, c = ct / 9;
        const int ci = c*16 + jp*2;
        const float a = src[((size_t)tap*CI + ci)*CI + co];
        const float b = src[((size_t)tap*CI + ci + 1)*CI + co];
        unsigned hi, lo; split2(a, b, hi, lo);
        const int L = co*32 + jp*4;
        *(unsigned*)(dstH + (size_t)ct*4096 + L) = hi;
        *(unsigned*)(dstL + (size_t)ct*4096 + L) = lo;
    }
}

// ---------------- prep: BN -> folded scale/bias tables -----------------------
__global__ __launch_bounds__(256)
void k_prep_bn(const float* g1, const float* b1, const float* m1, const float* v1,
               const float* g2, const float* b2, const float* m2, const float* v2,
               const float* g3, const float* b3, const float* m3, const float* v3,
               const float* g4, const float* b4, const float* m4, const float* v4,
               float* bnAs, float* bnAb, float* bnBs, float* bnBb)
{
    const int t = threadIdx.x, c = t & 127;
    {
        const float *g = (t < 128) ? g1 : g2, *b = (t < 128) ? b1 : b2;
        const float *m = (t < 128) ? m1 : m2, *v = (t < 128) ? v1 : v2;
        const float s = g[c] * rsqrtf(v[c] + BN_EPS);
        bnAs[t] = s; bnAb[t] = b[c] - m[c]*s;
    }
    {
        const float *g = (t < 128) ? g3 : g4, *b = (t < 128) ? b3 : b4;
        const float *m = (t < 128) ? m3 : m4, *v = (t < 128) ? v3 : v4;
        const float s = g[c] * rsqrtf(v[c] + BN_EPS);
        bnBs[t] = s; bnBb[t] = b[c] - m[c]*s;
    }
}

// ---------------- MFMA 3x3 conv, bf16x3 split + folded BN + ReLU -------------
// Grid 1024: xcd=wgid&7 -> sel, ch2, row (XCD-clustered W working set).
// Block = one row x 64 co, 4 waves; wave = 1 M-tile x 1 N-tile (balanced
// MFMA<->LDS at 16 waves/CU). X LDS DOUBLE-BUFFERED (1 barrier/chunk);
// stage decode hoisted to per-thread constants; cvt-based bf16 split.
// W: global->VGPR rolling dy-group double-buffer, issued pre-barrier.
// mfma(A=W^T[co][k], B=X[px][k]) -> D[col=px][row=co]  (k_pam-validated map)
template<int CICH, int NCOTOT, int WCOBASE>
__global__ __launch_bounds__(256)
void k_conv(const float* __restrict__ xin0, const float* __restrict__ xin1,
            const char* __restrict__ wtH0, const char* __restrict__ wtL0,
            const char* __restrict__ wtH1, const char* __restrict__ wtL1,
            const float* __restrict__ bnS, const float* __restrict__ bnBi,
            float* __restrict__ out0, float* __restrict__ out1)
{
    constexpr int NCHNK = CICH / 16;
    constexpr int XPAGE = 66 * 32;            // 2112 B per staged row
    constexpr int XBUF  = 3 * XPAGE;          // 6336 B per plane per buffer
    __shared__ __align__(16) char Xs[4*XBUF]; // [buf0 h][buf0 l][buf1 h][buf1 l]

    const int t    = threadIdx.x;
    const int wgid = blockIdx.x;              // 1024
    const int xcd  = wgid & 7;
    const int sel  = xcd >> 2;
    const int ch2  = (xcd >> 1) & 1;
    const int row  = ((wgid >> 3) << 1) | (xcd & 1);   // 0..255 = b*64 + h
    const float* xin = sel ? xin1 : xin0;
    const char*  wtH = sel ? wtH1 : wtH0;
    const char*  wtL = sel ? wtL1 : wtL0;
    float*       dst = sel ? out1 : out0;

    const int bb  = row >> 6, hh = row & 63;
    const int dyLo = (hh == 0)  ? 1 : 0;
    const int dyHi = (hh == 63) ? 1 : 2;
    const int l = t & 63, w = t >> 6;
    const int lo5 = l & 31, hf = l >> 5;
    const int mi = w >> 1, nt = w & 1;
    const int corow = WCOBASE*sel + ch2*64 + nt*32 + lo5;

    // ---- hoisted stage-decode constants (chunk-invariant) ----
    bool    sAct[4], sIn[4];
    int     sLoff[4];
    size_t  sGoff[4];
    #pragma unroll
    for (int i = 0; i < 4; ++i) {
        const int u = t + i*256;
        sAct[i] = false; sIn[i] = false; sLoff[i] = 0; sGoff[i] = 0;
        if (u < 792) {
            const int dyr = u/264, rs = u - dyr*264;
            const int s = rs >> 2, u4 = rs & 3;
            sAct[i]  = (dyr >= dyLo && dyr <= dyHi);
            sIn[i]   = (s >= 1 && s <= 64);
            sLoff[i] = dyr*XPAGE + ((s*32 + u4*8) ^ ((s & 7) << 4));
            sGoff[i] = (((size_t)bb*Hn + (hh + dyr - 1))*Wn + (s - 1))*CICH + u4*4;
        }
    }
    // hoisted compute X offsets (dx = 0,1,2), page-relative
    int xoff[3];
    #pragma unroll
    for (int dx = 0; dx < 3; ++dx) {
        const int s = mi*32 + lo5 + dx;
        xoff[dx] = (s*32 + hf*16) ^ ((s & 7) << 4);
    }

    f32x16 acc = f16z();
    short8 whA[3], wlA[3], whB[3], wlB[3];

    auto issueW = [&](int c, int dy, short8 (&h)[3], short8 (&lw)[3]) {
        #pragma unroll
        for (int dx = 0; dx < 3; ++dx) {
            const size_t wo = ((size_t)(c*9 + dy*3 + dx)*NCOTOT + corow)*32 + hf*16;
            h[dx]  = *(const short8*)(wtH + wo);
            lw[dx] = *(const short8*)(wtL + wo);
        }
    };
    auto compDy = [&](const char* Xh, const char* Xl, int dy,
                      const short8 (&h)[3], const short8 (&lw)[3]) {
        const char* Xph = Xh + dy*XPAGE;
        const char* Xpl = Xl + dy*XPAGE;
        #pragma unroll
        for (int dx = 0; dx < 3; ++dx) {
            const short8 xfh = *(const short8*)(Xph + xoff[dx]);
            const short8 xfl = *(const short8*)(Xpl + xoff[dx]);
            acc = __builtin_amdgcn_mfma_f32_32x32x16_bf16(h[dx],  xfh, acc, 0, 0, 0);
            acc = __builtin_amdgcn_mfma_f32_32x32x16_bf16(h[dx],  xfl, acc, 0, 0, 0);
            acc = __builtin_amdgcn_mfma_f32_32x32x16_bf16(lw[dx], xfh, acc, 0, 0, 0);
        }
    };

    float4 xr[4];
    // ---- prefetch chunk 0's X ----
    #pragma unroll
    for (int i = 0; i < 4; ++i) {
        float4 v = make_float4(0.f,0.f,0.f,0.f);
        if (sAct[i] && sIn[i]) v = *(const float4*)&xin[sGoff[i]];
        xr[i] = v;
    }

    int p = 0;
    for (int c = 0; c < NCHNK; ++c) {
        char* Xh = Xs + p*2*XBUF;
        char* Xl = Xh + XBUF;
        // ---- issue W for first two dy-groups (ride the barrier drain) ----
        issueW(c, dyLo, whA, wlA);
        if (dyLo + 1 <= dyHi) issueW(c, dyLo + 1, whB, wlB);
        // ---- stage-write chunk c into buf p (decode hoisted) ----
        #pragma unroll
        for (int i = 0; i < 4; ++i) {
            if (sAct[i]) {
                uint2 vh, vl;
                split2c(xr[i].x, xr[i].y, vh.x, vl.x);
                split2c(xr[i].z, xr[i].w, vh.y, vl.y);
                *(uint2*)(Xh + sLoff[i]) = vh;
                *(uint2*)(Xl + sLoff[i]) = vl;
            }
        }
        __syncthreads();                      // single barrier per chunk
        // ---- prefetch chunk c+1's X (flies under compute) ----
        if (c + 1 < NCHNK) {
            #pragma unroll
            for (int i = 0; i < 4; ++i) {
                float4 v = make_float4(0.f,0.f,0.f,0.f);
                if (sAct[i] && sIn[i])
                    v = *(const float4*)&xin[sGoff[i] + (size_t)(c + 1)*16];
                xr[i] = v;
            }
        }
        // ---- compute dy-groups, rolling W double-buffer ----
        compDy(Xh, Xl, dyLo, whA, wlA);
        if (dyLo + 1 <= dyHi) {
            if (dyLo + 2 <= dyHi) issueW(c, dyLo + 2, whA, wlA);
            compDy(Xh, Xl, dyLo + 1, whB, wlB);
            if (dyLo + 2 <= dyHi) compDy(Xh, Xl, dyLo + 2, whA, wlA);
        }
        p ^= 1;
    }
    // ---- epilogue: folded BN + ReLU ----
    const int px = mi*32 + lo5;
    const size_t pg = (size_t)row*Wn + px;
    #pragma unroll
    for (int r = 0; r < 16; ++r) {
        const int crow = (r & 3) + 8*(r >> 2) + 4*hf;
        const int och = ch2*64 + nt*32 + crow;
        const int bnidx = sel*128 + och;
        dst[pg*CI + och] = fmaxf(fmaf(acc[r], bnS[bnidx], bnBi[bnidx]), 0.f);
    }
}

// ---------------- K2a: q,k 1x1 conv -> bf16 [NPIX][16] each ------------------
__global__ __launch_bounds__(256)
void k_qk(const float* __restrict__ feat1,
          const float* __restrict__ wq, const float* __restrict__ bq,
          const float* __restrict__ wk, const float* __restrict__ bk,
          __hip_bfloat16* __restrict__ qb, __hip_bfloat16* __restrict__ kb)
{
    __shared__ float Al[64*129];
    __shared__ __align__(16) float Wl[128*32];
    const int t = threadIdx.x;
    const int pb = blockIdx.x * 64;
    for (int idx = t; idx < 64*128; idx += 256) {
        const int p = idx >> 7, ci = idx & 127;
        Al[p*129 + ci] = feat1[(size_t)(pb + p)*CI + ci];
    }
    for (int idx = t; idx < 128*32; idx += 256) {
        const int ci = idx >> 5, c = idx & 31;
        Wl[idx] = (c < 16) ? wq[ci*16 + c] : wk[ci*16 + (c - 16)];
    }
    __syncthreads();
    const int p = t & 63, cg = t >> 6, co = cg * 8;
    F8 acc = f8zero();
    #pragma unroll 8
    for (int ci = 0; ci < 128; ++ci) {
        const float a = Al[p*129 + ci];
        const float4 wlo = *(const float4*)&Wl[ci*32 + co];
        const float4 whi = *(const float4*)&Wl[ci*32 + co + 4];
        fma8(acc, a, wlo, whi);
    }
    const float* af = (const float*)&acc;
    #pragma unroll
    for (int j = 0; j < 8; ++j) {
        const int c = co + j;
        if (c < 16) qb[(size_t)(pb + p)*16 + c]        = __float2bfloat16(af[j] + bq[c]);
        else        kb[(size_t)(pb + p)*16 + (c - 16)] = __float2bfloat16(af[j] + bk[c - 16]);
    }
}

// ---------------- K2b: v 1x1 conv -> bf16 TRANSPOSED [b][c][pix] -------------
__global__ __launch_bounds__(256)
void k_v(const float* __restrict__ feat1, const float* __restrict__ wv,
         const float* __restrict__ bv, __hip_bfloat16* __restrict__ vbT)
{
    __shared__ float Al[32*129];
    __shared__ __align__(16) float Wl[64*128];
    const int t = threadIdx.x;
    const int pb = blockIdx.x * 32;
    for (int idx = t; idx < 32*128; idx += 256) {
        const int p = idx >> 7, ci = idx & 127;
        Al[p*129 + ci] = feat1[(size_t)(pb + p)*CI + ci];
    }
    const int px = t & 15, co = (t >> 4) * 8;
    F8 acc0 = f8zero(), acc1 = f8zero();
    for (int ch = 0; ch < 2; ++ch) {
        __syncthreads();
        #pragma unroll
        for (int r = 0; r < 8; ++r) {
            const int i4 = t + r*256;
            const int kk = i4 >> 5, c4 = (i4 & 31) * 4;
            *(float4*)&Wl[kk*128 + c4] = *(const float4*)&wv[(size_t)(ch*64 + kk)*CI + c4];
        }
        __syncthreads();
        #pragma unroll 4
        for (int kk = 0; kk < 64; ++kk) {
            const float a0 = Al[px*129 + ch*64 + kk];
            const float a1 = Al[(px+16)*129 + ch*64 + kk];
            const float4 wlo = *(const float4*)&Wl[kk*128 + co];
            const float4 whi = *(const float4*)&Wl[kk*128 + co + 4];
            fma8(acc0, a0, wlo, whi);
            fma8(acc1, a1, wlo, whi);
        }
    }
    const int p0 = pb + px;
    const int bb = p0 / HWn, pin0 = p0 % HWn;
    const float* a0f = (const float*)&acc0;
    const float* a1f = (const float*)&acc1;
    #pragma unroll
    for (int j = 0; j < 8; ++j) {
        const int c = co + j;
        const size_t rowb = ((size_t)bb*CI + c) * HWn;
        vbT[rowb + pin0]      = __float2bfloat16(a0f[j] + bv[c]);
        vbT[rowb + pin0 + 16] = __float2bfloat16(a1f[j] + bv[c]);
    }
}

// ---------------- K3: PAM flash attention, 4-wave K-split --------------------
__global__ __launch_bounds__(256)
void k_pam(const __hip_bfloat16* __restrict__ qb, const __hip_bfloat16* __restrict__ kb,
           const __hip_bfloat16* __restrict__ vbT, const float* __restrict__ feat1,
           const float* __restrict__ gamma, float* __restrict__ saf)
{
    __shared__ __align__(16) char pbuf[16896];   // Ppk[4][1024 u32] -> osum[32][132] f32
    __shared__ float msArr[4][32];
    __shared__ float ssArr[4][32];
    __shared__ float ssum[32];
    const int t  = threadIdx.x;
    const int wv = t >> 6, l = t & 63;
    const int lo5 = l & 31, h = l >> 5;
    unsigned* Ppk = (unsigned*)(pbuf + wv*4096);
    float* osum = (float*)pbuf;

    const int q0 = blockIdx.x * 32;
    const int bb = q0 / HWn;
    const size_t jb = (size_t)bb * HWn;
    const __hip_bfloat16* vbB = vbT + (size_t)bb * CI * HWn;

    const short8 qfrag = *(const short8*)&qb[(size_t)(q0 + lo5)*16 + 8*h];
    const f32x16 zro = f16z();

    f32x16 o[4];
    #pragma unroll
    for (int cb = 0; cb < 4; ++cb) o[cb] = f16z();

    float m_run = -1e30f, s_run = 0.f;

    for (int k0 = wv*1024; k0 < wv*1024 + 1024; k0 += 64) {
        const short8 kf0 = *(const short8*)&kb[(jb + k0 +      lo5)*16 + 8*h];
        const short8 kf1 = *(const short8*)&kb[(jb + k0 + 32 + lo5)*16 + 8*h];
        short8 vf[4][4];
        #pragma unroll
        for (int s = 0; s < 4; ++s)
            #pragma unroll
            for (int cb = 0; cb < 4; ++cb)
                vf[s][cb] = *(const short8*)&vbB[((size_t)(cb*32 + lo5))*HWn + k0 + s*16 + 8*h];

        f32x16 e0 = __builtin_amdgcn_mfma_f32_32x32x16_bf16(kf0, qfrag, zro, 0, 0, 0);
        f32x16 e1 = __builtin_amdgcn_mfma_f32_32x32x16_bf16(kf1, qfrag, zro, 0, 0, 0);

        float mt = fmaxf(e0[0], e1[0]);
        #pragma unroll
        for (int r = 1; r < 16; ++r) mt = fmaxf(mt, fmaxf(e0[r], e1[r]));
        mt = fmaxf(mt, __shfl_xor(mt, 32));

        if (__any(mt > m_run + 8.f)) {
            const float mnew = fmaxf(m_run, mt);
            const float sc = __expf(m_run - mnew);
            s_run *= sc;
            #pragma unroll
            for (int cb = 0; cb < 4; ++cb)
                #pragma unroll
                for (int r = 0; r < 16; ++r) o[cb][r] *= sc;
            m_run = mnew;
        }

        #pragma unroll
        for (int r = 0; r < 16; ++r) {
            e0[r] = __expf(e0[r] - m_run);
            e1[r] = __expf(e1[r] - m_run);
        }
        float ss = 0.f;
        #pragma unroll
        for (int r = 0; r < 16; ++r) ss += e0[r] + e1[r];
        s_run += ss;

        #pragma unroll
        for (int r = 0; r < 16; r += 2) {
            const int pidx = ((r & 3) >> 1) + 4*(r >> 2) + 2*h;
            Ppk[pidx*32 + lo5]        = pack2(e0[r], e0[r+1]);
            Ppk[(16 + pidx)*32 + lo5] = pack2(e1[r], e1[r+1]);
        }
        #pragma unroll
        for (int s = 0; s < 4; ++s) {
            union { unsigned u[4]; short8 s8; } P;
            #pragma unroll
            for (int w = 0; w < 4; ++w)
                P.u[w] = Ppk[(s*8 + 4*h + w)*32 + lo5];
            #pragma unroll
            for (int cb = 0; cb < 4; ++cb)
                o[cb] = __builtin_amdgcn_mfma_f32_32x32x16_bf16(vf[s][cb], P.s8, o[cb], 0, 0, 0);
        }
    }

    // ---- publish per-wave (m, s) ----
    const float s_w = s_run + __shfl_xor(s_run, 32);
    if (h == 0) { msArr[wv][lo5] = m_run; ssArr[wv][lo5] = s_w; }
    __syncthreads();                          // all waves done with Ppk too

    // ---- merge: global max, total denominator, per-wave rescale ----
    float M = msArr[0][lo5];
    #pragma unroll
    for (int w = 1; w < 4; ++w) M = fmaxf(M, msArr[w][lo5]);
    float stot = 0.f;
    #pragma unroll
    for (int w = 0; w < 4; ++w) stot += __expf(msArr[w][lo5] - M) * ssArr[w][lo5];
    if (wv == 0 && h == 0) ssum[lo5] = stot;
    const float myscale = __expf(m_run - M);
    #pragma unroll
    for (int cb = 0; cb < 4; ++cb)
        #pragma unroll
        for (int r = 0; r < 16; ++r) o[cb][r] *= myscale;

    // ---- accumulate o across waves into osum (aliases Ppk; 4 passes) ----
    for (int w = 0; w < 4; ++w) {
        if (wv == w) {
            #pragma unroll
            for (int cb = 0; cb < 4; ++cb)
                #pragma unroll
                for (int r = 0; r < 16; ++r) {
                    const int c = cb*32 + (r & 3) + 8*(r >> 2) + 4*h;
                    float* p = &osum[lo5*132 + c];
                    if (w == 0) *p = o[cb][r]; else *p += o[cb][r];
                }
        }
        __syncthreads();
    }

    // ---- normalize + residual, coalesced write ----
    const float g = gamma[0];
    const int q = t >> 3, c0 = (t & 7) * 16;
    const float inv = 1.f / ssum[q];
    const size_t base = (size_t)(q0 + q)*CI + c0;
    #pragma unroll
    for (int j = 0; j < 16; ++j)
        saf[base + j] = g*(osum[q*132 + c0 + j]*inv) + feat1[base + j];
}

// ---------------- K4x: transpose feat2 -> bf16 hi/lo [b][c][HW] --------------
__global__ __launch_bounds__(256)
void k_xpose(const float* __restrict__ feat2,
             char* __restrict__ f2TH, char* __restrict__ f2TL)
{
    __shared__ float Xl[64*129];
    const int t = threadIdx.x;
    const int pb = blockIdx.x * 64;
    const int bb = pb / HWn, pin = pb % HWn;
    for (int idx = t; idx < 64*128; idx += 256) {
        const int p = idx >> 7, ci = idx & 127;
        Xl[p*129 + ci] = feat2[(size_t)(pb + p)*CI + ci];
    }
    __syncthreads();
    const int c = t >> 1, half = t & 1;
    const size_t rowb = ((size_t)(bb*CI + c)*HWn + pin + half*32) * 2;
    #pragma unroll
    for (int j = 0; j < 16; ++j) {
        const float a = Xl[(half*32 + 2*j)*129 + c];
        const float b = Xl[(half*32 + 2*j + 1)*129 + c];
        unsigned hi, lo; split2(a, b, hi, lo);
        *(unsigned*)(f2TH + rowb + 4*j) = hi;
        *(unsigned*)(f2TL + rowb + 4*j) = lo;
    }
}

// ---------------- K4a: CAM energy via MFMA, split-K partials -----------------
__global__ __launch_bounds__(256)
void k_cam_energy_m(const char* __restrict__ f2TH, const char* __restrict__ f2TL,
                    float* __restrict__ epart)
{
    __shared__ __align__(16) char Vh[128*256];
    __shared__ __align__(16) char Vl[128*256];
    const int t = threadIdx.x;
    const int ks = blockIdx.x, bb = blockIdx.y;
    const int l = t & 63, w = t >> 6;
    const int lo5 = l & 31, hf = l >> 5;

    #pragma unroll
    for (int pass = 0; pass < 8; ++pass) {
        const int slot = pass*256 + t;          // 0..2047
        const int c = slot >> 4, g = slot & 15; // 16B granule
        const size_t gaddr = ((size_t)(bb*CI + c)*HWn + ks*128)*2 + g*16;
        const int laddr = c*256 + ((g*16) ^ ((c & 15) << 4));
        *(float4*)(Vh + laddr) = *(const float4*)(f2TH + gaddr);
        *(float4*)(Vl + laddr) = *(const float4*)(f2TL + gaddr);
    }
    __syncthreads();

    f32x16 acc[4];
    #pragma unroll
    for (int nj = 0; nj < 4; ++nj) acc[nj] = f16z();
    const int cA = w*32 + lo5;
    const int swA = (cA & 15) << 4;

    #pragma unroll
    for (int kk = 0; kk < 8; ++kk) {
        const int kb = kk*32 + hf*16;
        const short8 ah = *(const short8*)(Vh + cA*256 + (kb ^ swA));
        const short8 al = *(const short8*)(Vl + cA*256 + (kb ^ swA));
        #pragma unroll
        for (int nj = 0; nj < 4; ++nj) {
            const int dB = nj*32 + lo5;
            const int swB = (dB & 15) << 4;
            const short8 bh = *(const short8*)(Vh + dB*256 + (kb ^ swB));
            const short8 bl = *(const short8*)(Vl + dB*256 + (kb ^ swB));
            acc[nj] = __builtin_amdgcn_mfma_f32_32x32x16_bf16(ah, bh, acc[nj], 0, 0, 0);
            acc[nj] = __builtin_amdgcn_mfma_f32_32x32x16_bf16(al, bh, acc[nj], 0, 0, 0);
            acc[nj] = __builtin_amdgcn_mfma_f32_32x32x16_bf16(ah, bl, acc[nj], 0, 0, 0);
        }
    }
    float* ep = epart + ((size_t)(bb*32 + ks)*CI)*CI;
    #pragma unroll
    for (int nj = 0; nj < 4; ++nj)
        #pragma unroll
        for (int r = 0; r < 16; ++r) {
            const int c = w*32 + (r & 3) + 8*(r >> 2) + 4*hf;
            ep[(size_t)c*CI + nj*32 + lo5] = acc[nj][r];
        }
}

// ---------------- K4b: fused reduce(32 partials) + max-subtract softmax ------
__global__ __launch_bounds__(64)
void k_cam_rs(const float* __restrict__ epart, float* __restrict__ att)
{
    const int lane = threadIdx.x;
    const int row = blockIdx.x;             // b*128 + c
    const int bb = row >> 7, c = row & 127;
    float2 e = make_float2(0.f, 0.f);
    for (int ks = 0; ks < 32; ++ks) {
        const float2 v = *(const float2*)&epart[
            ((size_t)(bb*32 + ks)*CI + c)*CI + lane*2];
        e.x += v.x; e.y += v.y;
    }
    float M = fmaxf(e.x, e.y);
    #pragma unroll
    for (int off = 32; off > 0; off >>= 1) M = fmaxf(M, __shfl_xor(M, off));
    const float en0 = M - e.x, en1 = M - e.y;
    float mx = fmaxf(en0, en1);
    #pragma unroll
    for (int off = 32; off > 0; off >>= 1) mx = fmaxf(mx, __shfl_xor(mx, off));
    const float p0 = __expf(en0 - mx), p1 = __expf(en1 - mx);
    float s = p0 + p1;
    #pragma unroll
    for (int off = 32; off > 0; off >>= 1) s += __shfl_xor(s, off);
    const float inv = 1.f / s;
    float2 o; o.x = p0*inv; o.y = p1*inv;
    *(float2*)&att[(size_t)row*CI + lane*2] = o;
}

// ---------------- K4c: CAM apply: sc = g*(X att^T) + X ----------------------
__global__ __launch_bounds__(256)
void k_cam_apply(const float* __restrict__ feat2, const float* __restrict__ att,
                 const float* __restrict__ gamma, float* __restrict__ sc_feat)
{
    __shared__ float Xl[64*129];
    __shared__ __align__(16) float aT[128*64];
    const int t = threadIdx.x;
    const int pb = blockIdx.x * 64;
    const int bb = pb / HWn;
    const int ch = blockIdx.y * 64;
    for (int idx = t; idx < 64*128; idx += 256) {
        const int p = idx >> 7, ci = idx & 127;
        Xl[p*129 + ci] = feat2[(size_t)(pb + p)*CI + ci];
    }
    for (int idx = t; idx < 128*64; idx += 256) {
        const int d = idx >> 6, cc = idx & 63;
        aT[d*64 + cc] = att[((size_t)bb*CI + ch + cc)*CI + d];
    }
    __syncthreads();
    const int px = t & 63, cg = t >> 6;
    F8 accA = f8zero(), accB = f8zero();
    #pragma unroll 4
    for (int d = 0; d < 128; ++d) {
        const float xv = Xl[px*129 + d];
        const float* ap = &aT[d*64 + cg*16];
        const float4 a0 = *(const float4*)&ap[0];
        const float4 a1 = *(const float4*)&ap[4];
        const float4 a2 = *(const float4*)&ap[8];
        const float4 a3 = *(const float4*)&ap[12];
        fma8(accA, xv, a0, a1);
        fma8(accB, xv, a2, a3);
    }
    const float g = gamma[0];
    const float* fa = (const float*)&accA;
    const float* fb = (const float*)&accB;
    #pragma unroll
    for (int j = 0; j < 8; ++j) {
        const int cA = ch + cg*16 + j;
        const int cB = cA + 8;
        sc_feat[(size_t)(pb + px)*CI + cA] = g*fa[j] + Xl[px*129 + cA];
        sc_feat[(size_t)(pb + px)*CI + cB] = g*fb[j] + Xl[px*129 + cB];
    }
}

// ---------------- K7: final 1x1 conv (sum of two branches) -> out ------------
__global__ __launch_bounds__(256)
void k_final(const float* __restrict__ sa, const float* __restrict__ sc,
             const float* __restrict__ w8, float* __restrict__ out)
{
    __shared__ float Xl[64*129];
    __shared__ float w8l[128*COn];
    const int t = threadIdx.x;
    const int pb = blockIdx.x * 64;
    for (int idx = t; idx < 64*128; idx += 256) {
        const int p = idx >> 7, ci = idx & 127;
        const size_t gi = (size_t)(pb + p)*CI + ci;
        Xl[p*129 + ci] = sa[gi] + sc[gi];
    }
    for (int idx = t; idx < 128*COn; idx += 256) w8l[idx] = w8[idx];
    __syncthreads();
    for (int idx = t; idx < 64*COn; idx += 256) {
        const int p = idx / COn, co = idx - p*COn;
        float acc = 0.f;
        #pragma unroll 8
        for (int ci = 0; ci < 128; ++ci)
            acc = fmaf(Xl[p*129 + ci], w8l[ci*COn + co], acc);
        out[(size_t)(pb + p)*COn + co] = acc;
    }
}

extern "C" void kernel_launch(void* const* d_in, const int* in_sizes, int n_in,
                              void* d_out, int out_size, void* d_ws, size_t ws_size,
                              hipStream_t stream)
{
    const float* x    = (const float*)d_in[0];
    const float* w5a  = (const float*)d_in[1];
    const float* w5c  = (const float*)d_in[2];
    const float* wq   = (const float*)d_in[3];
    const float* bq   = (const float*)d_in[4];
    const float* wk   = (const float*)d_in[5];
    const float* bk   = (const float*)d_in[6];
    const float* wv   = (const float*)d_in[7];
    const float* bv   = (const float*)d_in[8];
    const float* pgam = (const float*)d_in[9];
    const float* cgam = (const float*)d_in[10];
    const float* w51  = (const float*)d_in[11];
    const float* w52  = (const float*)d_in[12];
    const float* w8   = (const float*)d_in[13];
    const float* bn1g = (const float*)d_in[14];
    const float* bn1b = (const float*)d_in[15];
    const float* bn1m = (const float*)d_in[16];
    const float* bn1v = (const float*)d_in[17];
    const float* bn2g = (const float*)d_in[18];
    const float* bn2b = (const float*)d_in[19];
    const float* bn2m = (const float*)d_in[20];
    const float* bn2v = (const float*)d_in[21];
    const float* bn3g = (const float*)d_in[22];
    const float* bn3b = (const float*)d_in[23];
    const float* bn3m = (const float*)d_in[24];
    const float* bn3v = (const float*)d_in[25];
    const float* bn4g = (const float*)d_in[26];
    const float* bn4b = (const float*)d_in[27];
    const float* bn4m = (const float*)d_in[28];
    const float* bn4v = (const float*)d_in[29];

    char* wsb = (char*)d_ws;
    // region [0, 8MB): feat1 (conv1->pam) -> f2TH/f2TL (xpose->energy) -> sa_conv
    float* feat1  = (float*)(wsb + 0);
    char*  f2TH   = wsb + 0;                    // 4 MB
    char*  f2TL   = wsb + 4194304;              // 4 MB
    float* feat2  = (float*)(wsb + 8388608);    // 8 MB (reused as sc_conv)
    float* saf    = (float*)(wsb + 16777216);   // 8 MB
    // region [24MB..32MB): wt1 planes (prep->conv1) -> epart (energy->rs) -> scf
    float* scf    = (float*)(wsb + 25165824);   // 8 MB
    char*  wt1H   = wsb + 25165824;             // 2359296
    char*  wt1L   = wsb + 27525120;             // 2359296 -> 29884416
    float* epart  = (float*)(wsb + 25165824);   // 8 MB (32 slices x 64KB x 4 b)
    float* att    = (float*)(wsb + 33816576);   // 256 KB
    __hip_bfloat16* qb16 = (__hip_bfloat16*)(wsb + 34078720);  // 512 KB
    __hip_bfloat16* kb16 = (__hip_bfloat16*)(wsb + 34603008);  // 512 KB
    __hip_bfloat16* vbT  = (__hip_bfloat16*)(wsb + 35127296);  // 4 MB -> 39321600
    char* wt2aH = wsb + 39321600;               // 294912 -> 39616512
    char* wt2aL = wsb + 39616512;               // 294912 -> 39911424
    char* wt2bH = wsb + 39911424;               // 294912 -> 40206336
    char* wt2bL = wsb + 40206336;               // 294912 -> 40501248
    float* bnAs = (float*)(wsb + 40501248);     // 1 KB each
    float* bnAb = (float*)(wsb + 40502272);
    float* bnBs = (float*)(wsb + 40503296);
    float* bnBb = (float*)(wsb + 40504320);     // high-water 40505344
    float* sa_conv = feat1;                     // feat1/f2T dead after energy
    float* sc_conv = feat2;                     // feat2 dead after cam_apply
    float* out  = (float*)d_out;

    k_prep_w<<<dim3(2880), 256, 0, stream>>>(w5a, w5c, w51, w52,
        wt1H, wt1L, wt2aH, wt2aL, wt2bH, wt2bL);
    k_prep_bn<<<dim3(1), 256, 0, stream>>>(bn1g, bn1b, bn1m, bn1v, bn2g, bn2b, bn2m, bn2v,
                                           bn3g, bn3b, bn3m, bn3v, bn4g, bn4b, bn4m, bn4v,
                                           bnAs, bnAb, bnBs, bnBb);
    k_conv<512, 256, 128><<<dim3(1024), 256, 0, stream>>>(
        x, x, wt1H, wt1L, wt1H, wt1L, bnAs, bnAb, feat1, feat2);
    k_qk<<<dim3(NPIX/64), 256, 0, stream>>>(feat1, wq, bq, wk, bk, qb16, kb16);
    k_v<<<dim3(NPIX/32), 256, 0, stream>>>(feat1, wv, bv, vbT);
    k_pam<<<dim3(NPIX/32), 256, 0, stream>>>(qb16, kb16, vbT, feat1, pgam, saf);
    k_xpose<<<dim3(NPIX/64), 256, 0, stream>>>(feat2, f2TH, f2TL);
    k_cam_energy_m<<<dim3(32, Bn), 256, 0, stream>>>(f2TH, f2TL, epart);
    k_cam_rs<<<dim3(Bn*CI), 64, 0, stream>>>(epart, att);
    k_cam_apply<<<dim3(NPIX/64, 2), 256, 0, stream>>>(feat2, att, cgam, scf);
    k_conv<128, 128, 0><<<dim3(1024), 256, 0, stream>>>(
        saf, scf, wt2aH, wt2aL, wt2bH, wt2bL, bnBs, bnBb, sa_conv, sc_conv);
    k_final<<<dim3(NPIX/64), 256, 0, stream>>>(sa_conv, sc_conv, w8, out);
}

// Round 12
// 244.241 us; speedup vs baseline: 2.7073x; 1.3997x over previous
//
#include <hip/hip_runtime.h>
#include <hip/hip_bf16.h>
#include <math.h>

#define BN_EPS 1e-3f

constexpr int Bn = 4, Hn = 64, Wn = 64, CIN = 512, CI = 128;
constexpr int HWn = Hn * Wn;        // 4096
constexpr int NPIX = Bn * HWn;      // 16384
constexpr int COn = 19;

struct F8 { float4 lo, hi; };

__device__ __forceinline__ F8 f8zero() {
    F8 r; r.lo = make_float4(0.f,0.f,0.f,0.f); r.hi = make_float4(0.f,0.f,0.f,0.f); return r;
}
__device__ __forceinline__ void fma8(F8 &acc, float a, const float4 &wlo, const float4 &whi) {
    acc.lo.x = fmaf(a, wlo.x, acc.lo.x);
    acc.lo.y = fmaf(a, wlo.y, acc.lo.y);
    acc.lo.z = fmaf(a, wlo.z, acc.lo.z);
    acc.lo.w = fmaf(a, wlo.w, acc.lo.w);
    acc.hi.x = fmaf(a, whi.x, acc.hi.x);
    acc.hi.y = fmaf(a, whi.y, acc.hi.y);
    acc.hi.z = fmaf(a, whi.z, acc.hi.z);
    acc.hi.w = fmaf(a, whi.w, acc.hi.w);
}

// ---- MFMA helpers -----------------------------------------------------------
typedef __attribute__((ext_vector_type(8)))  short    short8;  // 8 bf16
typedef __attribute__((ext_vector_type(8)))  _Float16 half8;   // 8 fp16
typedef __attribute__((ext_vector_type(16))) float    f32x16;

__device__ __forceinline__ f32x16 f16z() {
    f32x16 z;
    #pragma unroll
    for (int i = 0; i < 16; ++i) z[i] = 0.f;
    return z;
}
// fp32 -> bf16 (RNE), integer ops
__device__ __forceinline__ unsigned f2b(float f) {
    union { float f; unsigned u; } c; c.f = f;
    return (c.u + 0x7FFFu + ((c.u >> 16) & 1u)) >> 16;
}
__device__ __forceinline__ unsigned pack2(float lo, float hi) {
    return (f2b(hi) << 16) | f2b(lo);
}
// split (a,b) into packed bf16 hi words + bf16 lo residuals
__device__ __forceinline__ void split2(float a, float b, unsigned &hi, unsigned &lo) {
    const unsigned ha = f2b(a), hb = f2b(b);
    union { unsigned u; float f; } ua, ub; ua.u = ha << 16; ub.u = hb << 16;
    hi = (hb << 16) | ha;
    lo = pack2(a - ua.f, b - ub.f);
}
// pack two fp32 -> packed fp16 pair (RNE via v_cvt)
__device__ __forceinline__ unsigned pkh2(float a, float b) {
    union { _Float16 h; unsigned short u; } ca, cb;
    ca.h = (_Float16)a; cb.h = (_Float16)b;
    return ((unsigned)cb.u << 16) | ca.u;
}

// ---------------- prep: weights -> fp16 single plane, co-major ---------------
// wt1F: [32 chunk][9 tap][256 co][16 ch] fp16 (co<128 -> w5a, else w5c)
// wt2aF/bF: [8 chunk][9 tap][128 co][16 ch] fp16 for w51/w52
__global__ __launch_bounds__(256)
void k_prep_w(const float* __restrict__ w5a, const float* __restrict__ w5c,
              const float* __restrict__ w51, const float* __restrict__ w52,
              char* __restrict__ wt1F, char* __restrict__ wt2aF, char* __restrict__ wt2bF)
{
    int idx = blockIdx.x * 256 + threadIdx.x;
    if (idx < 589824) {                       // 32*9*256*8 pairs
        const int jp = idx & 7, co = (idx >> 3) & 255, ct = idx >> 11; // ct=c*9+tap
        const int tap = ct % 9, c = ct / 9;
        const float* src = (co < 128) ? w5a : w5c;
        const int coc = co & 127;
        const int ci = c*16 + jp*2;
        const float a = src[((size_t)tap*CIN + ci)*CI + coc];
        const float b = src[((size_t)tap*CIN + ci + 1)*CI + coc];
        const int L = co*32 + jp*4;
        *(unsigned*)(wt1F + (size_t)ct*8192 + L) = pkh2(a, b);
    } else {
        int k = idx - 589824;                 // 2 * 8*9*128*8 pairs
        if (k >= 147456) return;
        const float* src = (k < 73728) ? w51 : w52;
        char* dstF = (k < 73728) ? wt2aF : wt2bF;
        if (k >= 73728) k -= 73728;
        const int jp = k & 7, co = (k >> 3) & 127, ct = k >> 10; // ct=c*9+tap
        const int tap = ct % 9, c = ct / 9;
        const int ci = c*16 + jp*2;
        const float a = src[((size_t)tap*CI + ci)*CI + co];
        const float b = src[((size_t)tap*CI + ci + 1)*CI + co];
        const int L = co*32 + jp*4;
        *(unsigned*)(dstF + (size_t)ct*4096 + L) = pkh2(a, b);
    }
}

// ---------------- prep: BN -> folded scale/bias tables -----------------------
__global__ __launch_bounds__(256)
void k_prep_bn(const float* g1, const float* b1, const float* m1, const float* v1,
               const float* g2, const float* b2, const float* m2, const float* v2,
               const float* g3, const float* b3, const float* m3, const float* v3,
               const float* g4, const float* b4, const float* m4, const float* v4,
               float* bnAs, float* bnAb, float* bnBs, float* bnBb)
{
    const int t = threadIdx.x, c = t & 127;
    {
        const float *g = (t < 128) ? g1 : g2, *b = (t < 128) ? b1 : b2;
        const float *m = (t < 128) ? m1 : m2, *v = (t < 128) ? v1 : v2;
        const float s = g[c] * rsqrtf(v[c] + BN_EPS);
        bnAs[t] = s; bnAb[t] = b[c] - m[c]*s;
    }
    {
        const float *g = (t < 128) ? g3 : g4, *b = (t < 128) ? b3 : b4;
        const float *m = (t < 128) ? m3 : m4, *v = (t < 128) ? v3 : v4;
        const float s = g[c] * rsqrtf(v[c] + BN_EPS);
        bnBs[t] = s; bnBb[t] = b[c] - m[c]*s;
    }
}

// ---------------- prep: x -> fp16 conv layout [row][32 chunk][64 pix][16 ch] -
__global__ __launch_bounds__(256)
void k_prep_x(const float* __restrict__ x, _Float16* __restrict__ xcv)
{
    __shared__ float Xl[16*520];
    const int t = threadIdx.x;
    const int pb = blockIdx.x * 16;           // 1024 blocks; 16 px each (same row)
    #pragma unroll
    for (int i = 0; i < 8; ++i) {
        const int u = t + i*256;
        const int px = u >> 7, c4 = (u & 127) * 4;
        *(float4*)&Xl[px*520 + c4] = *(const float4*)&x[(size_t)(pb + px)*CIN + c4];
    }
    __syncthreads();
    const int rowg = pb >> 6, pixb = pb & 63;
    #pragma unroll
    for (int i = 0; i < 8; ++i) {
        const int u = t + i*256;              // 2048 4-ch units
        const int chunk = u >> 6, rem = u & 63;
        const int pl = rem >> 2, u4 = rem & 3;
        const float* src = &Xl[pl*520 + chunk*16 + u4*4];
        uint2 v;
        v.x = pkh2(src[0], src[1]);
        v.y = pkh2(src[2], src[3]);
        *(uint2*)&xcv[(((size_t)rowg*32 + chunk)*64 + (pixb + pl))*16 + u4*4] = v;
    }
}

// ---------------- MFMA 3x3 conv, single fp16 + folded BN + ReLU --------------
// Grid 1024: xcd=wgid&7 -> sel, ch2, row (XCD-clustered). Block = row x 64 co,
// 4 waves; wave = 1 M-tile x 1 N-tile. Input is PRE-CONVERTED fp16 in conv
// layout [row][NCHNK chunk][64 pix][16 ch]; staging = pure 8B copy with XOR
// swizzle, 2 chunks per barrier, register prefetch one pair ahead. W fp16
// single plane, 9-tap register double-buffer (A issued pre-barrier).
// mfma(A=W^T[co][k], B=X[px][k]) -> D[col=px][row=co]  (k_pam-validated map)
template<int NCHNK, int NCOTOT, int WCOBASE>
__global__ __launch_bounds__(256)
void k_convh(const _Float16* __restrict__ xcv0, const _Float16* __restrict__ xcv1,
             const _Float16* __restrict__ wtF0, const _Float16* __restrict__ wtF1,
             const float* __restrict__ bnS, const float* __restrict__ bnBi,
             float* __restrict__ out0, float* __restrict__ out1)
{
    constexpr int XPAGE = 66*32;              // 2112 B per dyr page
    constexpr int XCH   = 3*XPAGE;            // 6336 B per chunk
    __shared__ __align__(16) char Xs[2*2*XCH];

    const int t    = threadIdx.x;
    const int wgid = blockIdx.x;              // 1024
    const int xcd  = wgid & 7;
    const int sel  = xcd >> 2;
    const int ch2  = (xcd >> 1) & 1;
    const int row  = ((wgid >> 3) << 1) | (xcd & 1);   // 0..255
    const _Float16* xcv = sel ? xcv1 : xcv0;
    const _Float16* wtF = sel ? wtF1 : wtF0;
    float* dst = sel ? out1 : out0;

    const int hh = row & 63;
    const int dyLo = (hh == 0)  ? 1 : 0;
    const int dyHi = (hh == 63) ? 1 : 2;
    const int l = t & 63, w = t >> 6;
    const int lo5 = l & 31, hf = l >> 5;
    const int mi = w >> 1, nt = w & 1;
    const int corow = WCOBASE*sel + ch2*64 + nt*32 + lo5;

    // hoisted stage decode: 1584 8B-units over 7 slots/thread
    bool sAct[7], sIn[7]; int sLoff[7]; unsigned sGoff[7];
    #pragma unroll
    for (int i = 0; i < 7; ++i) {
        const int u = t + i*256;
        sAct[i] = false; sIn[i] = false; sLoff[i] = 0; sGoff[i] = 0;
        if (u < 1584) {
            const int cc = (u >= 792) ? 1 : 0;
            const int uu = u - cc*792;
            const int dyr = uu/264, rs = uu - dyr*264;
            const int s = rs >> 2, u4 = rs & 3;
            sAct[i]  = (dyr >= dyLo && dyr <= dyHi);
            sIn[i]   = (s >= 1 && s <= 64);
            sLoff[i] = cc*XCH + dyr*XPAGE + ((s*32 + u4*8) ^ ((s & 7) << 4));
            sGoff[i] = (unsigned)(((row + dyr - 1)*NCHNK + cc)*1024 + (s - 1)*16 + u4*4);
        }
    }
    int xoff[3];
    #pragma unroll
    for (int dx = 0; dx < 3; ++dx) {
        const int s = mi*32 + lo5 + dx;
        xoff[dx] = (s*32 + hf*16) ^ ((s & 7) << 4);
    }

    f32x16 acc = f16z();
    half8 wA[9], wB[9];

    auto issueW9 = [&](int c, half8 (&wr)[9]) {
        #pragma unroll
        for (int tap = 0; tap < 9; ++tap)
            wr[tap] = *(const half8*)&wtF[((size_t)(c*9 + tap)*NCOTOT + corow)*16 + hf*8];
    };
    auto compC = [&](const char* Xb, int cc, const half8 (&wr)[9]) {
        #pragma unroll
        for (int dy = 0; dy < 3; ++dy) {
            if (dy < dyLo || dy > dyHi) continue;
            const char* Xp = Xb + cc*XCH + dy*XPAGE;
            #pragma unroll
            for (int dx = 0; dx < 3; ++dx) {
                const half8 xf = *(const half8*)(Xp + xoff[dx]);
                acc = __builtin_amdgcn_mfma_f32_32x32x16_f16(wr[dy*3 + dx], xf, acc, 0, 0, 0);
            }
        }
    };

    uint2 xr[7];
    auto loadX = [&](int cbase) {
        #pragma unroll
        for (int i = 0; i < 7; ++i) {
            uint2 v; v.x = 0u; v.y = 0u;
            if (sAct[i] && sIn[i])
                v = *(const uint2*)&xcv[(size_t)sGoff[i] + (size_t)cbase*1024];
            xr[i] = v;
        }
    };

    loadX(0);
    int p = 0;
    for (int c = 0; c < NCHNK; c += 2) {
        issueW9(c, wA);                        // rides the barrier drain
        char* Xb = Xs + p*2*XCH;
        #pragma unroll
        for (int i = 0; i < 7; ++i)
            if (sAct[i]) *(uint2*)(Xb + sLoff[i]) = xr[i];
        __syncthreads();                       // one barrier per 2 chunks
        if (c + 2 < NCHNK) loadX(c + 2);
        issueW9(c + 1, wB);                    // covered by cc=0 compute
        compC(Xb, 0, wA);
        compC(Xb, 1, wB);
        p ^= 1;
    }
    // ---- epilogue: folded BN + ReLU (fp32 out) ----
    const int px = mi*32 + lo5;
    const size_t pg = (size_t)row*Wn + px;
    #pragma unroll
    for (int r = 0; r < 16; ++r) {
        const int crow = (r & 3) + 8*(r >> 2) + 4*hf;
        const int och = ch2*64 + nt*32 + crow;
        const int bnidx = sel*128 + och;
        dst[pg*CI + och] = fmaxf(fmaf(acc[r], bnS[bnidx], bnBi[bnidx]), 0.f);
    }
}

// ---------------- K2a: q,k 1x1 conv -> bf16 [NPIX][16] each ------------------
__global__ __launch_bounds__(256)
void k_qk(const float* __restrict__ feat1,
          const float* __restrict__ wq, const float* __restrict__ bq,
          const float* __restrict__ wk, const float* __restrict__ bk,
          __hip_bfloat16* __restrict__ qb, __hip_bfloat16* __restrict__ kb)
{
    __shared__ float Al[64*129];
    __shared__ __align__(16) float Wl[128*32];
    const int t = threadIdx.x;
    const int pb = blockIdx.x * 64;
    for (int idx = t; idx < 64*128; idx += 256) {
        const int p = idx >> 7, ci = idx & 127;
        Al[p*129 + ci] = feat1[(size_t)(pb + p)*CI + ci];
    }
    for (int idx = t; idx < 128*32; idx += 256) {
        const int ci = idx >> 5, c = idx & 31;
        Wl[idx] = (c < 16) ? wq[ci*16 + c] : wk[ci*16 + (c - 16)];
    }
    __syncthreads();
    const int p = t & 63, cg = t >> 6, co = cg * 8;
    F8 acc = f8zero();
    #pragma unroll 8
    for (int ci = 0; ci < 128; ++ci) {
        const float a = Al[p*129 + ci];
        const float4 wlo = *(const float4*)&Wl[ci*32 + co];
        const float4 whi = *(const float4*)&Wl[ci*32 + co + 4];
        fma8(acc, a, wlo, whi);
    }
    const float* af = (const float*)&acc;
    #pragma unroll
    for (int j = 0; j < 8; ++j) {
        const int c = co + j;
        if (c < 16) qb[(size_t)(pb + p)*16 + c]        = __float2bfloat16(af[j] + bq[c]);
        else        kb[(size_t)(pb + p)*16 + (c - 16)] = __float2bfloat16(af[j] + bk[c - 16]);
    }
}

// ---------------- K2b: v 1x1 conv -> bf16 TRANSPOSED [b][c][pix] -------------
__global__ __launch_bounds__(256)
void k_v(const float* __restrict__ feat1, const float* __restrict__ wv,
         const float* __restrict__ bv, __hip_bfloat16* __restrict__ vbT)
{
    __shared__ float Al[32*129];
    __shared__ __align__(16) float Wl[64*128];
    const int t = threadIdx.x;
    const int pb = blockIdx.x * 32;
    for (int idx = t; idx < 32*128; idx += 256) {
        const int p = idx >> 7, ci = idx & 127;
        Al[p*129 + ci] = feat1[(size_t)(pb + p)*CI + ci];
    }
    const int px = t & 15, co = (t >> 4) * 8;
    F8 acc0 = f8zero(), acc1 = f8zero();
    for (int ch = 0; ch < 2; ++ch) {
        __syncthreads();
        #pragma unroll
        for (int r = 0; r < 8; ++r) {
            const int i4 = t + r*256;
            const int kk = i4 >> 5, c4 = (i4 & 31) * 4;
            *(float4*)&Wl[kk*128 + c4] = *(const float4*)&wv[(size_t)(ch*64 + kk)*CI + c4];
        }
        __syncthreads();
        #pragma unroll 4
        for (int kk = 0; kk < 64; ++kk) {
            const float a0 = Al[px*129 + ch*64 + kk];
            const float a1 = Al[(px+16)*129 + ch*64 + kk];
            const float4 wlo = *(const float4*)&Wl[kk*128 + co];
            const float4 whi = *(const float4*)&Wl[kk*128 + co + 4];
            fma8(acc0, a0, wlo, whi);
            fma8(acc1, a1, wlo, whi);
        }
    }
    const int p0 = pb + px;
    const int bb = p0 / HWn, pin0 = p0 % HWn;
    const float* a0f = (const float*)&acc0;
    const float* a1f = (const float*)&acc1;
    #pragma unroll
    for (int j = 0; j < 8; ++j) {
        const int c = co + j;
        const size_t rowb = ((size_t)bb*CI + c) * HWn;
        vbT[rowb + pin0]      = __float2bfloat16(a0f[j] + bv[c]);
        vbT[rowb + pin0 + 16] = __float2bfloat16(a1f[j] + bv[c]);
    }
}

// ---------------- K3: PAM flash attention, 4-wave K-split --------------------
// Output written DIRECTLY in conv2's fp16 layout [row][8 chunk][64 pix][16 ch].
__global__ __launch_bounds__(256)
void k_pam(const __hip_bfloat16* __restrict__ qb, const __hip_bfloat16* __restrict__ kb,
           const __hip_bfloat16* __restrict__ vbT, const float* __restrict__ feat1,
           const float* __restrict__ gamma, _Float16* __restrict__ saf_h)
{
    __shared__ __align__(16) char pbuf[16896];   // Ppk[4][1024 u32] -> osum[32][132] f32
    __shared__ float msArr[4][32];
    __shared__ float ssArr[4][32];
    __shared__ float ssum[32];
    const int t  = threadIdx.x;
    const int wv = t >> 6, l = t & 63;
    const int lo5 = l & 31, h = l >> 5;
    unsigned* Ppk = (unsigned*)(pbuf + wv*4096);
    float* osum = (float*)pbuf;

    const int q0 = blockIdx.x * 32;
    const int bb = q0 / HWn;
    const size_t jb = (size_t)bb * HWn;
    const __hip_bfloat16* vbB = vbT + (size_t)bb * CI * HWn;

    const short8 qfrag = *(const short8*)&qb[(size_t)(q0 + lo5)*16 + 8*h];
    const f32x16 zro = f16z();

    f32x16 o[4];
    #pragma unroll
    for (int cb = 0; cb < 4; ++cb) o[cb] = f16z();

    float m_run = -1e30f, s_run = 0.f;

    for (int k0 = wv*1024; k0 < wv*1024 + 1024; k0 += 64) {
        const short8 kf0 = *(const short8*)&kb[(jb + k0 +      lo5)*16 + 8*h];
        const short8 kf1 = *(const short8*)&kb[(jb + k0 + 32 + lo5)*16 + 8*h];
        short8 vf[4][4];
        #pragma unroll
        for (int s = 0; s < 4; ++s)
            #pragma unroll
            for (int cb = 0; cb < 4; ++cb)
                vf[s][cb] = *(const short8*)&vbB[((size_t)(cb*32 + lo5))*HWn + k0 + s*16 + 8*h];

        f32x16 e0 = __builtin_amdgcn_mfma_f32_32x32x16_bf16(kf0, qfrag, zro, 0, 0, 0);
        f32x16 e1 = __builtin_amdgcn_mfma_f32_32x32x16_bf16(kf1, qfrag, zro, 0, 0, 0);

        float mt = fmaxf(e0[0], e1[0]);
        #pragma unroll
        for (int r = 1; r < 16; ++r) mt = fmaxf(mt, fmaxf(e0[r], e1[r]));
        mt = fmaxf(mt, __shfl_xor(mt, 32));

        if (__any(mt > m_run + 8.f)) {
            const float mnew = fmaxf(m_run, mt);
            const float sc = __expf(m_run - mnew);
            s_run *= sc;
            #pragma unroll
            for (int cb = 0; cb < 4; ++cb)
                #pragma unroll
                for (int r = 0; r < 16; ++r) o[cb][r] *= sc;
            m_run = mnew;
        }

        #pragma unroll
        for (int r = 0; r < 16; ++r) {
            e0[r] = __expf(e0[r] - m_run);
            e1[r] = __expf(e1[r] - m_run);
        }
        float ss = 0.f;
        #pragma unroll
        for (int r = 0; r < 16; ++r) ss += e0[r] + e1[r];
        s_run += ss;

        #pragma unroll
        for (int r = 0; r < 16; r += 2) {
            const int pidx = ((r & 3) >> 1) + 4*(r >> 2) + 2*h;
            Ppk[pidx*32 + lo5]        = pack2(e0[r], e0[r+1]);
            Ppk[(16 + pidx)*32 + lo5] = pack2(e1[r], e1[r+1]);
        }
        #pragma unroll
        for (int s = 0; s < 4; ++s) {
            union { unsigned u[4]; short8 s8; } P;
            #pragma unroll
            for (int w = 0; w < 4; ++w)
                P.u[w] = Ppk[(s*8 + 4*h + w)*32 + lo5];
            #pragma unroll
            for (int cb = 0; cb < 4; ++cb)
                o[cb] = __builtin_amdgcn_mfma_f32_32x32x16_bf16(vf[s][cb], P.s8, o[cb], 0, 0, 0);
        }
    }

    // ---- publish per-wave (m, s) ----
    const float s_w = s_run + __shfl_xor(s_run, 32);
    if (h == 0) { msArr[wv][lo5] = m_run; ssArr[wv][lo5] = s_w; }
    __syncthreads();

    // ---- merge ----
    float M = msArr[0][lo5];
    #pragma unroll
    for (int w = 1; w < 4; ++w) M = fmaxf(M, msArr[w][lo5]);
    float stot = 0.f;
    #pragma unroll
    for (int w = 0; w < 4; ++w) stot += __expf(msArr[w][lo5] - M) * ssArr[w][lo5];
    if (wv == 0 && h == 0) ssum[lo5] = stot;
    const float myscale = __expf(m_run - M);
    #pragma unroll
    for (int cb = 0; cb < 4; ++cb)
        #pragma unroll
        for (int r = 0; r < 16; ++r) o[cb][r] *= myscale;

    for (int w = 0; w < 4; ++w) {
        if (wv == w) {
            #pragma unroll
            for (int cb = 0; cb < 4; ++cb)
                #pragma unroll
                for (int r = 0; r < 16; ++r) {
                    const int c = cb*32 + (r & 3) + 8*(r >> 2) + 4*h;
                    float* p = &osum[lo5*132 + c];
                    if (w == 0) *p = o[cb][r]; else *p += o[cb][r];
                }
        }
        __syncthreads();
    }

    // ---- normalize + residual, write fp16 conv layout ----
    const float g = gamma[0];
    const int qloc = t >> 3, ch8 = t & 7;
    const float inv = 1.f / ssum[qloc];
    const int pgl = q0 + qloc;
    const int rowp = pgl >> 6, pixp = pgl & 63;
    const size_t gbase = (size_t)pgl*CI + ch8*16;
    union { _Float16 hv[16]; uint4 u[2]; } tmp;
    #pragma unroll
    for (int j = 0; j < 16; ++j)
        tmp.hv[j] = (_Float16)(g*(osum[qloc*132 + ch8*16 + j]*inv) + feat1[gbase + j]);
    uint4* dsth = (uint4*)&saf_h[((size_t)(rowp*8 + ch8)*64 + pixp)*16];
    dsth[0] = tmp.u[0];
    dsth[1] = tmp.u[1];
}

// ---------------- K4x: transpose feat2 -> bf16 hi/lo [b][c][HW] --------------
__global__ __launch_bounds__(256)
void k_xpose(const float* __restrict__ feat2,
             char* __restrict__ f2TH, char* __restrict__ f2TL)
{
    __shared__ float Xl[64*129];
    const int t = threadIdx.x;
    const int pb = blockIdx.x * 64;
    const int bb = pb / HWn, pin = pb % HWn;
    for (int idx = t; idx < 64*128; idx += 256) {
        const int p = idx >> 7, ci = idx & 127;
        Xl[p*129 + ci] = feat2[(size_t)(pb + p)*CI + ci];
    }
    __syncthreads();
    const int c = t >> 1, half = t & 1;
    const size_t rowb = ((size_t)(bb*CI + c)*HWn + pin + half*32) * 2;
    #pragma unroll
    for (int j = 0; j < 16; ++j) {
        const float a = Xl[(half*32 + 2*j)*129 + c];
        const float b = Xl[(half*32 + 2*j + 1)*129 + c];
        unsigned hi, lo; split2(a, b, hi, lo);
        *(unsigned*)(f2TH + rowb + 4*j) = hi;
        *(unsigned*)(f2TL + rowb + 4*j) = lo;
    }
}

// ---------------- K4a: CAM energy via MFMA, split-K partials -----------------
__global__ __launch_bounds__(256)
void k_cam_energy_m(const char* __restrict__ f2TH, const char* __restrict__ f2TL,
                    float* __restrict__ epart)
{
    __shared__ __align__(16) char Vh[128*256];
    __shared__ __align__(16) char Vl[128*256];
    const int t = threadIdx.x;
    const int ks = blockIdx.x, bb = blockIdx.y;
    const int l = t & 63, w = t >> 6;
    const int lo5 = l & 31, hf = l >> 5;

    #pragma unroll
    for (int pass = 0; pass < 8; ++pass) {
        const int slot = pass*256 + t;
        const int c = slot >> 4, g = slot & 15;
        const size_t gaddr = ((size_t)(bb*CI + c)*HWn + ks*128)*2 + g*16;
        const int laddr = c*256 + ((g*16) ^ ((c & 15) << 4));
        *(float4*)(Vh + laddr) = *(const float4*)(f2TH + gaddr);
        *(float4*)(Vl + laddr) = *(const float4*)(f2TL + gaddr);
    }
    __syncthreads();

    f32x16 acc[4];
    #pragma unroll
    for (int nj = 0; nj < 4; ++nj) acc[nj] = f16z();
    const int cA = w*32 + lo5;
    const int swA = (cA & 15) << 4;

    #pragma unroll
    for (int kk = 0; kk < 8; ++kk) {
        const int kb = kk*32 + hf*16;
        const short8 ah = *(const short8*)(Vh + cA*256 + (kb ^ swA));
        const short8 al = *(const short8*)(Vl + cA*256 + (kb ^ swA));
        #pragma unroll
        for (int nj = 0; nj < 4; ++nj) {
            const int dB = nj*32 + lo5;
            const int swB = (dB & 15) << 4;
            const short8 bh = *(const short8*)(Vh + dB*256 + (kb ^ swB));
            const short8 bl = *(const short8*)(Vl + dB*256 + (kb ^ swB));
            acc[nj] = __builtin_amdgcn_mfma_f32_32x32x16_bf16(ah, bh, acc[nj], 0, 0, 0);
            acc[nj] = __builtin_amdgcn_mfma_f32_32x32x16_bf16(al, bh, acc[nj], 0, 0, 0);
            acc[nj] = __builtin_amdgcn_mfma_f32_32x32x16_bf16(ah, bl, acc[nj], 0, 0, 0);
        }
    }
    float* ep = epart + ((size_t)(bb*32 + ks)*CI)*CI;
    #pragma unroll
    for (int nj = 0; nj < 4; ++nj)
        #pragma unroll
        for (int r = 0; r < 16; ++r) {
            const int c = w*32 + (r & 3) + 8*(r >> 2) + 4*hf;
            ep[(size_t)c*CI + nj*32 + lo5] = acc[nj][r];
        }
}

// ---------------- K4b: fused reduce + max-subtract softmax -------------------
__global__ __launch_bounds__(64)
void k_cam_rs(const float* __restrict__ epart, float* __restrict__ att)
{
    const int lane = threadIdx.x;
    const int row = blockIdx.x;             // b*128 + c
    const int bb = row >> 7, c = row & 127;
    float2 e = make_float2(0.f, 0.f);
    for (int ks = 0; ks < 32; ++ks) {
        const float2 v = *(const float2*)&epart[
            ((size_t)(bb*32 + ks)*CI + c)*CI + lane*2];
        e.x += v.x; e.y += v.y;
    }
    float M = fmaxf(e.x, e.y);
    #pragma unroll
    for (int off = 32; off > 0; off >>= 1) M = fmaxf(M, __shfl_xor(M, off));
    const float en0 = M - e.x, en1 = M - e.y;
    float mx = fmaxf(en0, en1);
    #pragma unroll
    for (int off = 32; off > 0; off >>= 1) mx = fmaxf(mx, __shfl_xor(mx, off));
    const float p0 = __expf(en0 - mx), p1 = __expf(en1 - mx);
    float s = p0 + p1;
    #pragma unroll
    for (int off = 32; off > 0; off >>= 1) s += __shfl_xor(s, off);
    const float inv = 1.f / s;
    float2 o; o.x = p0*inv; o.y = p1*inv;
    *(float2*)&att[(size_t)row*CI + lane*2] = o;
}

// ---------------- K4c: CAM apply -> fp16 conv layout -------------------------
__global__ __launch_bounds__(256)
void k_cam_apply(const float* __restrict__ feat2, const float* __restrict__ att,
                 const float* __restrict__ gamma, _Float16* __restrict__ scf_h)
{
    __shared__ float Xl[64*129];
    __shared__ __align__(16) float aT[128*64];
    const int t = threadIdx.x;
    const int pb = blockIdx.x * 64;
    const int bb = pb / HWn;
    const int ch = blockIdx.y * 64;
    for (int idx = t; idx < 64*128; idx += 256) {
        const int p = idx >> 7, ci = idx & 127;
        Xl[p*129 + ci] = feat2[(size_t)(pb + p)*CI + ci];
    }
    for (int idx = t; idx < 128*64; idx += 256) {
        const int d = idx >> 6, cc = idx & 63;
        aT[d*64 + cc] = att[((size_t)bb*CI + ch + cc)*CI + d];
    }
    __syncthreads();
    const int px = t & 63, cg = t >> 6;
    F8 accA = f8zero(), accB = f8zero();
    #pragma unroll 4
    for (int d = 0; d < 128; ++d) {
        const float xv = Xl[px*129 + d];
        const float* ap = &aT[d*64 + cg*16];
        const float4 a0 = *(const float4*)&ap[0];
        const float4 a1 = *(const float4*)&ap[4];
        const float4 a2 = *(const float4*)&ap[8];
        const float4 a3 = *(const float4*)&ap[12];
        fma8(accA, xv, a0, a1);
        fma8(accB, xv, a2, a3);
    }
    const float g = gamma[0];
    const float* fa = (const float*)&accA;
    const float* fb = (const float*)&accB;
    const int p0g = pb + px;
    const int rowA = p0g >> 6, pixA = p0g & 63;
    const int chunkA = (ch >> 4) + cg;               // cA>>4 for j<8
    const size_t baseA = ((size_t)(rowA*8 + chunkA)*64 + pixA)*16;
    #pragma unroll
    for (int j = 0; j < 8; ++j) {
        const int cA = ch + cg*16 + j;
        const int cB = cA + 8;
        scf_h[baseA + j]     = (_Float16)(g*fa[j] + Xl[px*129 + cA]);
        scf_h[baseA + 8 + j] = (_Float16)(g*fb[j] + Xl[px*129 + cB]);
    }
}

// ---------------- K7: final 1x1 conv (sum of two branches) -> out ------------
__global__ __launch_bounds__(256)
void k_final(const float* __restrict__ sa, const float* __restrict__ sc,
             const float* __restrict__ w8, float* __restrict__ out)
{
    __shared__ float Xl[64*129];
    __shared__ float w8l[128*COn];
    const int t = threadIdx.x;
    const int pb = blockIdx.x * 64;
    for (int idx = t; idx < 64*128; idx += 256) {
        const int p = idx >> 7, ci = idx & 127;
        const size_t gi = (size_t)(pb + p)*CI + ci;
        Xl[p*129 + ci] = sa[gi] + sc[gi];
    }
    for (int idx = t; idx < 128*COn; idx += 256) w8l[idx] = w8[idx];
    __syncthreads();
    for (int idx = t; idx < 64*COn; idx += 256) {
        const int p = idx / COn, co = idx - p*COn;
        float acc = 0.f;
        #pragma unroll 8
        for (int ci = 0; ci < 128; ++ci)
            acc = fmaf(Xl[p*129 + ci], w8l[ci*COn + co], acc);
        out[(size_t)(pb + p)*COn + co] = acc;
    }
}

extern "C" void kernel_launch(void* const* d_in, const int* in_sizes, int n_in,
                              void* d_out, int out_size, void* d_ws, size_t ws_size,
                              hipStream_t stream)
{
    const float* x    = (const float*)d_in[0];
    const float* w5a  = (const float*)d_in[1];
    const float* w5c  = (const float*)d_in[2];
    const float* wq   = (const float*)d_in[3];
    const float* bq   = (const float*)d_in[4];
    const float* wk   = (const float*)d_in[5];
    const float* bk   = (const float*)d_in[6];
    const float* wv   = (const float*)d_in[7];
    const float* bv   = (const float*)d_in[8];
    const float* pgam = (const float*)d_in[9];
    const float* cgam = (const float*)d_in[10];
    const float* w51  = (const float*)d_in[11];
    const float* w52  = (const float*)d_in[12];
    const float* w8   = (const float*)d_in[13];
    const float* bn1g = (const float*)d_in[14];
    const float* bn1b = (const float*)d_in[15];
    const float* bn1m = (const float*)d_in[16];
    const float* bn1v = (const float*)d_in[17];
    const float* bn2g = (const float*)d_in[18];
    const float* bn2b = (const float*)d_in[19];
    const float* bn2m = (const float*)d_in[20];
    const float* bn2v = (const float*)d_in[21];
    const float* bn3g = (const float*)d_in[22];
    const float* bn3b = (const float*)d_in[23];
    const float* bn3m = (const float*)d_in[24];
    const float* bn3v = (const float*)d_in[25];
    const float* bn4g = (const float*)d_in[26];
    const float* bn4b = (const float*)d_in[27];
    const float* bn4m = (const float*)d_in[28];
    const float* bn4v = (const float*)d_in[29];

    char* wsb = (char*)d_ws;
    // [0,8MB): feat1 (conv1 out) -> f2TH/f2TL (xpose->energy) -> sa_conv
    float* feat1 = (float*)(wsb + 0);
    char*  f2TH  = wsb + 0;                     // 4 MB
    char*  f2TL  = wsb + 4194304;               // 4 MB
    // [8,16MB): feat2 -> sc_conv
    float* feat2 = (float*)(wsb + 8388608);
    // [16,32MB): xcv (16 MB, prep_x -> conv1); then saf_h/scf_h/epart
    _Float16* xcv   = (_Float16*)(wsb + 16777216);
    _Float16* saf_h = (_Float16*)(wsb + 16777216);   // 4 MB (post-conv1)
    _Float16* scf_h = (_Float16*)(wsb + 20971520);   // 4 MB
    float*    epart = (float*)(wsb + 25165824);      // 8 MB -> 33554432
    float* att = (float*)(wsb + 33816576);           // 256 KB
    __hip_bfloat16* qb16 = (__hip_bfloat16*)(wsb + 34078720);  // 512 KB
    __hip_bfloat16* kb16 = (__hip_bfloat16*)(wsb + 34603008);  // 512 KB
    __hip_bfloat16* vbT  = (__hip_bfloat16*)(wsb + 35127296);  // 4 MB -> 39321600
    char* wt1F  = wsb + 39321600;               // 2359296 -> 41680896
    char* wt2aF = wsb + 41680896;               // 294912  -> 41975808
    char* wt2bF = wsb + 41975808;               // 294912  -> 42270720
    float* bnAs = (float*)(wsb + 42270720);     // 1 KB each
    float* bnAb = (float*)(wsb + 42271744);
    float* bnBs = (float*)(wsb + 42272768);
    float* bnBb = (float*)(wsb + 42273792);     // high-water 42274816
    float* sa_conv = feat1;
    float* sc_conv = feat2;
    float* out  = (float*)d_out;

    k_prep_w<<<dim3(2880), 256, 0, stream>>>(w5a, w5c, w51, w52, wt1F, wt2aF, wt2bF);
    k_prep_bn<<<dim3(1), 256, 0, stream>>>(bn1g, bn1b, bn1m, bn1v, bn2g, bn2b, bn2m, bn2v,
                                           bn3g, bn3b, bn3m, bn3v, bn4g, bn4b, bn4m, bn4v,
                                           bnAs, bnAb, bnBs, bnBb);
    k_prep_x<<<dim3(1024), 256, 0, stream>>>(x, xcv);
    k_convh<32, 256, 128><<<dim3(1024), 256, 0, stream>>>(
        xcv, xcv, (const _Float16*)wt1F, (const _Float16*)wt1F, bnAs, bnAb, feat1, feat2);
    k_qk<<<dim3(NPIX/64), 256, 0, stream>>>(feat1, wq, bq, wk, bk, qb16, kb16);
    k_v<<<dim3(NPIX/32), 256, 0, stream>>>(feat1, wv, bv, vbT);
    k_pam<<<dim3(NPIX/32), 256, 0, stream>>>(qb16, kb16, vbT, feat1, pgam, saf_h);
    k_xpose<<<dim3(NPIX/64), 256, 0, stream>>>(feat2, f2TH, f2TL);
    k_cam_energy_m<<<dim3(32, Bn), 256, 0, stream>>>(f2TH, f2TL, epart);
    k_cam_rs<<<dim3(Bn*CI), 64, 0, stream>>>(epart, att);
    k_cam_apply<<<dim3(NPIX/64, 2), 256, 0, stream>>>(feat2, att, cgam, scf_h);
    k_convh<8, 128, 0><<<dim3(1024), 256, 0, stream>>>(
        saf_h, scf_h, (const _Float16*)wt2aF, (const _Float16*)wt2bF,
        bnBs, bnBb, sa_conv, sc_conv);
    k_final<<<dim3(NPIX/64), 256, 0, stream>>>(sa_conv, sc_conv, w8, out);
}